// Round 3
// baseline (221.158 us; speedup 1.0000x reference)
//
#include <hip/hip_runtime.h>
#include <math.h>

// ---------------------------------------------------------------------------
// AngleEncodingQuantumNet: conv1+BN+relu+pool -> conv2+BN+relu+pool -> fc1
// (tanh) -> sel -> 10-qubit RY/CZ circuit -> post1(relu) -> post2.
// Train-mode BN => stats pass then apply pass.
// conv2 = MFMA over shift-sections (no im2col): LDS input is [pixel][ic]
// (ic contiguous) so each A-frag is one ds_read_b128; 3x3 shift = address
// offset. 3-way split AhBh+AlBh+AhBl (error ~2^-20 rel, negligible).
// fc1 = bf16 MFMA, 2-way split A (measured 7.6e-6 final absmax, thr 3.8e-5).
// ---------------------------------------------------------------------------

#define BATCH 2048
#define PI_F 3.14159265358979323846f
#define KP 3200          // fc1 padded K' = 2*1568 -> 3200 (50 BK=64 steps)
#define KSTEPS 50
#define BSTRIDE 480      // conv2 B' row stride (bf16): 960B%128B=64 -> balanced

typedef unsigned short ushort_t;
typedef __attribute__((ext_vector_type(8))) short bf16x8;
typedef __attribute__((ext_vector_type(4))) float f32x4;

__device__ __forceinline__ float wave_reduce_add(float v) {
#pragma unroll
  for (int off = 32; off >= 1; off >>= 1) v += __shfl_xor(v, off, 64);
  return v;
}

__device__ __forceinline__ ushort_t f2bf(float v) {  // RNE f32 -> bf16 bits
  unsigned u = __float_as_uint(v);
  u += 0x7FFFu + ((u >> 16) & 1u);
  return (ushort_t)(u >> 16);
}
__device__ __forceinline__ float bf2f(ushort_t b) {
  return __uint_as_float(((unsigned)b) << 16);
}

// ---------------- conv1: stats pass (+ bonus block builds conv2 B') --------
__global__ __launch_bounds__(256) void k_conv1_stats(
    const float* __restrict__ x, const float* __restrict__ cw,
    const float* __restrict__ cb, float* __restrict__ part1,
    const float* __restrict__ cw2, ushort_t* __restrict__ wB) {
  const int t = threadIdx.x;
  if (blockIdx.x == BATCH) {
    // build conv2 B': [oc][k'], k' = sec*16+ic, sec 0..26 = [Bh|Bh|Bl] x 9
    for (int i = t; i < 32 * BSTRIDE; i += 256) {
      int oc = i / BSTRIDE, k = i - oc * BSTRIDE;
      ushort_t val = 0;
      if (k < 432) {
        int sec = k >> 4, ic = k & 15;
        int s = (sec >= 18) ? (sec - 18) : (sec >= 9 ? sec - 9 : sec);
        float w = cw2[oc * 144 + ic * 9 + s];
        if (sec < 18) val = f2bf(w);
        else val = f2bf(w - bf2f(f2bf(w)));
      }
      wB[i] = val;
    }
    return;
  }
  const int b = blockIdx.x;
  __shared__ float xs[30][33];
  __shared__ float ws[160];
  __shared__ float redS[16][28];
  __shared__ float redQ[16][28];
  for (int i = t; i < 30 * 33; i += 256) (&xs[0][0])[i] = 0.f;
  if (t < 144) ws[t] = cw[t];
  else if (t < 160) ws[t] = cb[t - 144];
  __syncthreads();
  const float* xb = x + b * 784;
  for (int i = t; i < 784; i += 256) xs[1 + i / 28][1 + (i % 28)] = xb[i];
  __syncthreads();
  for (int task = t; task < 448; task += 256) {
    const int oc = task / 28;
    const int row = task - oc * 28;
    float wk[9];
#pragma unroll
    for (int k = 0; k < 9; ++k) wk[k] = ws[oc * 9 + k];
    const float bc = ws[144 + oc];
    float A0 = xs[row][0], A1 = xs[row][1];
    float B0 = xs[row + 1][0], B1 = xs[row + 1][1];
    float C0 = xs[row + 2][0], C1 = xs[row + 2][1];
    float s = 0.f, q = 0.f;
#pragma unroll 4
    for (int xx = 0; xx < 28; ++xx) {
      float A2 = xs[row][xx + 2], B2 = xs[row + 1][xx + 2], C2 = xs[row + 2][xx + 2];
      float acc = bc;
      acc = fmaf(wk[0], A0, acc); acc = fmaf(wk[1], A1, acc); acc = fmaf(wk[2], A2, acc);
      acc = fmaf(wk[3], B0, acc); acc = fmaf(wk[4], B1, acc); acc = fmaf(wk[5], B2, acc);
      acc = fmaf(wk[6], C0, acc); acc = fmaf(wk[7], C1, acc); acc = fmaf(wk[8], C2, acc);
      s += acc; q = fmaf(acc, acc, q);
      A0 = A1; A1 = A2; B0 = B1; B1 = B2; C0 = C1; C1 = C2;
    }
    redS[oc][row] = s;
    redQ[oc][row] = q;
  }
  __syncthreads();
  if (t < 32) {
    const int c = t >> 1;
    float acc = 0.f;
    if (t & 1) {
#pragma unroll 4
      for (int r = 0; r < 28; ++r) acc += redQ[c][r];
    } else {
#pragma unroll 4
      for (int r = 0; r < 28; ++r) acc += redS[c][r];
    }
    part1[b * 32 + t] = acc;
  }
}

// ---------------- BN stats fold (both layers) -------------------------------
__global__ __launch_bounds__(256) void k_bnstat(
    const float* __restrict__ part, const float* __restrict__ g,
    const float* __restrict__ bb, float* __restrict__ stats,
    int nch, int nblk, double invN) {
  const int c = blockIdx.x;
  const int t = threadIdx.x;
  const int stride = nch * 2;
  double ls = 0.0, lq = 0.0;
  for (int i = t; i < nblk; i += 256) {
    ls += (double)part[i * stride + c * 2];
    lq += (double)part[i * stride + c * 2 + 1];
  }
#pragma unroll
  for (int off = 32; off >= 1; off >>= 1) {
    ls += __shfl_xor(ls, off, 64);
    lq += __shfl_xor(lq, off, 64);
  }
  __shared__ double rs[4], rq[4];
  if ((t & 63) == 0) { rs[t >> 6] = ls; rq[t >> 6] = lq; }
  __syncthreads();
  if (t == 0) {
    double S = rs[0] + rs[1] + rs[2] + rs[3];
    double Q = rq[0] + rq[1] + rq[2] + rq[3];
    double mean = S * invN;
    double var = Q * invN - mean * mean;
    double inv = 1.0 / sqrt(var + 1e-5);
    double sc = (double)g[c] * inv;
    stats[c * 2] = (float)sc;
    stats[c * 2 + 1] = (float)((double)bb[c] - mean * sc);
  }
}

// ---------------- conv1: fused BN+relu+pool, emits h1 as hi/lo bf16 ---------
// output layout: h1bf[b][plane][pixel=y*14+x][ic] ushort (6272/image)
__global__ __launch_bounds__(256) void k_conv1_fused(
    const float* __restrict__ x, const float* __restrict__ cw,
    const float* __restrict__ cb, const float* __restrict__ stats1,
    ushort_t* __restrict__ h1bf) {
  const int b = blockIdx.x;
  const int t = threadIdx.x;
  __shared__ float xs[30][33];
  __shared__ float ws[160];
  __shared__ __align__(16) ushort_t obuf[2 * 3136];
  for (int i = t; i < 30 * 33; i += 256) (&xs[0][0])[i] = 0.f;
  if (t < 144) ws[t] = cw[t];
  else if (t < 160) ws[t] = cb[t - 144];
  __syncthreads();
  const float* xb = x + b * 784;
  for (int i = t; i < 784; i += 256) xs[1 + i / 28][1 + (i % 28)] = xb[i];
  __syncthreads();
  if (t < 224) {
    const int oc = t / 14;
    const int pr = t - oc * 14;
    float wk[9];
#pragma unroll
    for (int k = 0; k < 9; ++k) wk[k] = ws[oc * 9 + k];
    const float bc = ws[144 + oc];
    const float scale = stats1[oc * 2], shift = stats1[oc * 2 + 1];
    const int r0 = 2 * pr;
    float A0 = xs[r0][0],     A1 = xs[r0][1];
    float B0 = xs[r0 + 1][0], B1 = xs[r0 + 1][1];
    float C0 = xs[r0 + 2][0], C1 = xs[r0 + 2][1];
    float D0 = xs[r0 + 3][0], D1 = xs[r0 + 3][1];
    float pmax = 0.f;
#pragma unroll 4
    for (int xx = 0; xx < 28; ++xx) {
      float A2 = xs[r0][xx + 2], B2 = xs[r0 + 1][xx + 2];
      float C2 = xs[r0 + 2][xx + 2], D2 = xs[r0 + 3][xx + 2];
      float c0 = bc, c1 = bc;
      c0 = fmaf(wk[0], A0, c0); c0 = fmaf(wk[1], A1, c0); c0 = fmaf(wk[2], A2, c0);
      c0 = fmaf(wk[3], B0, c0); c0 = fmaf(wk[4], B1, c0); c0 = fmaf(wk[5], B2, c0);
      c0 = fmaf(wk[6], C0, c0); c0 = fmaf(wk[7], C1, c0); c0 = fmaf(wk[8], C2, c0);
      c1 = fmaf(wk[0], B0, c1); c1 = fmaf(wk[1], B1, c1); c1 = fmaf(wk[2], B2, c1);
      c1 = fmaf(wk[3], C0, c1); c1 = fmaf(wk[4], C1, c1); c1 = fmaf(wk[5], C2, c1);
      c1 = fmaf(wk[6], D0, c1); c1 = fmaf(wk[7], D1, c1); c1 = fmaf(wk[8], D2, c1);
      float e0 = fmaxf(fmaf(scale, c0, shift), 0.f);
      float e1 = fmaxf(fmaf(scale, c1, shift), 0.f);
      float m = fmaxf(e0, e1);
      if ((xx & 1) == 0) {
        pmax = m;
      } else {
        float pv = fmaxf(pmax, m);
        ushort_t hi = f2bf(pv);
        ushort_t lo = f2bf(pv - bf2f(hi));
        int pidx = (pr * 14 + (xx >> 1)) * 16 + oc;
        obuf[pidx] = hi;
        obuf[3136 + pidx] = lo;
      }
      A0 = A1; A1 = A2; B0 = B1; B1 = B2; C0 = C1; C1 = C2; D0 = D1; D1 = D2;
    }
  }
  __syncthreads();
  uint4* dst = (uint4*)(h1bf + (size_t)b * 6272);
  const uint4* sob = (const uint4*)obuf;
  for (int i = t; i < 784; i += 256) dst[i] = sob[i];
}

// ---------------- conv2 via MFMA (shift-section K, no im2col) ---------------
// A in LDS: [plane][py 0..15][px 0..15][ic 0..15] bf16, image at (+1,+1),
// borders zero. A-frag = 8 contiguous ic = 1 ds_read_b128; shift (dy,dx) is
// an address offset. K' = 27 sections of 16 ([AhBh 9][AlBh 9][AhBl 9]) ->
// 14 MFMA k-steps (last half zero-killed by B pad). Raw out [b][196][32].
__global__ __launch_bounds__(256) void k_conv2_mfma(
    const ushort_t* __restrict__ h1bf, const ushort_t* __restrict__ wB,
    const float* __restrict__ cb, float* __restrict__ part2,
    float* __restrict__ raw) {
  const int b = blockIdx.x;
  const int t = threadIdx.x;
  __shared__ __align__(16) ushort_t aT[2 * 4096];
  __shared__ __align__(16) ushort_t bS[32 * BSTRIDE];
  __shared__ float red[4][64];
  {
    uint4 z = make_uint4(0, 0, 0, 0);
    uint4* a4 = (uint4*)aT;
#pragma unroll
    for (int i = 0; i < 4; ++i) a4[t + i * 256] = z;  // 1024 uint4 = 16KB
    uint4* b4 = (uint4*)bS;
    const uint4* w4 = (const uint4*)wB;
    for (int i = t; i < (32 * BSTRIDE) / 8; i += 256) b4[i] = w4[i];
  }
  __syncthreads();
  {
    uint4* a4 = (uint4*)aT;
    const uint4* src = (const uint4*)(h1bf + (size_t)b * 6272);
    for (int i = t; i < 784; i += 256) {
      int plane = i / 392, j = i - plane * 392;
      int pix = j >> 1, half = j & 1;
      int y = pix / 14, x = pix - y * 14;
      a4[plane * 512 + ((y + 1) * 16 + (x + 1)) * 2 + half] = src[i];
    }
  }
  __syncthreads();

  const int lane = t & 63;
  const int wv = t >> 6;
  const int ic0 = ((lane >> 4) & 1) * 8;
  const int hb = lane >> 5;
  int abase[4];
#pragma unroll
  for (int fi = 0; fi < 4; ++fi) {
    int f = wv + fi * 4;
    int p = f * 16 + (lane & 15);
    int pp = p < 196 ? p : 195;
    int y = pp / 14, x = pp - y * 14;
    abase[fi] = (y * 16 + x) * 16 + ic0;
  }
  const float bias0 = cb[lane & 15];
  const float bias1 = cb[16 + (lane & 15)];
  f32x4 acc[4][2];
#pragma unroll
  for (int fi = 0; fi < 4; ++fi) {
    acc[fi][0] = (f32x4){bias0, bias0, bias0, bias0};
    acc[fi][1] = (f32x4){bias1, bias1, bias1, bias1};
  }
  const int kb = (lane & 15) * BSTRIDE + (lane >> 4) * 8;
#pragma unroll
  for (int kt = 0; kt < 14; ++kt) {
    bf16x8 bv0 = *(const bf16x8*)&bS[kb + kt * 32];
    bf16x8 bv1 = *(const bf16x8*)&bS[kb + 16 * BSTRIDE + kt * 32];
    int sec = 2 * kt + hb;
    int ss = sec >= 18 ? sec - 18 : (sec >= 9 ? sec - 9 : sec);
    if (ss > 8) ss = 8;  // sec==27: B is zero, A-read just stays in-bounds
    int plane = (sec >= 9 && sec < 18) ? 1 : 0;
    int dy = ss / 3, dx = ss - dy * 3;
    int doff = plane * 4096 + dy * 256 + dx * 16;
#pragma unroll
    for (int fi = 0; fi < 4; ++fi) {
      if (wv + fi * 4 < 13) {
        bf16x8 av = *(const bf16x8*)&aT[doff + abase[fi]];
        acc[fi][0] = __builtin_amdgcn_mfma_f32_16x16x32_bf16(av, bv0, acc[fi][0], 0, 0, 0);
        acc[fi][1] = __builtin_amdgcn_mfma_f32_16x16x32_bf16(av, bv1, acc[fi][1], 0, 0, 0);
      }
    }
  }
  // epilogue: raw store (oc innermost -> coalesced) + per-oc stats
  float s0 = 0.f, q0 = 0.f, s1 = 0.f, q1 = 0.f;
  float* rb = raw + (size_t)b * 6272;
#pragma unroll
  for (int fi = 0; fi < 4; ++fi) {
    int f = wv + fi * 4;
    if (f < 13) {
#pragma unroll
      for (int r = 0; r < 4; ++r) {
        int p = f * 16 + (lane >> 4) * 4 + r;
        if (p < 196) {
          float v0 = acc[fi][0][r], v1 = acc[fi][1][r];
          rb[p * 32 + (lane & 15)] = v0;
          rb[p * 32 + 16 + (lane & 15)] = v1;
          s0 += v0; q0 = fmaf(v0, v0, q0);
          s1 += v1; q1 = fmaf(v1, v1, q1);
        }
      }
    }
  }
  s0 += __shfl_xor(s0, 16, 64); s0 += __shfl_xor(s0, 32, 64);
  q0 += __shfl_xor(q0, 16, 64); q0 += __shfl_xor(q0, 32, 64);
  s1 += __shfl_xor(s1, 16, 64); s1 += __shfl_xor(s1, 32, 64);
  q1 += __shfl_xor(q1, 16, 64); q1 += __shfl_xor(q1, 32, 64);
  if (lane < 16) {
    red[wv][lane * 2] = s0;            red[wv][lane * 2 + 1] = q0;
    red[wv][(lane + 16) * 2] = s1;     red[wv][(lane + 16) * 2 + 1] = q1;
  }
  __syncthreads();
  if (t < 64) part2[b * 64 + t] = red[0][t] + red[1][t] + red[2][t] + red[3][t];
}

// ---------------- pack A': BN+relu+pool from raw, then [Ah | Al] bf16 -------
__global__ __launch_bounds__(256) void k_pack_a(
    const float* __restrict__ raw, const float* __restrict__ stats2,
    ushort_t* __restrict__ Ap) {
  const int m = blockIdx.x, t = threadIdx.x;
  __shared__ float hv[1568];
  for (int i = t; i < 1568; i += 256) {
    int oc = i / 49, r = i - oc * 49;
    int py = r / 7, px = r - py * 7;
    const float* rp = raw + (size_t)m * 6272 + (py * 28 + px * 2) * 32 + oc;
    float a = rp[0], bq = rp[32], c = rp[448], d = rp[480];
    float mx = fmaxf(fmaxf(a, bq), fmaxf(c, d));
    float mn = fminf(fminf(a, bq), fminf(c, d));
    float sc = stats2[oc * 2], sh = stats2[oc * 2 + 1];
    hv[i] = fmaxf(fmaf(sc, (sc >= 0.f ? mx : mn), sh), 0.f);  // BN monotone
  }
  __syncthreads();
  ushort_t* ap = Ap + (size_t)m * KP;
  for (int c = t; c < KP / 8; c += 256) {
    union { ushort_t u[8]; uint4 v; } o;
    if (c < 196) {
#pragma unroll
      for (int j = 0; j < 8; ++j) o.u[j] = f2bf(hv[c * 8 + j]);
    } else if (c < 392) {
#pragma unroll
      for (int j = 0; j < 8; ++j) {
        float v = hv[(c - 196) * 8 + j];
        o.u[j] = f2bf(v - bf2f(f2bf(v)));
      }
    } else {
      o.v = make_uint4(0, 0, 0, 0);
    }
    *(uint4*)(ap + c * 8) = o.v;
  }
}

// ---------------- pack B': [Bh | Bh] bf16, rows padded to 832 ---------------
__global__ __launch_bounds__(256) void k_pack_b(
    const float* __restrict__ w, ushort_t* __restrict__ Bp) {
  const int n = blockIdx.x, t = threadIdx.x;
  ushort_t* bp = Bp + (size_t)n * KP;
  if (t < 196) {
    union { ushort_t u[8]; uint4 v; } o;
    o.v = make_uint4(0, 0, 0, 0);
    if (n < 784) {
      const float* wp = w + (size_t)n * 1568 + t * 8;
#pragma unroll
      for (int j = 0; j < 8; ++j) o.u[j] = f2bf(wp[j]);
    }
    *(uint4*)(bp + t * 8) = o.v;
    *(uint4*)(bp + 1568 + t * 8) = o.v;
  } else if (t < 204) {
    *(uint4*)(bp + 3136 + (t - 196) * 8) = make_uint4(0, 0, 0, 0);
  }
}

// ---------------- fc1 as bf16 MFMA GEMM + tanh ------------------------------
__global__ __launch_bounds__(256) void k_fc1_mfma(
    const ushort_t* __restrict__ Ap, const ushort_t* __restrict__ Bp,
    const float* __restrict__ bias, float* __restrict__ feats) {
  __shared__ ushort_t As[64 * 64];
  __shared__ ushort_t Bs[64 * 64];
  const int t = threadIdx.x;
  const int id = blockIdx.x;
  const int swz = (id & 7) * 52 + (id >> 3);  // 416 = 8*52: XCD-contig chunks
  const int mt = swz & 31, nt = swz >> 5;
  const int m0 = mt * 64, n0 = nt * 64;
  const int lane = t & 63, wid = t >> 6;
  const int wm = wid >> 1, wn = wid & 1;

  const int srow = t >> 3, sslot = t & 7;
  const int xsl = (sslot ^ (srow & 7)) << 3;
  ushort_t* awp = &As[srow * 64 + xsl];
  ushort_t* bwp = &Bs[srow * 64 + xsl];
  const uint4* agp = (const uint4*)(Ap + (size_t)(m0 + srow) * KP) + sslot;
  const uint4* bgp = (const uint4*)(Bp + (size_t)(n0 + srow) * KP) + sslot;
  const int ROWOFF = 32 * (KP / 8);

  const int rbaseA = (wm * 32 + (lane & 15)) * 64;
  const int rbaseB = (wn * 32 + (lane & 15)) * 64;
  const int x0 = (((lane >> 4) + 0) ^ (lane & 7)) << 3;
  const int x1 = (((lane >> 4) + 4) ^ (lane & 7)) << 3;

  f32x4 acc00 = {0.f, 0.f, 0.f, 0.f};
  f32x4 acc01 = acc00, acc10 = acc00, acc11 = acc00;

  uint4 ca0 = agp[0], ca1 = agp[ROWOFF];
  uint4 cb0 = bgp[0], cb1 = bgp[ROWOFF];
  for (int kt = 0; kt < KSTEPS; ++kt) {
    __syncthreads();
    *(uint4*)awp = ca0; *(uint4*)(awp + 32 * 64) = ca1;
    *(uint4*)bwp = cb0; *(uint4*)(bwp + 32 * 64) = cb1;
    __syncthreads();
    uint4 na0 = ca0, na1 = ca1, nb0 = cb0, nb1 = cb1;
    if (kt < KSTEPS - 1) {
      const uint4* ag = agp + (kt + 1) * 8;
      const uint4* bg = bgp + (kt + 1) * 8;
      na0 = ag[0]; na1 = ag[ROWOFF]; nb0 = bg[0]; nb1 = bg[ROWOFF];
    }
    {
      bf16x8 a0 = *(const bf16x8*)&As[rbaseA + x0];
      bf16x8 a1 = *(const bf16x8*)&As[rbaseA + 1024 + x0];
      bf16x8 b0 = *(const bf16x8*)&Bs[rbaseB + x0];
      bf16x8 b1 = *(const bf16x8*)&Bs[rbaseB + 1024 + x0];
      acc00 = __builtin_amdgcn_mfma_f32_16x16x32_bf16(a0, b0, acc00, 0, 0, 0);
      acc01 = __builtin_amdgcn_mfma_f32_16x16x32_bf16(a0, b1, acc01, 0, 0, 0);
      acc10 = __builtin_amdgcn_mfma_f32_16x16x32_bf16(a1, b0, acc10, 0, 0, 0);
      acc11 = __builtin_amdgcn_mfma_f32_16x16x32_bf16(a1, b1, acc11, 0, 0, 0);
    }
    {
      bf16x8 a0 = *(const bf16x8*)&As[rbaseA + x1];
      bf16x8 a1 = *(const bf16x8*)&As[rbaseA + 1024 + x1];
      bf16x8 b0 = *(const bf16x8*)&Bs[rbaseB + x1];
      bf16x8 b1 = *(const bf16x8*)&Bs[rbaseB + 1024 + x1];
      acc00 = __builtin_amdgcn_mfma_f32_16x16x32_bf16(a0, b0, acc00, 0, 0, 0);
      acc01 = __builtin_amdgcn_mfma_f32_16x16x32_bf16(a0, b1, acc01, 0, 0, 0);
      acc10 = __builtin_amdgcn_mfma_f32_16x16x32_bf16(a1, b0, acc10, 0, 0, 0);
      acc11 = __builtin_amdgcn_mfma_f32_16x16x32_bf16(a1, b1, acc11, 0, 0, 0);
    }
    ca0 = na0; ca1 = na1; cb0 = nb0; cb1 = nb1;
  }

  const int nbase = n0 + wn * 32 + (lane & 15);
  const int mbase = m0 + wm * 32 + ((lane >> 4) << 2);
  auto emit = [&](f32x4 v, int fm, int fn) {
    const int n = nbase + fn * 16;
    if (n < 784) {
      const float bv = bias[n];
      const int mr = mbase + fm * 16;
#pragma unroll
      for (int r = 0; r < 4; ++r)
        feats[(size_t)(mr + r) * 784 + n] = tanhf(v[r] + bv);
    }
  };
  emit(acc00, 0, 0); emit(acc01, 0, 1); emit(acc10, 1, 0); emit(acc11, 1, 1);
}

// ---------------- sel: feats[2048][784] @ sel_w[10][784]^T + b --------------
__global__ __launch_bounds__(256) void k_sel(
    const float* __restrict__ feats, const float* __restrict__ sw,
    const float* __restrict__ sb, float* __restrict__ selv) {
  const int wid = (blockIdx.x << 2) + (threadIdx.x >> 6);
  const int lane = threadIdx.x & 63;
  const float* f = feats + (size_t)wid * 784;
  float acc[10];
#pragma unroll
  for (int i = 0; i < 10; ++i) acc[i] = 0.f;
  for (int k = lane; k < 784; k += 64) {
    const float fv = f[k];
#pragma unroll
    for (int i = 0; i < 10; ++i) acc[i] = fmaf(fv, sw[i * 784 + k], acc[i]);
  }
#pragma unroll
  for (int i = 0; i < 10; ++i) acc[i] = wave_reduce_add(acc[i]);
  if (lane == 0) {
#pragma unroll
    for (int i = 0; i < 10; ++i) selv[wid * 10 + i] = acc[i] + sb[i];
  }
}

// ---------------- 10-qubit statevector circuit ------------------------------
template <int W>
__device__ __forceinline__ void ry_gate(float (&a)[16], int lane, float th) {
  float s, c;
  sincosf(0.5f * th, &s, &c);
  if (W < 4) {
    const int st = 1 << W;
#pragma unroll
    for (int r = 0; r < 16; ++r) {
      if (!(r & st)) {
        float lo = a[r], hi = a[r + st];
        a[r] = fmaf(c, lo, -s * hi);
        a[r + st] = fmaf(s, lo, c * hi);
      }
    }
  } else {
    const int m = 1 << (W - 4);
    const float sg = (lane & m) ? s : -s;
#pragma unroll
    for (int r = 0; r < 16; ++r) {
      float other = __shfl_xor(a[r], m, 64);
      a[r] = fmaf(c, a[r], sg * other);
    }
  }
}

#define RY10(EXPR)                                                   \
  {                                                                  \
    ry_gate<0>(a, lane, EXPR(0)); ry_gate<1>(a, lane, EXPR(1));      \
    ry_gate<2>(a, lane, EXPR(2)); ry_gate<3>(a, lane, EXPR(3));      \
    ry_gate<4>(a, lane, EXPR(4)); ry_gate<5>(a, lane, EXPR(5));      \
    ry_gate<6>(a, lane, EXPR(6)); ry_gate<7>(a, lane, EXPR(7));      \
    ry_gate<8>(a, lane, EXPR(8)); ry_gate<9>(a, lane, EXPR(9));      \
  }

__global__ __launch_bounds__(256) void k_quantum(
    const float* __restrict__ selv, const float* __restrict__ qp,
    float* __restrict__ qout) {
  const int b = (blockIdx.x << 2) + (threadIdx.x >> 6);
  const int lane = threadIdx.x & 63;
  float a[16];
#pragma unroll
  for (int r = 0; r < 16; ++r) a[r] = 0.f;
  if (lane == 0) a[0] = 1.f;
  float czs[16];
#pragma unroll
  for (int r = 0; r < 16; ++r) {
    int idx = (lane << 4) | r;
    czs[r] = (__popc(idx & (idx >> 1)) & 1) ? -1.f : 1.f;
  }
  const float* sp = selv + b * 10;
#define ENC(i) (sp[i] * PI_F)
  RY10(ENC)
#undef ENC
  for (int layer = 0; layer < 3; ++layer) {
    const float* lp = qp + layer * 10;
#define LAY(i) (lp[i])
    RY10(LAY)
#undef LAY
#pragma unroll
    for (int r = 0; r < 16; ++r) a[r] *= czs[r];
  }
  float p[16];
  float lt = 0.f;
#pragma unroll
  for (int r = 0; r < 16; ++r) { p[r] = a[r] * a[r]; lt += p[r]; }
  float z[10];
#pragma unroll
  for (int w = 0; w < 4; ++w) {
    float v = 0.f;
#pragma unroll
    for (int r = 0; r < 16; ++r) v += ((r >> w) & 1) ? -p[r] : p[r];
    z[w] = v;
  }
#pragma unroll
  for (int w = 4; w < 10; ++w) z[w] = ((lane >> (w - 4)) & 1) ? -lt : lt;
#pragma unroll
  for (int w = 0; w < 10; ++w) z[w] = wave_reduce_add(z[w]);
  if (lane == 0) {
#pragma unroll
    for (int w = 0; w < 10; ++w) qout[b * 10 + w] = z[w];
  }
}

// ---------------- post layers ------------------------------------------------
__global__ __launch_bounds__(256) void k_post(
    const float* __restrict__ qout, const float* __restrict__ w1,
    const float* __restrict__ b1, const float* __restrict__ w2,
    const float* __restrict__ b2, float* __restrict__ out) {
  const int b = blockIdx.x * 256 + threadIdx.x;
  float qv[10];
#pragma unroll
  for (int i = 0; i < 10; ++i) qv[i] = qout[b * 10 + i];
  float h[32];
#pragma unroll
  for (int jj = 0; jj < 32; ++jj) {
    float s = b1[jj];
#pragma unroll
    for (int i = 0; i < 10; ++i) s = fmaf(w1[jj * 10 + i], qv[i], s);
    h[jj] = fmaxf(s, 0.f);
  }
#pragma unroll
  for (int o = 0; o < 10; ++o) {
    float s = b2[o];
#pragma unroll
    for (int jj = 0; jj < 32; ++jj) s = fmaf(w2[o * 32 + jj], h[jj], s);
    out[b * 10 + o] = s;
  }
}

// ---------------------------------------------------------------------------
extern "C" void kernel_launch(void* const* d_in, const int* in_sizes, int n_in,
                              void* d_out, int out_size, void* d_ws, size_t ws_size,
                              hipStream_t stream) {
  (void)in_sizes; (void)n_in; (void)out_size; (void)ws_size;
  const float* x    = (const float*)d_in[0];
  const float* c1w  = (const float*)d_in[1];
  const float* c1b  = (const float*)d_in[2];
  const float* bn1g = (const float*)d_in[3];
  const float* bn1b = (const float*)d_in[4];
  const float* c2w  = (const float*)d_in[5];
  const float* c2b  = (const float*)d_in[6];
  const float* bn2g = (const float*)d_in[7];
  const float* bn2b = (const float*)d_in[8];
  const float* fc1w = (const float*)d_in[9];
  const float* fc1b = (const float*)d_in[10];
  const float* selw = (const float*)d_in[11];
  const float* selb = (const float*)d_in[12];
  const float* qpar = (const float*)d_in[13];
  const float* p1w  = (const float*)d_in[14];
  const float* p1b  = (const float*)d_in[15];
  const float* p2w  = (const float*)d_in[16];
  const float* p2b  = (const float*)d_in[17];

  // ws layout (floats), total = 22,442,080 f = 89,768,320 B (round-2-proven).
  // Aliases: Ap (1,638,400 f) sits in h1bf (dead after conv2_mfma);
  //          wB (7,680 f) sits at start of feats (written later by fc1).
  float* ws = (float*)d_ws;
  ushort_t* h1bf = (ushort_t*)ws;           // 2048*6272 us = 3,211,264 f... x2 planes = 6,422,528 f
  ushort_t* Ap   = (ushort_t*)ws;           // alias
  size_t o = 6422528;
  float* raw    = ws + o; o += 12845056;    // [2048][196][32]
  ushort_t* Bp  = (ushort_t*)(ws + o); o += 1331200;
  float* feats  = ws + o; o += 1605632;
  ushort_t* wB  = (ushort_t*)feats;         // alias (32*480 us = 7,680 f)
  float* part1  = ws + o; o += 65536;
  float* part2  = ws + o; o += 131072;
  float* stats1 = ws + o; o += 32;
  float* stats2 = ws + o; o += 64;
  float* selv   = ws + o; o += 20480;
  float* qout   = ws + o; o += 20480;
  float* outp   = (float*)d_out;

  k_conv1_stats<<<BATCH + 1, 256, 0, stream>>>(x, c1w, c1b, part1, c2w, wB);
  k_bnstat<<<16, 256, 0, stream>>>(part1, bn1g, bn1b, stats1, 16, BATCH,
                                   1.0 / (2048.0 * 784.0));
  k_conv1_fused<<<BATCH, 256, 0, stream>>>(x, c1w, c1b, stats1, h1bf);
  k_conv2_mfma<<<BATCH, 256, 0, stream>>>(h1bf, wB, c2b, part2, raw);
  k_bnstat<<<32, 256, 0, stream>>>(part2, bn2g, bn2b, stats2, 32, BATCH,
                                   1.0 / (2048.0 * 196.0));
  k_pack_a<<<BATCH, 256, 0, stream>>>(raw, stats2, Ap);
  k_pack_b<<<832, 256, 0, stream>>>(fc1w, Bp);
  k_fc1_mfma<<<416, 256, 0, stream>>>(Ap, Bp, fc1b, feats);
  k_sel<<<512, 256, 0, stream>>>(feats, selw, selb, selv);
  k_quantum<<<512, 256, 0, stream>>>(selv, qpar, qout);
  k_post<<<8, 256, 0, stream>>>(qout, p1w, p1b, p2w, p2b, outp);
}

// Round 4
// 166.236 us; speedup vs baseline: 1.3304x; 1.3304x over previous
//
#include <hip/hip_runtime.h>
#include <math.h>

// ---------------------------------------------------------------------------
// AngleEncodingQuantumNet: conv1+BN+relu+pool -> conv2+BN+relu+pool -> fc1
// (tanh) -> sel -> 10-qubit RY/CZ circuit -> post1(relu) -> post2.
// Train-mode BN => stats pass then apply pass.
// conv2 = MFMA over shift-sections (no im2col). R4: pixel stride 24 ushorts
// (48B -> 2-way banks = free), B stride 456 (2-way), 2 images/block with
// 8 waves (16 waves/CU at 80.4KB LDS), pack_a LDS-staged coalesced.
// fc1 = bf16 MFMA, 2-way split A (measured 7.6e-6 final absmax, thr 3.8e-5).
// ---------------------------------------------------------------------------

#define BATCH 2048
#define PI_F 3.14159265358979323846f
#define KP 3200          // fc1 padded K' = 2*1568 -> 3200 (50 BK=64 steps)
#define KSTEPS 50
#define BSTRIDE 456      // conv2 B' row stride (ushorts): 912B -> bank step 4

typedef unsigned short ushort_t;
typedef __attribute__((ext_vector_type(8))) short bf16x8;
typedef __attribute__((ext_vector_type(4))) float f32x4;

__device__ __forceinline__ float wave_reduce_add(float v) {
#pragma unroll
  for (int off = 32; off >= 1; off >>= 1) v += __shfl_xor(v, off, 64);
  return v;
}

__device__ __forceinline__ ushort_t f2bf(float v) {  // RNE f32 -> bf16 bits
  unsigned u = __float_as_uint(v);
  u += 0x7FFFu + ((u >> 16) & 1u);
  return (ushort_t)(u >> 16);
}
__device__ __forceinline__ float bf2f(ushort_t b) {
  return __uint_as_float(((unsigned)b) << 16);
}

// ---------------- conv1: stats pass (+ bonus block builds conv2 B') --------
__global__ __launch_bounds__(256) void k_conv1_stats(
    const float* __restrict__ x, const float* __restrict__ cw,
    const float* __restrict__ cb, float* __restrict__ part1,
    const float* __restrict__ cw2, ushort_t* __restrict__ wB) {
  const int t = threadIdx.x;
  if (blockIdx.x == BATCH) {
    // conv2 B': [oc][k'], k' = sec*16+ic, sec 0..26 = [Bh x9 | Bh x9 | Bl x9]
    for (int i = t; i < 32 * BSTRIDE; i += 256) {
      int oc = i / BSTRIDE, k = i - oc * BSTRIDE;
      ushort_t val = 0;
      if (k < 432) {
        int sec = k >> 4, ic = k & 15;
        int s = (sec >= 18) ? (sec - 18) : (sec >= 9 ? sec - 9 : sec);
        float w = cw2[oc * 144 + ic * 9 + s];
        if (sec < 18) val = f2bf(w);
        else val = f2bf(w - bf2f(f2bf(w)));
      }
      wB[i] = val;
    }
    return;
  }
  const int b = blockIdx.x;
  __shared__ float xs[30][33];
  __shared__ float ws[160];
  __shared__ float redS[16][28];
  __shared__ float redQ[16][28];
  for (int i = t; i < 30 * 33; i += 256) (&xs[0][0])[i] = 0.f;
  if (t < 144) ws[t] = cw[t];
  else if (t < 160) ws[t] = cb[t - 144];
  __syncthreads();
  const float* xb = x + b * 784;
  for (int i = t; i < 784; i += 256) xs[1 + i / 28][1 + (i % 28)] = xb[i];
  __syncthreads();
  for (int task = t; task < 448; task += 256) {
    const int oc = task / 28;
    const int row = task - oc * 28;
    float wk[9];
#pragma unroll
    for (int k = 0; k < 9; ++k) wk[k] = ws[oc * 9 + k];
    const float bc = ws[144 + oc];
    float A0 = xs[row][0], A1 = xs[row][1];
    float B0 = xs[row + 1][0], B1 = xs[row + 1][1];
    float C0 = xs[row + 2][0], C1 = xs[row + 2][1];
    float s = 0.f, q = 0.f;
#pragma unroll 4
    for (int xx = 0; xx < 28; ++xx) {
      float A2 = xs[row][xx + 2], B2 = xs[row + 1][xx + 2], C2 = xs[row + 2][xx + 2];
      float acc = bc;
      acc = fmaf(wk[0], A0, acc); acc = fmaf(wk[1], A1, acc); acc = fmaf(wk[2], A2, acc);
      acc = fmaf(wk[3], B0, acc); acc = fmaf(wk[4], B1, acc); acc = fmaf(wk[5], B2, acc);
      acc = fmaf(wk[6], C0, acc); acc = fmaf(wk[7], C1, acc); acc = fmaf(wk[8], C2, acc);
      s += acc; q = fmaf(acc, acc, q);
      A0 = A1; A1 = A2; B0 = B1; B1 = B2; C0 = C1; C1 = C2;
    }
    redS[oc][row] = s;
    redQ[oc][row] = q;
  }
  __syncthreads();
  if (t < 32) {
    const int c = t >> 1;
    float acc = 0.f;
    if (t & 1) {
#pragma unroll 4
      for (int r = 0; r < 28; ++r) acc += redQ[c][r];
    } else {
#pragma unroll 4
      for (int r = 0; r < 28; ++r) acc += redS[c][r];
    }
    part1[b * 32 + t] = acc;
  }
}

// ---------------- BN stats fold (both layers) -------------------------------
__global__ __launch_bounds__(256) void k_bnstat(
    const float* __restrict__ part, const float* __restrict__ g,
    const float* __restrict__ bb, float* __restrict__ stats,
    int nch, int nblk, double invN) {
  const int c = blockIdx.x;
  const int t = threadIdx.x;
  const int stride = nch * 2;
  double ls = 0.0, lq = 0.0;
  for (int i = t; i < nblk; i += 256) {
    ls += (double)part[i * stride + c * 2];
    lq += (double)part[i * stride + c * 2 + 1];
  }
#pragma unroll
  for (int off = 32; off >= 1; off >>= 1) {
    ls += __shfl_xor(ls, off, 64);
    lq += __shfl_xor(lq, off, 64);
  }
  __shared__ double rs[4], rq[4];
  if ((t & 63) == 0) { rs[t >> 6] = ls; rq[t >> 6] = lq; }
  __syncthreads();
  if (t == 0) {
    double S = rs[0] + rs[1] + rs[2] + rs[3];
    double Q = rq[0] + rq[1] + rq[2] + rq[3];
    double mean = S * invN;
    double var = Q * invN - mean * mean;
    double inv = 1.0 / sqrt(var + 1e-5);
    double sc = (double)g[c] * inv;
    stats[c * 2] = (float)sc;
    stats[c * 2 + 1] = (float)((double)bb[c] - mean * sc);
  }
}

// ---------------- conv1: fused BN+relu+pool, emits h1 as hi/lo bf16 ---------
// output layout: h1bf[b][plane][pixel=y*14+x][ic] ushort (6272/image)
__global__ __launch_bounds__(256) void k_conv1_fused(
    const float* __restrict__ x, const float* __restrict__ cw,
    const float* __restrict__ cb, const float* __restrict__ stats1,
    ushort_t* __restrict__ h1bf) {
  const int b = blockIdx.x;
  const int t = threadIdx.x;
  __shared__ float xs[30][33];
  __shared__ float ws[160];
  __shared__ __align__(16) ushort_t obuf[2 * 3136];
  for (int i = t; i < 30 * 33; i += 256) (&xs[0][0])[i] = 0.f;
  if (t < 144) ws[t] = cw[t];
  else if (t < 160) ws[t] = cb[t - 144];
  __syncthreads();
  const float* xb = x + b * 784;
  for (int i = t; i < 784; i += 256) xs[1 + i / 28][1 + (i % 28)] = xb[i];
  __syncthreads();
  if (t < 224) {
    const int oc = t / 14;
    const int pr = t - oc * 14;
    float wk[9];
#pragma unroll
    for (int k = 0; k < 9; ++k) wk[k] = ws[oc * 9 + k];
    const float bc = ws[144 + oc];
    const float scale = stats1[oc * 2], shift = stats1[oc * 2 + 1];
    const int r0 = 2 * pr;
    float A0 = xs[r0][0],     A1 = xs[r0][1];
    float B0 = xs[r0 + 1][0], B1 = xs[r0 + 1][1];
    float C0 = xs[r0 + 2][0], C1 = xs[r0 + 2][1];
    float D0 = xs[r0 + 3][0], D1 = xs[r0 + 3][1];
    float pmax = 0.f;
#pragma unroll 4
    for (int xx = 0; xx < 28; ++xx) {
      float A2 = xs[r0][xx + 2], B2 = xs[r0 + 1][xx + 2];
      float C2 = xs[r0 + 2][xx + 2], D2 = xs[r0 + 3][xx + 2];
      float c0 = bc, c1 = bc;
      c0 = fmaf(wk[0], A0, c0); c0 = fmaf(wk[1], A1, c0); c0 = fmaf(wk[2], A2, c0);
      c0 = fmaf(wk[3], B0, c0); c0 = fmaf(wk[4], B1, c0); c0 = fmaf(wk[5], B2, c0);
      c0 = fmaf(wk[6], C0, c0); c0 = fmaf(wk[7], C1, c0); c0 = fmaf(wk[8], C2, c0);
      c1 = fmaf(wk[0], B0, c1); c1 = fmaf(wk[1], B1, c1); c1 = fmaf(wk[2], B2, c1);
      c1 = fmaf(wk[3], C0, c1); c1 = fmaf(wk[4], C1, c1); c1 = fmaf(wk[5], C2, c1);
      c1 = fmaf(wk[6], D0, c1); c1 = fmaf(wk[7], D1, c1); c1 = fmaf(wk[8], D2, c1);
      float e0 = fmaxf(fmaf(scale, c0, shift), 0.f);
      float e1 = fmaxf(fmaf(scale, c1, shift), 0.f);
      float m = fmaxf(e0, e1);
      if ((xx & 1) == 0) {
        pmax = m;
      } else {
        float pv = fmaxf(pmax, m);
        ushort_t hi = f2bf(pv);
        ushort_t lo = f2bf(pv - bf2f(hi));
        int pidx = (pr * 14 + (xx >> 1)) * 16 + oc;
        obuf[pidx] = hi;
        obuf[3136 + pidx] = lo;
      }
      A0 = A1; A1 = A2; B0 = B1; B1 = B2; C0 = C1; C1 = C2; D0 = D1; D1 = D2;
    }
  }
  __syncthreads();
  uint4* dst = (uint4*)(h1bf + (size_t)b * 6272);
  const uint4* sob = (const uint4*)obuf;
  for (int i = t; i < 784; i += 256) dst[i] = sob[i];
}

// ---------------- conv2 via MFMA (shift-section K, no im2col) ---------------
// 2 images/block, 512 threads (waves 0-3 -> img0, 4-7 -> img1). A in LDS:
// [img][plane][pixel(16x16 padded)][24] (48B pixel stride -> 2-way banks);
// B [32][456]. A-frag = 1 ds_read_b128; 3x3 shift = address offset.
// K' = 27 sections ([AhBh 9][AlBh 9][AhBl 9]) -> 14 k-steps. Raw [b][196][32].
__global__ __launch_bounds__(512, 4) void k_conv2_mfma(
    const ushort_t* __restrict__ h1bf, const ushort_t* __restrict__ wB,
    const float* __restrict__ cb, float* __restrict__ part2,
    float* __restrict__ raw) {
  const int b0 = blockIdx.x * 2;
  const int t = threadIdx.x;
  __shared__ __align__(16) ushort_t aT[2 * 12288];   // 49,152 B
  __shared__ __align__(16) ushort_t bS[32 * BSTRIDE]; // 29,184 B
  __shared__ float red[2][4][64];                     //  2,048 B
  {
    uint4 z = make_uint4(0, 0, 0, 0);
    uint4* a4 = (uint4*)aT;
#pragma unroll
    for (int i = 0; i < 6; ++i) a4[t + i * 512] = z;  // 3072 uint4
    uint4* b4 = (uint4*)bS;
    const uint4* w4 = (const uint4*)wB;
    for (int i = t; i < (32 * BSTRIDE) / 8; i += 512) b4[i] = w4[i];
  }
  __syncthreads();
  {
    uint4* a4 = (uint4*)aT;
    const uint4* src = (const uint4*)(h1bf + (size_t)b0 * 6272);
    for (int i = t; i < 1568; i += 512) {
      int img = i / 784, j = i - img * 784;
      int plane = j / 392, jj = j - plane * 392;
      int pix = jj >> 1, half = jj & 1;
      int y = pix / 14, x = pix - y * 14;
      a4[img * 1536 + plane * 768 + ((y + 1) * 16 + (x + 1)) * 3 + half] =
          src[img * 784 + j];
    }
  }
  __syncthreads();

  const int lane = t & 63;
  const int wv = t >> 6;
  const int img = wv >> 2, wi = wv & 3;
  const int ic0 = ((lane >> 4) & 1) * 8;
  const int hb = lane >> 5;
  const int imgbase = img * 12288;
  int abase[4];
#pragma unroll
  for (int fi = 0; fi < 4; ++fi) {
    int f = wi + fi * 4;
    int p = f * 16 + (lane & 15);
    int pp = p < 196 ? p : 195;
    int y = pp / 14, x = pp - y * 14;
    abase[fi] = imgbase + (y * 16 + x) * 24 + ic0;
  }
  f32x4 acc[4][2];
  {
    const float bias0 = cb[lane & 15];
    const float bias1 = cb[16 + (lane & 15)];
#pragma unroll
    for (int fi = 0; fi < 4; ++fi) {
      acc[fi][0] = (f32x4){bias0, bias0, bias0, bias0};
      acc[fi][1] = (f32x4){bias1, bias1, bias1, bias1};
    }
  }
  const int kb = (lane & 15) * BSTRIDE + (lane >> 4) * 8;
#pragma unroll
  for (int kt = 0; kt < 14; ++kt) {
    bf16x8 bv0 = *(const bf16x8*)&bS[kb + kt * 32];
    bf16x8 bv1 = *(const bf16x8*)&bS[kb + 16 * BSTRIDE + kt * 32];
    int sec = 2 * kt + hb;
    int ss = sec >= 18 ? sec - 18 : (sec >= 9 ? sec - 9 : sec);
    if (ss > 8) ss = 8;  // sec==27: B is zero, A-read just stays in-bounds
    int plane = (sec >= 9 && sec < 18) ? 1 : 0;
    int dy = ss / 3, dx = ss - dy * 3;
    int doff = plane * 6144 + dy * 384 + dx * 24;
#pragma unroll
    for (int fi = 0; fi < 4; ++fi) {
      if (wi + fi * 4 < 13) {
        bf16x8 av = *(const bf16x8*)&aT[doff + abase[fi]];
        acc[fi][0] = __builtin_amdgcn_mfma_f32_16x16x32_bf16(av, bv0, acc[fi][0], 0, 0, 0);
        acc[fi][1] = __builtin_amdgcn_mfma_f32_16x16x32_bf16(av, bv1, acc[fi][1], 0, 0, 0);
      }
    }
  }
  // epilogue: raw store (oc innermost -> coalesced) + per-oc stats
  float s0 = 0.f, q0 = 0.f, s1 = 0.f, q1 = 0.f;
  float* rb = raw + (size_t)(b0 + img) * 6272;
#pragma unroll
  for (int fi = 0; fi < 4; ++fi) {
    int f = wi + fi * 4;
    if (f < 13) {
#pragma unroll
      for (int r = 0; r < 4; ++r) {
        int p = f * 16 + (lane >> 4) * 4 + r;
        if (p < 196) {
          float v0 = acc[fi][0][r], v1 = acc[fi][1][r];
          rb[p * 32 + (lane & 15)] = v0;
          rb[p * 32 + 16 + (lane & 15)] = v1;
          s0 += v0; q0 = fmaf(v0, v0, q0);
          s1 += v1; q1 = fmaf(v1, v1, q1);
        }
      }
    }
  }
  s0 += __shfl_xor(s0, 16, 64); s0 += __shfl_xor(s0, 32, 64);
  q0 += __shfl_xor(q0, 16, 64); q0 += __shfl_xor(q0, 32, 64);
  s1 += __shfl_xor(s1, 16, 64); s1 += __shfl_xor(s1, 32, 64);
  q1 += __shfl_xor(q1, 16, 64); q1 += __shfl_xor(q1, 32, 64);
  if (lane < 16) {
    red[img][wi][lane * 2] = s0;        red[img][wi][lane * 2 + 1] = q0;
    red[img][wi][(lane + 16) * 2] = s1; red[img][wi][(lane + 16) * 2 + 1] = q1;
  }
  __syncthreads();
  if (t < 128) {
    int im = t >> 6, c = t & 63;
    part2[(b0 + im) * 64 + c] =
        red[im][0][c] + red[im][1][c] + red[im][2][c] + red[im][3][c];
  }
}

// ---------------- pack A': BN+relu+pool from raw, then [Ah | Al] bf16 -------
// raw staged via LDS (coalesced float4 loads; [196][36] pad kills bank-0 hit)
__global__ __launch_bounds__(256) void k_pack_a(
    const float* __restrict__ raw, const float* __restrict__ stats2,
    ushort_t* __restrict__ Ap) {
  const int m = blockIdx.x, t = threadIdx.x;
  __shared__ float rL[196 * 36];
  __shared__ float hv[1568];
  {
    const float4* src = (const float4*)(raw + (size_t)m * 6272);
    for (int i = t; i < 1568; i += 256) {
      int pix = i >> 3, q = i & 7;
      *(float4*)&rL[pix * 36 + q * 4] = src[i];
    }
  }
  __syncthreads();
  for (int i = t; i < 1568; i += 256) {
    int oc = i / 49, r = i - oc * 49;
    int py = r / 7, px = r - py * 7;
    int base = (py * 28 + px * 2) * 36 + oc;
    float a = rL[base], bq = rL[base + 36], c = rL[base + 504], d = rL[base + 540];
    float mx = fmaxf(fmaxf(a, bq), fmaxf(c, d));
    float mn = fminf(fminf(a, bq), fminf(c, d));
    float sc = stats2[oc * 2], sh = stats2[oc * 2 + 1];
    hv[i] = fmaxf(fmaf(sc, (sc >= 0.f ? mx : mn), sh), 0.f);  // BN monotone
  }
  __syncthreads();
  ushort_t* ap = Ap + (size_t)m * KP;
  for (int c = t; c < KP / 8; c += 256) {
    union { ushort_t u[8]; uint4 v; } o;
    if (c < 196) {
#pragma unroll
      for (int j = 0; j < 8; ++j) o.u[j] = f2bf(hv[c * 8 + j]);
    } else if (c < 392) {
#pragma unroll
      for (int j = 0; j < 8; ++j) {
        float v = hv[(c - 196) * 8 + j];
        o.u[j] = f2bf(v - bf2f(f2bf(v)));
      }
    } else {
      o.v = make_uint4(0, 0, 0, 0);
    }
    *(uint4*)(ap + c * 8) = o.v;
  }
}

// ---------------- pack B': [Bh | Bh] bf16, rows padded to 832 ---------------
__global__ __launch_bounds__(256) void k_pack_b(
    const float* __restrict__ w, ushort_t* __restrict__ Bp) {
  const int n = blockIdx.x, t = threadIdx.x;
  ushort_t* bp = Bp + (size_t)n * KP;
  if (t < 196) {
    union { ushort_t u[8]; uint4 v; } o;
    o.v = make_uint4(0, 0, 0, 0);
    if (n < 784) {
      const float* wp = w + (size_t)n * 1568 + t * 8;
#pragma unroll
      for (int j = 0; j < 8; ++j) o.u[j] = f2bf(wp[j]);
    }
    *(uint4*)(bp + t * 8) = o.v;
    *(uint4*)(bp + 1568 + t * 8) = o.v;
  } else if (t < 204) {
    *(uint4*)(bp + 3136 + (t - 196) * 8) = make_uint4(0, 0, 0, 0);
  }
}

// ---------------- fc1 as bf16 MFMA GEMM + tanh ------------------------------
__global__ __launch_bounds__(256) void k_fc1_mfma(
    const ushort_t* __restrict__ Ap, const ushort_t* __restrict__ Bp,
    const float* __restrict__ bias, float* __restrict__ feats) {
  __shared__ ushort_t As[64 * 64];
  __shared__ ushort_t Bs[64 * 64];
  const int t = threadIdx.x;
  const int id = blockIdx.x;
  const int swz = (id & 7) * 52 + (id >> 3);  // 416 = 8*52: XCD-contig chunks
  const int mt = swz & 31, nt = swz >> 5;
  const int m0 = mt * 64, n0 = nt * 64;
  const int lane = t & 63, wid = t >> 6;
  const int wm = wid >> 1, wn = wid & 1;

  const int srow = t >> 3, sslot = t & 7;
  const int xsl = (sslot ^ (srow & 7)) << 3;
  ushort_t* awp = &As[srow * 64 + xsl];
  ushort_t* bwp = &Bs[srow * 64 + xsl];
  const uint4* agp = (const uint4*)(Ap + (size_t)(m0 + srow) * KP) + sslot;
  const uint4* bgp = (const uint4*)(Bp + (size_t)(n0 + srow) * KP) + sslot;
  const int ROWOFF = 32 * (KP / 8);

  const int rbaseA = (wm * 32 + (lane & 15)) * 64;
  const int rbaseB = (wn * 32 + (lane & 15)) * 64;
  const int x0 = (((lane >> 4) + 0) ^ (lane & 7)) << 3;
  const int x1 = (((lane >> 4) + 4) ^ (lane & 7)) << 3;

  f32x4 acc00 = {0.f, 0.f, 0.f, 0.f};
  f32x4 acc01 = acc00, acc10 = acc00, acc11 = acc00;

  uint4 ca0 = agp[0], ca1 = agp[ROWOFF];
  uint4 cb0 = bgp[0], cb1 = bgp[ROWOFF];
  for (int kt = 0; kt < KSTEPS; ++kt) {
    __syncthreads();
    *(uint4*)awp = ca0; *(uint4*)(awp + 32 * 64) = ca1;
    *(uint4*)bwp = cb0; *(uint4*)(bwp + 32 * 64) = cb1;
    __syncthreads();
    uint4 na0 = ca0, na1 = ca1, nb0 = cb0, nb1 = cb1;
    if (kt < KSTEPS - 1) {
      const uint4* ag = agp + (kt + 1) * 8;
      const uint4* bg = bgp + (kt + 1) * 8;
      na0 = ag[0]; na1 = ag[ROWOFF]; nb0 = bg[0]; nb1 = bg[ROWOFF];
    }
    {
      bf16x8 a0 = *(const bf16x8*)&As[rbaseA + x0];
      bf16x8 a1 = *(const bf16x8*)&As[rbaseA + 1024 + x0];
      bf16x8 b0 = *(const bf16x8*)&Bs[rbaseB + x0];
      bf16x8 b1 = *(const bf16x8*)&Bs[rbaseB + 1024 + x0];
      acc00 = __builtin_amdgcn_mfma_f32_16x16x32_bf16(a0, b0, acc00, 0, 0, 0);
      acc01 = __builtin_amdgcn_mfma_f32_16x16x32_bf16(a0, b1, acc01, 0, 0, 0);
      acc10 = __builtin_amdgcn_mfma_f32_16x16x32_bf16(a1, b0, acc10, 0, 0, 0);
      acc11 = __builtin_amdgcn_mfma_f32_16x16x32_bf16(a1, b1, acc11, 0, 0, 0);
    }
    {
      bf16x8 a0 = *(const bf16x8*)&As[rbaseA + x1];
      bf16x8 a1 = *(const bf16x8*)&As[rbaseA + 1024 + x1];
      bf16x8 b0 = *(const bf16x8*)&Bs[rbaseB + x1];
      bf16x8 b1 = *(const bf16x8*)&Bs[rbaseB + 1024 + x1];
      acc00 = __builtin_amdgcn_mfma_f32_16x16x32_bf16(a0, b0, acc00, 0, 0, 0);
      acc01 = __builtin_amdgcn_mfma_f32_16x16x32_bf16(a0, b1, acc01, 0, 0, 0);
      acc10 = __builtin_amdgcn_mfma_f32_16x16x32_bf16(a1, b0, acc10, 0, 0, 0);
      acc11 = __builtin_amdgcn_mfma_f32_16x16x32_bf16(a1, b1, acc11, 0, 0, 0);
    }
    ca0 = na0; ca1 = na1; cb0 = nb0; cb1 = nb1;
  }

  const int nbase = n0 + wn * 32 + (lane & 15);
  const int mbase = m0 + wm * 32 + ((lane >> 4) << 2);
  auto emit = [&](f32x4 v, int fm, int fn) {
    const int n = nbase + fn * 16;
    if (n < 784) {
      const float bv = bias[n];
      const int mr = mbase + fm * 16;
#pragma unroll
      for (int r = 0; r < 4; ++r)
        feats[(size_t)(mr + r) * 784 + n] = tanhf(v[r] + bv);
    }
  };
  emit(acc00, 0, 0); emit(acc01, 0, 1); emit(acc10, 1, 0); emit(acc11, 1, 1);
}

// ---------------- sel: feats[2048][784] @ sel_w[10][784]^T + b --------------
__global__ __launch_bounds__(256) void k_sel(
    const float* __restrict__ feats, const float* __restrict__ sw,
    const float* __restrict__ sb, float* __restrict__ selv) {
  const int wid = (blockIdx.x << 2) + (threadIdx.x >> 6);
  const int lane = threadIdx.x & 63;
  const float* f = feats + (size_t)wid * 784;
  float acc[10];
#pragma unroll
  for (int i = 0; i < 10; ++i) acc[i] = 0.f;
  for (int k = lane; k < 784; k += 64) {
    const float fv = f[k];
#pragma unroll
    for (int i = 0; i < 10; ++i) acc[i] = fmaf(fv, sw[i * 784 + k], acc[i]);
  }
#pragma unroll
  for (int i = 0; i < 10; ++i) acc[i] = wave_reduce_add(acc[i]);
  if (lane == 0) {
#pragma unroll
    for (int i = 0; i < 10; ++i) selv[wid * 10 + i] = acc[i] + sb[i];
  }
}

// ---------------- 10-qubit statevector circuit ------------------------------
template <int W>
__device__ __forceinline__ void ry_gate(float (&a)[16], int lane, float th) {
  float s, c;
  sincosf(0.5f * th, &s, &c);
  if (W < 4) {
    const int st = 1 << W;
#pragma unroll
    for (int r = 0; r < 16; ++r) {
      if (!(r & st)) {
        float lo = a[r], hi = a[r + st];
        a[r] = fmaf(c, lo, -s * hi);
        a[r + st] = fmaf(s, lo, c * hi);
      }
    }
  } else {
    const int m = 1 << (W - 4);
    const float sg = (lane & m) ? s : -s;
#pragma unroll
    for (int r = 0; r < 16; ++r) {
      float other = __shfl_xor(a[r], m, 64);
      a[r] = fmaf(c, a[r], sg * other);
    }
  }
}

#define RY10(EXPR)                                                   \
  {                                                                  \
    ry_gate<0>(a, lane, EXPR(0)); ry_gate<1>(a, lane, EXPR(1));      \
    ry_gate<2>(a, lane, EXPR(2)); ry_gate<3>(a, lane, EXPR(3));      \
    ry_gate<4>(a, lane, EXPR(4)); ry_gate<5>(a, lane, EXPR(5));      \
    ry_gate<6>(a, lane, EXPR(6)); ry_gate<7>(a, lane, EXPR(7));      \
    ry_gate<8>(a, lane, EXPR(8)); ry_gate<9>(a, lane, EXPR(9));      \
  }

__global__ __launch_bounds__(256) void k_quantum(
    const float* __restrict__ selv, const float* __restrict__ qp,
    float* __restrict__ qout) {
  const int b = (blockIdx.x << 2) + (threadIdx.x >> 6);
  const int lane = threadIdx.x & 63;
  float a[16];
#pragma unroll
  for (int r = 0; r < 16; ++r) a[r] = 0.f;
  if (lane == 0) a[0] = 1.f;
  float czs[16];
#pragma unroll
  for (int r = 0; r < 16; ++r) {
    int idx = (lane << 4) | r;
    czs[r] = (__popc(idx & (idx >> 1)) & 1) ? -1.f : 1.f;
  }
  const float* sp = selv + b * 10;
#define ENC(i) (sp[i] * PI_F)
  RY10(ENC)
#undef ENC
  for (int layer = 0; layer < 3; ++layer) {
    const float* lp = qp + layer * 10;
#define LAY(i) (lp[i])
    RY10(LAY)
#undef LAY
#pragma unroll
    for (int r = 0; r < 16; ++r) a[r] *= czs[r];
  }
  float p[16];
  float lt = 0.f;
#pragma unroll
  for (int r = 0; r < 16; ++r) { p[r] = a[r] * a[r]; lt += p[r]; }
  float z[10];
#pragma unroll
  for (int w = 0; w < 4; ++w) {
    float v = 0.f;
#pragma unroll
    for (int r = 0; r < 16; ++r) v += ((r >> w) & 1) ? -p[r] : p[r];
    z[w] = v;
  }
#pragma unroll
  for (int w = 4; w < 10; ++w) z[w] = ((lane >> (w - 4)) & 1) ? -lt : lt;
#pragma unroll
  for (int w = 0; w < 10; ++w) z[w] = wave_reduce_add(z[w]);
  if (lane == 0) {
#pragma unroll
    for (int w = 0; w < 10; ++w) qout[b * 10 + w] = z[w];
  }
}

// ---------------- post layers ------------------------------------------------
__global__ __launch_bounds__(256) void k_post(
    const float* __restrict__ qout, const float* __restrict__ w1,
    const float* __restrict__ b1, const float* __restrict__ w2,
    const float* __restrict__ b2, float* __restrict__ out) {
  const int b = blockIdx.x * 256 + threadIdx.x;
  float qv[10];
#pragma unroll
  for (int i = 0; i < 10; ++i) qv[i] = qout[b * 10 + i];
  float h[32];
#pragma unroll
  for (int jj = 0; jj < 32; ++jj) {
    float s = b1[jj];
#pragma unroll
    for (int i = 0; i < 10; ++i) s = fmaf(w1[jj * 10 + i], qv[i], s);
    h[jj] = fmaxf(s, 0.f);
  }
#pragma unroll
  for (int o = 0; o < 10; ++o) {
    float s = b2[o];
#pragma unroll
    for (int jj = 0; jj < 32; ++jj) s = fmaf(w2[o * 32 + jj], h[jj], s);
    out[b * 10 + o] = s;
  }
}

// ---------------------------------------------------------------------------
extern "C" void kernel_launch(void* const* d_in, const int* in_sizes, int n_in,
                              void* d_out, int out_size, void* d_ws, size_t ws_size,
                              hipStream_t stream) {
  (void)in_sizes; (void)n_in; (void)out_size; (void)ws_size;
  const float* x    = (const float*)d_in[0];
  const float* c1w  = (const float*)d_in[1];
  const float* c1b  = (const float*)d_in[2];
  const float* bn1g = (const float*)d_in[3];
  const float* bn1b = (const float*)d_in[4];
  const float* c2w  = (const float*)d_in[5];
  const float* c2b  = (const float*)d_in[6];
  const float* bn2g = (const float*)d_in[7];
  const float* bn2b = (const float*)d_in[8];
  const float* fc1w = (const float*)d_in[9];
  const float* fc1b = (const float*)d_in[10];
  const float* selw = (const float*)d_in[11];
  const float* selb = (const float*)d_in[12];
  const float* qpar = (const float*)d_in[13];
  const float* p1w  = (const float*)d_in[14];
  const float* p1b  = (const float*)d_in[15];
  const float* p2w  = (const float*)d_in[16];
  const float* p2b  = (const float*)d_in[17];

  // ws layout (floats), total = 22,442,080 f = 89,768,320 B (round-2-proven).
  // Aliases: Ap sits in h1bf (dead after conv2_mfma);
  //          wB (32*456 us = 7,296 f) sits at start of feats.
  float* ws = (float*)d_ws;
  ushort_t* h1bf = (ushort_t*)ws;
  ushort_t* Ap   = (ushort_t*)ws;           // alias
  size_t o = 6422528;
  float* raw    = ws + o; o += 12845056;    // [2048][196][32]
  ushort_t* Bp  = (ushort_t*)(ws + o); o += 1331200;
  float* feats  = ws + o; o += 1605632;
  ushort_t* wB  = (ushort_t*)feats;         // alias
  float* part1  = ws + o; o += 65536;
  float* part2  = ws + o; o += 131072;
  float* stats1 = ws + o; o += 32;
  float* stats2 = ws + o; o += 64;
  float* selv   = ws + o; o += 20480;
  float* qout   = ws + o; o += 20480;
  float* outp   = (float*)d_out;

  k_conv1_stats<<<BATCH + 1, 256, 0, stream>>>(x, c1w, c1b, part1, c2w, wB);
  k_bnstat<<<16, 256, 0, stream>>>(part1, bn1g, bn1b, stats1, 16, BATCH,
                                   1.0 / (2048.0 * 784.0));
  k_conv1_fused<<<BATCH, 256, 0, stream>>>(x, c1w, c1b, stats1, h1bf);
  k_conv2_mfma<<<BATCH / 2, 512, 0, stream>>>(h1bf, wB, c2b, part2, raw);
  k_bnstat<<<32, 256, 0, stream>>>(part2, bn2g, bn2b, stats2, 32, BATCH,
                                   1.0 / (2048.0 * 196.0));
  k_pack_a<<<BATCH, 256, 0, stream>>>(raw, stats2, Ap);
  k_pack_b<<<832, 256, 0, stream>>>(fc1w, Bp);
  k_fc1_mfma<<<416, 256, 0, stream>>>(Ap, Bp, fc1b, feats);
  k_sel<<<512, 256, 0, stream>>>(feats, selw, selb, selv);
  k_quantum<<<512, 256, 0, stream>>>(selv, qpar, qout);
  k_post<<<8, 256, 0, stream>>>(qout, p1w, p1b, p2w, p2b, outp);
}

// Round 5
// 161.616 us; speedup vs baseline: 1.3684x; 1.0286x over previous
//
#include <hip/hip_runtime.h>
#include <math.h>

// ---------------------------------------------------------------------------
// AngleEncodingQuantumNet: conv1+BN+relu+pool -> conv2+BN+relu+pool -> fc1
// (tanh) -> sel -> 10-qubit RY/CZ circuit -> post1(relu) -> post2.
// Train-mode BN => stats pass then apply pass.
// conv2 = MFMA over shift-sections (no im2col), 2 images/block, 8 waves.
// fc1 = bf16 MFMA, 2-way split A (K'=3200), R5: split-K=2 + 8-wave blocks
// (832 blocks = 26 waves/CU; was 6.5) + f32 partial combine w/ bias+tanh.
// Measured absmax 7.6e-6 (thr 3.8e-5).
// ---------------------------------------------------------------------------

#define BATCH 2048
#define PI_F 3.14159265358979323846f
#define KP 3200          // fc1 padded K' = 2*1568 -> 3200 (50 BK=64 steps)
#define KHALF 25         // K-steps per split-K block
#define BSTRIDE 456      // conv2 B' row stride (ushorts): 912B -> bank step 4

typedef unsigned short ushort_t;
typedef __attribute__((ext_vector_type(8))) short bf16x8;
typedef __attribute__((ext_vector_type(4))) float f32x4;

__device__ __forceinline__ float wave_reduce_add(float v) {
#pragma unroll
  for (int off = 32; off >= 1; off >>= 1) v += __shfl_xor(v, off, 64);
  return v;
}

__device__ __forceinline__ ushort_t f2bf(float v) {  // RNE f32 -> bf16 bits
  unsigned u = __float_as_uint(v);
  u += 0x7FFFu + ((u >> 16) & 1u);
  return (ushort_t)(u >> 16);
}
__device__ __forceinline__ float bf2f(ushort_t b) {
  return __uint_as_float(((unsigned)b) << 16);
}

// ---------------- conv1: stats pass (+ bonus block builds conv2 B') --------
__global__ __launch_bounds__(256) void k_conv1_stats(
    const float* __restrict__ x, const float* __restrict__ cw,
    const float* __restrict__ cb, float* __restrict__ part1,
    const float* __restrict__ cw2, ushort_t* __restrict__ wB) {
  const int t = threadIdx.x;
  if (blockIdx.x == BATCH) {
    // conv2 B': [oc][k'], k' = sec*16+ic, sec 0..26 = [Bh x9 | Bh x9 | Bl x9]
    for (int i = t; i < 32 * BSTRIDE; i += 256) {
      int oc = i / BSTRIDE, k = i - oc * BSTRIDE;
      ushort_t val = 0;
      if (k < 432) {
        int sec = k >> 4, ic = k & 15;
        int s = (sec >= 18) ? (sec - 18) : (sec >= 9 ? sec - 9 : sec);
        float w = cw2[oc * 144 + ic * 9 + s];
        if (sec < 18) val = f2bf(w);
        else val = f2bf(w - bf2f(f2bf(w)));
      }
      wB[i] = val;
    }
    return;
  }
  const int b = blockIdx.x;
  __shared__ float xs[30][33];
  __shared__ float ws[160];
  __shared__ float redS[16][28];
  __shared__ float redQ[16][28];
  for (int i = t; i < 30 * 33; i += 256) (&xs[0][0])[i] = 0.f;
  if (t < 144) ws[t] = cw[t];
  else if (t < 160) ws[t] = cb[t - 144];
  __syncthreads();
  const float* xb = x + b * 784;
  for (int i = t; i < 784; i += 256) xs[1 + i / 28][1 + (i % 28)] = xb[i];
  __syncthreads();
  for (int task = t; task < 448; task += 256) {
    const int oc = task / 28;
    const int row = task - oc * 28;
    float wk[9];
#pragma unroll
    for (int k = 0; k < 9; ++k) wk[k] = ws[oc * 9 + k];
    const float bc = ws[144 + oc];
    float A0 = xs[row][0], A1 = xs[row][1];
    float B0 = xs[row + 1][0], B1 = xs[row + 1][1];
    float C0 = xs[row + 2][0], C1 = xs[row + 2][1];
    float s = 0.f, q = 0.f;
#pragma unroll 4
    for (int xx = 0; xx < 28; ++xx) {
      float A2 = xs[row][xx + 2], B2 = xs[row + 1][xx + 2], C2 = xs[row + 2][xx + 2];
      float acc = bc;
      acc = fmaf(wk[0], A0, acc); acc = fmaf(wk[1], A1, acc); acc = fmaf(wk[2], A2, acc);
      acc = fmaf(wk[3], B0, acc); acc = fmaf(wk[4], B1, acc); acc = fmaf(wk[5], B2, acc);
      acc = fmaf(wk[6], C0, acc); acc = fmaf(wk[7], C1, acc); acc = fmaf(wk[8], C2, acc);
      s += acc; q = fmaf(acc, acc, q);
      A0 = A1; A1 = A2; B0 = B1; B1 = B2; C0 = C1; C1 = C2;
    }
    redS[oc][row] = s;
    redQ[oc][row] = q;
  }
  __syncthreads();
  if (t < 32) {
    const int c = t >> 1;
    float acc = 0.f;
    if (t & 1) {
#pragma unroll 4
      for (int r = 0; r < 28; ++r) acc += redQ[c][r];
    } else {
#pragma unroll 4
      for (int r = 0; r < 28; ++r) acc += redS[c][r];
    }
    part1[b * 32 + t] = acc;
  }
}

// ---------------- BN stats fold (both layers) -------------------------------
__global__ __launch_bounds__(256) void k_bnstat(
    const float* __restrict__ part, const float* __restrict__ g,
    const float* __restrict__ bb, float* __restrict__ stats,
    int nch, int nblk, double invN) {
  const int c = blockIdx.x;
  const int t = threadIdx.x;
  const int stride = nch * 2;
  double ls = 0.0, lq = 0.0;
  for (int i = t; i < nblk; i += 256) {
    ls += (double)part[i * stride + c * 2];
    lq += (double)part[i * stride + c * 2 + 1];
  }
#pragma unroll
  for (int off = 32; off >= 1; off >>= 1) {
    ls += __shfl_xor(ls, off, 64);
    lq += __shfl_xor(lq, off, 64);
  }
  __shared__ double rs[4], rq[4];
  if ((t & 63) == 0) { rs[t >> 6] = ls; rq[t >> 6] = lq; }
  __syncthreads();
  if (t == 0) {
    double S = rs[0] + rs[1] + rs[2] + rs[3];
    double Q = rq[0] + rq[1] + rq[2] + rq[3];
    double mean = S * invN;
    double var = Q * invN - mean * mean;
    double inv = 1.0 / sqrt(var + 1e-5);
    double sc = (double)g[c] * inv;
    stats[c * 2] = (float)sc;
    stats[c * 2 + 1] = (float)((double)bb[c] - mean * sc);
  }
}

// ---------------- conv1: fused BN+relu+pool, emits h1 as hi/lo bf16 ---------
// output layout: h1bf[b][plane][pixel=y*14+x][ic] ushort (6272/image)
__global__ __launch_bounds__(256) void k_conv1_fused(
    const float* __restrict__ x, const float* __restrict__ cw,
    const float* __restrict__ cb, const float* __restrict__ stats1,
    ushort_t* __restrict__ h1bf) {
  const int b = blockIdx.x;
  const int t = threadIdx.x;
  __shared__ float xs[30][33];
  __shared__ float ws[160];
  __shared__ __align__(16) ushort_t obuf[2 * 3136];
  for (int i = t; i < 30 * 33; i += 256) (&xs[0][0])[i] = 0.f;
  if (t < 144) ws[t] = cw[t];
  else if (t < 160) ws[t] = cb[t - 144];
  __syncthreads();
  const float* xb = x + b * 784;
  for (int i = t; i < 784; i += 256) xs[1 + i / 28][1 + (i % 28)] = xb[i];
  __syncthreads();
  if (t < 224) {
    const int oc = t / 14;
    const int pr = t - oc * 14;
    float wk[9];
#pragma unroll
    for (int k = 0; k < 9; ++k) wk[k] = ws[oc * 9 + k];
    const float bc = ws[144 + oc];
    const float scale = stats1[oc * 2], shift = stats1[oc * 2 + 1];
    const int r0 = 2 * pr;
    float A0 = xs[r0][0],     A1 = xs[r0][1];
    float B0 = xs[r0 + 1][0], B1 = xs[r0 + 1][1];
    float C0 = xs[r0 + 2][0], C1 = xs[r0 + 2][1];
    float D0 = xs[r0 + 3][0], D1 = xs[r0 + 3][1];
    float pmax = 0.f;
#pragma unroll 4
    for (int xx = 0; xx < 28; ++xx) {
      float A2 = xs[r0][xx + 2], B2 = xs[r0 + 1][xx + 2];
      float C2 = xs[r0 + 2][xx + 2], D2 = xs[r0 + 3][xx + 2];
      float c0 = bc, c1 = bc;
      c0 = fmaf(wk[0], A0, c0); c0 = fmaf(wk[1], A1, c0); c0 = fmaf(wk[2], A2, c0);
      c0 = fmaf(wk[3], B0, c0); c0 = fmaf(wk[4], B1, c0); c0 = fmaf(wk[5], B2, c0);
      c0 = fmaf(wk[6], C0, c0); c0 = fmaf(wk[7], C1, c0); c0 = fmaf(wk[8], C2, c0);
      c1 = fmaf(wk[0], B0, c1); c1 = fmaf(wk[1], B1, c1); c1 = fmaf(wk[2], B2, c1);
      c1 = fmaf(wk[3], C0, c1); c1 = fmaf(wk[4], C1, c1); c1 = fmaf(wk[5], C2, c1);
      c1 = fmaf(wk[6], D0, c1); c1 = fmaf(wk[7], D1, c1); c1 = fmaf(wk[8], D2, c1);
      float e0 = fmaxf(fmaf(scale, c0, shift), 0.f);
      float e1 = fmaxf(fmaf(scale, c1, shift), 0.f);
      float m = fmaxf(e0, e1);
      if ((xx & 1) == 0) {
        pmax = m;
      } else {
        float pv = fmaxf(pmax, m);
        ushort_t hi = f2bf(pv);
        ushort_t lo = f2bf(pv - bf2f(hi));
        int pidx = (pr * 14 + (xx >> 1)) * 16 + oc;
        obuf[pidx] = hi;
        obuf[3136 + pidx] = lo;
      }
      A0 = A1; A1 = A2; B0 = B1; B1 = B2; C0 = C1; C1 = C2; D0 = D1; D1 = D2;
    }
  }
  __syncthreads();
  uint4* dst = (uint4*)(h1bf + (size_t)b * 6272);
  const uint4* sob = (const uint4*)obuf;
  for (int i = t; i < 784; i += 256) dst[i] = sob[i];
}

// ---------------- conv2 via MFMA (shift-section K, no im2col) ---------------
// 2 images/block, 512 threads (waves 0-3 -> img0, 4-7 -> img1). A in LDS:
// [img][plane][pixel(16x16 padded)][24] (48B pixel stride -> 2-way banks);
// B [32][456]. A-frag = 1 ds_read_b128; 3x3 shift = address offset.
// K' = 27 sections ([AhBh 9][AlBh 9][AhBl 9]) -> 14 k-steps. Raw [b][196][32].
__global__ __launch_bounds__(512, 4) void k_conv2_mfma(
    const ushort_t* __restrict__ h1bf, const ushort_t* __restrict__ wB,
    const float* __restrict__ cb, float* __restrict__ part2,
    float* __restrict__ raw) {
  const int b0 = blockIdx.x * 2;
  const int t = threadIdx.x;
  __shared__ __align__(16) ushort_t aT[2 * 12288];   // 49,152 B
  __shared__ __align__(16) ushort_t bS[32 * BSTRIDE]; // 29,184 B
  __shared__ float red[2][4][64];                     //  2,048 B
  {
    uint4 z = make_uint4(0, 0, 0, 0);
    uint4* a4 = (uint4*)aT;
#pragma unroll
    for (int i = 0; i < 6; ++i) a4[t + i * 512] = z;  // 3072 uint4
    uint4* b4 = (uint4*)bS;
    const uint4* w4 = (const uint4*)wB;
    for (int i = t; i < (32 * BSTRIDE) / 8; i += 512) b4[i] = w4[i];
  }
  __syncthreads();
  {
    uint4* a4 = (uint4*)aT;
    const uint4* src = (const uint4*)(h1bf + (size_t)b0 * 6272);
    for (int i = t; i < 1568; i += 512) {
      int img = i / 784, j = i - img * 784;
      int plane = j / 392, jj = j - plane * 392;
      int pix = jj >> 1, half = jj & 1;
      int y = pix / 14, x = pix - y * 14;
      a4[img * 1536 + plane * 768 + ((y + 1) * 16 + (x + 1)) * 3 + half] =
          src[img * 784 + j];
    }
  }
  __syncthreads();

  const int lane = t & 63;
  const int wv = t >> 6;
  const int img = wv >> 2, wi = wv & 3;
  const int ic0 = ((lane >> 4) & 1) * 8;
  const int hb = lane >> 5;
  const int imgbase = img * 12288;
  int abase[4];
#pragma unroll
  for (int fi = 0; fi < 4; ++fi) {
    int f = wi + fi * 4;
    int p = f * 16 + (lane & 15);
    int pp = p < 196 ? p : 195;
    int y = pp / 14, x = pp - y * 14;
    abase[fi] = imgbase + (y * 16 + x) * 24 + ic0;
  }
  f32x4 acc[4][2];
  {
    const float bias0 = cb[lane & 15];
    const float bias1 = cb[16 + (lane & 15)];
#pragma unroll
    for (int fi = 0; fi < 4; ++fi) {
      acc[fi][0] = (f32x4){bias0, bias0, bias0, bias0};
      acc[fi][1] = (f32x4){bias1, bias1, bias1, bias1};
    }
  }
  const int kb = (lane & 15) * BSTRIDE + (lane >> 4) * 8;
#pragma unroll
  for (int kt = 0; kt < 14; ++kt) {
    bf16x8 bv0 = *(const bf16x8*)&bS[kb + kt * 32];
    bf16x8 bv1 = *(const bf16x8*)&bS[kb + 16 * BSTRIDE + kt * 32];
    int sec = 2 * kt + hb;
    int ss = sec >= 18 ? sec - 18 : (sec >= 9 ? sec - 9 : sec);
    if (ss > 8) ss = 8;  // sec==27: B is zero, A-read just stays in-bounds
    int plane = (sec >= 9 && sec < 18) ? 1 : 0;
    int dy = ss / 3, dx = ss - dy * 3;
    int doff = plane * 6144 + dy * 384 + dx * 24;
#pragma unroll
    for (int fi = 0; fi < 4; ++fi) {
      if (wi + fi * 4 < 13) {
        bf16x8 av = *(const bf16x8*)&aT[doff + abase[fi]];
        acc[fi][0] = __builtin_amdgcn_mfma_f32_16x16x32_bf16(av, bv0, acc[fi][0], 0, 0, 0);
        acc[fi][1] = __builtin_amdgcn_mfma_f32_16x16x32_bf16(av, bv1, acc[fi][1], 0, 0, 0);
      }
    }
  }
  // epilogue: raw store (oc innermost -> coalesced) + per-oc stats
  float s0 = 0.f, q0 = 0.f, s1 = 0.f, q1 = 0.f;
  float* rb = raw + (size_t)(b0 + img) * 6272;
#pragma unroll
  for (int fi = 0; fi < 4; ++fi) {
    int f = wi + fi * 4;
    if (f < 13) {
#pragma unroll
      for (int r = 0; r < 4; ++r) {
        int p = f * 16 + (lane >> 4) * 4 + r;
        if (p < 196) {
          float v0 = acc[fi][0][r], v1 = acc[fi][1][r];
          rb[p * 32 + (lane & 15)] = v0;
          rb[p * 32 + 16 + (lane & 15)] = v1;
          s0 += v0; q0 = fmaf(v0, v0, q0);
          s1 += v1; q1 = fmaf(v1, v1, q1);
        }
      }
    }
  }
  s0 += __shfl_xor(s0, 16, 64); s0 += __shfl_xor(s0, 32, 64);
  q0 += __shfl_xor(q0, 16, 64); q0 += __shfl_xor(q0, 32, 64);
  s1 += __shfl_xor(s1, 16, 64); s1 += __shfl_xor(s1, 32, 64);
  q1 += __shfl_xor(q1, 16, 64); q1 += __shfl_xor(q1, 32, 64);
  if (lane < 16) {
    red[img][wi][lane * 2] = s0;        red[img][wi][lane * 2 + 1] = q0;
    red[img][wi][(lane + 16) * 2] = s1; red[img][wi][(lane + 16) * 2 + 1] = q1;
  }
  __syncthreads();
  if (t < 128) {
    int im = t >> 6, c = t & 63;
    part2[(b0 + im) * 64 + c] =
        red[im][0][c] + red[im][1][c] + red[im][2][c] + red[im][3][c];
  }
}

// ---------------- pack A': BN+relu+pool from raw, then [Ah | Al] bf16 -------
// raw staged via LDS (coalesced float4 loads; [196][36] pad kills bank-0 hit)
__global__ __launch_bounds__(256) void k_pack_a(
    const float* __restrict__ raw, const float* __restrict__ stats2,
    ushort_t* __restrict__ Ap) {
  const int m = blockIdx.x, t = threadIdx.x;
  __shared__ float rL[196 * 36];
  __shared__ float hv[1568];
  {
    const float4* src = (const float4*)(raw + (size_t)m * 6272);
    for (int i = t; i < 1568; i += 256) {
      int pix = i >> 3, q = i & 7;
      *(float4*)&rL[pix * 36 + q * 4] = src[i];
    }
  }
  __syncthreads();
  for (int i = t; i < 1568; i += 256) {
    int oc = i / 49, r = i - oc * 49;
    int py = r / 7, px = r - py * 7;
    int base = (py * 28 + px * 2) * 36 + oc;
    float a = rL[base], bq = rL[base + 36], c = rL[base + 504], d = rL[base + 540];
    float mx = fmaxf(fmaxf(a, bq), fmaxf(c, d));
    float mn = fminf(fminf(a, bq), fminf(c, d));
    float sc = stats2[oc * 2], sh = stats2[oc * 2 + 1];
    hv[i] = fmaxf(fmaf(sc, (sc >= 0.f ? mx : mn), sh), 0.f);  // BN monotone
  }
  __syncthreads();
  ushort_t* ap = Ap + (size_t)m * KP;
  for (int c = t; c < KP / 8; c += 256) {
    union { ushort_t u[8]; uint4 v; } o;
    if (c < 196) {
#pragma unroll
      for (int j = 0; j < 8; ++j) o.u[j] = f2bf(hv[c * 8 + j]);
    } else if (c < 392) {
#pragma unroll
      for (int j = 0; j < 8; ++j) {
        float v = hv[(c - 196) * 8 + j];
        o.u[j] = f2bf(v - bf2f(f2bf(v)));
      }
    } else {
      o.v = make_uint4(0, 0, 0, 0);
    }
    *(uint4*)(ap + c * 8) = o.v;
  }
}

// ---------------- pack B': [Bh | Bh] bf16, rows padded to 832 ---------------
__global__ __launch_bounds__(256) void k_pack_b(
    const float* __restrict__ w, ushort_t* __restrict__ Bp) {
  const int n = blockIdx.x, t = threadIdx.x;
  ushort_t* bp = Bp + (size_t)n * KP;
  if (t < 196) {
    union { ushort_t u[8]; uint4 v; } o;
    o.v = make_uint4(0, 0, 0, 0);
    if (n < 784) {
      const float* wp = w + (size_t)n * 1568 + t * 8;
#pragma unroll
      for (int j = 0; j < 8; ++j) o.u[j] = f2bf(wp[j]);
    }
    *(uint4*)(bp + t * 8) = o.v;
    *(uint4*)(bp + 1568 + t * 8) = o.v;
  } else if (t < 204) {
    *(uint4*)(bp + 3136 + (t - 196) * 8) = make_uint4(0, 0, 0, 0);
  }
}

// ---------------- fc1 as bf16 MFMA GEMM, split-K=2 -> f32 partials ----------
// 64x64 tile, 8 waves (512 thr), wave-tile 16x32 (1 A-frag x 2 B-frags).
// grid = 832: tid = id%416 (XCD-swizzled), ks = id/416 selects 25 K-steps.
// partial[((ks*32+mt)*64+row)*832 + col].
__global__ __launch_bounds__(512) void k_fc1_mfma(
    const ushort_t* __restrict__ Ap, const ushort_t* __restrict__ Bp,
    float* __restrict__ partial) {
  __shared__ ushort_t As[64 * 64];
  __shared__ ushort_t Bs[64 * 64];
  const int t = threadIdx.x;
  const int id = blockIdx.x;
  const int tid = id & 415 ? id % 416 : id % 416;  // id%416
  const int ks = id / 416;
  const int swz = (tid & 7) * 52 + (tid >> 3);  // 416 = 8*52: XCD-contig
  const int mt = swz & 31, nt = swz >> 5;
  const int m0 = mt * 64, n0 = nt * 64;
  const int lane = t & 63, wid = t >> 6;
  const int wm = wid >> 1, wn = wid & 1;      // 4x2 wave grid, tile 16x32

  const int srow = t >> 3, sslot = t & 7;     // 512 thr: 1 uint4/matrix each
  const int xsl = (sslot ^ (srow & 7)) << 3;
  ushort_t* awp = &As[srow * 64 + xsl];
  ushort_t* bwp = &Bs[srow * 64 + xsl];
  const uint4* agp = (const uint4*)(Ap + (size_t)(m0 + srow) * KP) + sslot;
  const uint4* bgp = (const uint4*)(Bp + (size_t)(n0 + srow) * KP) + sslot;

  const int rbaseA = (wm * 16 + (lane & 15)) * 64;
  const int rbaseB = (wn * 32 + (lane & 15)) * 64;
  const int x0 = (((lane >> 4) + 0) ^ (lane & 7)) << 3;
  const int x1 = (((lane >> 4) + 4) ^ (lane & 7)) << 3;

  f32x4 acc0 = {0.f, 0.f, 0.f, 0.f};
  f32x4 acc1 = acc0;

  const int kt0 = ks * KHALF;
  uint4 ca = agp[kt0 * 8], cb = bgp[kt0 * 8];
  for (int kt = kt0; kt < kt0 + KHALF; ++kt) {
    __syncthreads();
    *(uint4*)awp = ca;
    *(uint4*)bwp = cb;
    __syncthreads();
    uint4 na = ca, nb = cb;
    if (kt < kt0 + KHALF - 1) {  // prefetch next K-tile
      na = agp[(kt + 1) * 8];
      nb = bgp[(kt + 1) * 8];
    }
    {
      bf16x8 a0 = *(const bf16x8*)&As[rbaseA + x0];
      bf16x8 b0 = *(const bf16x8*)&Bs[rbaseB + x0];
      bf16x8 b1 = *(const bf16x8*)&Bs[rbaseB + 1024 + x0];
      acc0 = __builtin_amdgcn_mfma_f32_16x16x32_bf16(a0, b0, acc0, 0, 0, 0);
      acc1 = __builtin_amdgcn_mfma_f32_16x16x32_bf16(a0, b1, acc1, 0, 0, 0);
    }
    {
      bf16x8 a0 = *(const bf16x8*)&As[rbaseA + x1];
      bf16x8 b0 = *(const bf16x8*)&Bs[rbaseB + x1];
      bf16x8 b1 = *(const bf16x8*)&Bs[rbaseB + 1024 + x1];
      acc0 = __builtin_amdgcn_mfma_f32_16x16x32_bf16(a0, b0, acc0, 0, 0, 0);
      acc1 = __builtin_amdgcn_mfma_f32_16x16x32_bf16(a0, b1, acc1, 0, 0, 0);
    }
    ca = na; cb = nb;
  }

  // C/D: col=lane&15, row=(lane>>4)*4+reg [m89]
  const int rowb = wm * 16 + ((lane >> 4) << 2);
  const int colb = n0 + wn * 32 + (lane & 15);
  float* pb = partial + ((size_t)(ks * 32 + mt) * 64 + rowb) * 832 + colb;
#pragma unroll
  for (int r = 0; r < 4; ++r) {
    pb[r * 832] = acc0[r];
    pb[r * 832 + 16] = acc1[r];
  }
}

// ---------------- fc1 combine: sum 2 partials + bias + tanh -> feats --------
__global__ __launch_bounds__(256) void k_fc1_combine(
    const float* __restrict__ partial, const float* __restrict__ bias,
    float* __restrict__ feats) {
  const int m = blockIdx.x;
  const int t = threadIdx.x;
  const int mt = m >> 6, r = m & 63;
  const float* p0 = partial + ((size_t)mt * 64 + r) * 832;
  const float* p1 = p0 + (size_t)32 * 64 * 832;
  float* fo = feats + (size_t)m * 784;
  for (int c = t; c < 784; c += 256)
    fo[c] = tanhf(p0[c] + p1[c] + bias[c]);
}

// ---------------- sel: feats[2048][784] @ sel_w[10][784]^T + b --------------
__global__ __launch_bounds__(256) void k_sel(
    const float* __restrict__ feats, const float* __restrict__ sw,
    const float* __restrict__ sb, float* __restrict__ selv) {
  const int wid = (blockIdx.x << 2) + (threadIdx.x >> 6);
  const int lane = threadIdx.x & 63;
  const float* f = feats + (size_t)wid * 784;
  float acc[10];
#pragma unroll
  for (int i = 0; i < 10; ++i) acc[i] = 0.f;
  for (int k = lane; k < 784; k += 64) {
    const float fv = f[k];
#pragma unroll
    for (int i = 0; i < 10; ++i) acc[i] = fmaf(fv, sw[i * 784 + k], acc[i]);
  }
#pragma unroll
  for (int i = 0; i < 10; ++i) acc[i] = wave_reduce_add(acc[i]);
  if (lane == 0) {
#pragma unroll
    for (int i = 0; i < 10; ++i) selv[wid * 10 + i] = acc[i] + sb[i];
  }
}

// ---------------- 10-qubit statevector circuit ------------------------------
template <int W>
__device__ __forceinline__ void ry_gate(float (&a)[16], int lane, float th) {
  float s, c;
  sincosf(0.5f * th, &s, &c);
  if (W < 4) {
    const int st = 1 << W;
#pragma unroll
    for (int r = 0; r < 16; ++r) {
      if (!(r & st)) {
        float lo = a[r], hi = a[r + st];
        a[r] = fmaf(c, lo, -s * hi);
        a[r + st] = fmaf(s, lo, c * hi);
      }
    }
  } else {
    const int m = 1 << (W - 4);
    const float sg = (lane & m) ? s : -s;
#pragma unroll
    for (int r = 0; r < 16; ++r) {
      float other = __shfl_xor(a[r], m, 64);
      a[r] = fmaf(c, a[r], sg * other);
    }
  }
}

#define RY10(EXPR)                                                   \
  {                                                                  \
    ry_gate<0>(a, lane, EXPR(0)); ry_gate<1>(a, lane, EXPR(1));      \
    ry_gate<2>(a, lane, EXPR(2)); ry_gate<3>(a, lane, EXPR(3));      \
    ry_gate<4>(a, lane, EXPR(4)); ry_gate<5>(a, lane, EXPR(5));      \
    ry_gate<6>(a, lane, EXPR(6)); ry_gate<7>(a, lane, EXPR(7));      \
    ry_gate<8>(a, lane, EXPR(8)); ry_gate<9>(a, lane, EXPR(9));      \
  }

__global__ __launch_bounds__(256) void k_quantum(
    const float* __restrict__ selv, const float* __restrict__ qp,
    float* __restrict__ qout) {
  const int b = (blockIdx.x << 2) + (threadIdx.x >> 6);
  const int lane = threadIdx.x & 63;
  float a[16];
#pragma unroll
  for (int r = 0; r < 16; ++r) a[r] = 0.f;
  if (lane == 0) a[0] = 1.f;
  float czs[16];
#pragma unroll
  for (int r = 0; r < 16; ++r) {
    int idx = (lane << 4) | r;
    czs[r] = (__popc(idx & (idx >> 1)) & 1) ? -1.f : 1.f;
  }
  const float* sp = selv + b * 10;
#define ENC(i) (sp[i] * PI_F)
  RY10(ENC)
#undef ENC
  for (int layer = 0; layer < 3; ++layer) {
    const float* lp = qp + layer * 10;
#define LAY(i) (lp[i])
    RY10(LAY)
#undef LAY
#pragma unroll
    for (int r = 0; r < 16; ++r) a[r] *= czs[r];
  }
  float p[16];
  float lt = 0.f;
#pragma unroll
  for (int r = 0; r < 16; ++r) { p[r] = a[r] * a[r]; lt += p[r]; }
  float z[10];
#pragma unroll
  for (int w = 0; w < 4; ++w) {
    float v = 0.f;
#pragma unroll
    for (int r = 0; r < 16; ++r) v += ((r >> w) & 1) ? -p[r] : p[r];
    z[w] = v;
  }
#pragma unroll
  for (int w = 4; w < 10; ++w) z[w] = ((lane >> (w - 4)) & 1) ? -lt : lt;
#pragma unroll
  for (int w = 0; w < 10; ++w) z[w] = wave_reduce_add(z[w]);
  if (lane == 0) {
#pragma unroll
    for (int w = 0; w < 10; ++w) qout[b * 10 + w] = z[w];
  }
}

// ---------------- post layers ------------------------------------------------
__global__ __launch_bounds__(256) void k_post(
    const float* __restrict__ qout, const float* __restrict__ w1,
    const float* __restrict__ b1, const float* __restrict__ w2,
    const float* __restrict__ b2, float* __restrict__ out) {
  const int b = blockIdx.x * 256 + threadIdx.x;
  float qv[10];
#pragma unroll
  for (int i = 0; i < 10; ++i) qv[i] = qout[b * 10 + i];
  float h[32];
#pragma unroll
  for (int jj = 0; jj < 32; ++jj) {
    float s = b1[jj];
#pragma unroll
    for (int i = 0; i < 10; ++i) s = fmaf(w1[jj * 10 + i], qv[i], s);
    h[jj] = fmaxf(s, 0.f);
  }
#pragma unroll
  for (int o = 0; o < 10; ++o) {
    float s = b2[o];
#pragma unroll
    for (int jj = 0; jj < 32; ++jj) s = fmaf(w2[o * 32 + jj], h[jj], s);
    out[b * 10 + o] = s;
  }
}

// ---------------------------------------------------------------------------
extern "C" void kernel_launch(void* const* d_in, const int* in_sizes, int n_in,
                              void* d_out, int out_size, void* d_ws, size_t ws_size,
                              hipStream_t stream) {
  (void)in_sizes; (void)n_in; (void)out_size; (void)ws_size;
  const float* x    = (const float*)d_in[0];
  const float* c1w  = (const float*)d_in[1];
  const float* c1b  = (const float*)d_in[2];
  const float* bn1g = (const float*)d_in[3];
  const float* bn1b = (const float*)d_in[4];
  const float* c2w  = (const float*)d_in[5];
  const float* c2b  = (const float*)d_in[6];
  const float* bn2g = (const float*)d_in[7];
  const float* bn2b = (const float*)d_in[8];
  const float* fc1w = (const float*)d_in[9];
  const float* fc1b = (const float*)d_in[10];
  const float* selw = (const float*)d_in[11];
  const float* selb = (const float*)d_in[12];
  const float* qpar = (const float*)d_in[13];
  const float* p1w  = (const float*)d_in[14];
  const float* p1b  = (const float*)d_in[15];
  const float* p2w  = (const float*)d_in[16];
  const float* p2b  = (const float*)d_in[17];

  // ws layout (floats), total = 22,442,080 f = 89,768,320 B (round-2-proven).
  // Aliases: Ap sits in h1bf (dead after conv2_mfma); wB at start of feats;
  //          fc1 partial (3,407,872 f) reuses raw (dead after pack_a).
  float* ws = (float*)d_ws;
  ushort_t* h1bf = (ushort_t*)ws;
  ushort_t* Ap   = (ushort_t*)ws;           // alias
  size_t o = 6422528;
  float* raw    = ws + o; o += 12845056;    // [2048][196][32]
  float* partial = raw;                     // alias (fc1 split-K partials)
  ushort_t* Bp  = (ushort_t*)(ws + o); o += 1331200;
  float* feats  = ws + o; o += 1605632;
  ushort_t* wB  = (ushort_t*)feats;         // alias
  float* part1  = ws + o; o += 65536;
  float* part2  = ws + o; o += 131072;
  float* stats1 = ws + o; o += 32;
  float* stats2 = ws + o; o += 64;
  float* selv   = ws + o; o += 20480;
  float* qout   = ws + o; o += 20480;
  float* outp   = (float*)d_out;

  k_conv1_stats<<<BATCH + 1, 256, 0, stream>>>(x, c1w, c1b, part1, c2w, wB);
  k_bnstat<<<16, 256, 0, stream>>>(part1, bn1g, bn1b, stats1, 16, BATCH,
                                   1.0 / (2048.0 * 784.0));
  k_conv1_fused<<<BATCH, 256, 0, stream>>>(x, c1w, c1b, stats1, h1bf);
  k_conv2_mfma<<<BATCH / 2, 512, 0, stream>>>(h1bf, wB, c2b, part2, raw);
  k_bnstat<<<32, 256, 0, stream>>>(part2, bn2g, bn2b, stats2, 32, BATCH,
                                   1.0 / (2048.0 * 196.0));
  k_pack_a<<<BATCH, 256, 0, stream>>>(raw, stats2, Ap);
  k_pack_b<<<832, 256, 0, stream>>>(fc1w, Bp);
  k_fc1_mfma<<<832, 512, 0, stream>>>(Ap, Bp, partial);
  k_fc1_combine<<<BATCH, 256, 0, stream>>>(partial, fc1b, feats);
  k_sel<<<512, 256, 0, stream>>>(feats, selw, selb, selv);
  k_quantum<<<512, 256, 0, stream>>>(selv, qpar, qout);
  k_post<<<8, 256, 0, stream>>>(qout, p1w, p1b, p2w, p2b, outp);
}

// Round 7
// 136.443 us; speedup vs baseline: 1.6209x; 1.1845x over previous
//
#include <hip/hip_runtime.h>
#include <math.h>

// ---------------------------------------------------------------------------
// AngleEncodingQuantumNet: conv1+BN+relu+pool -> conv2+BN+relu+pool -> fc1
// (tanh) -> sel -> 10-qubit RY/CZ circuit -> post1(relu) -> post2.
// Train-mode BN => stats pass then apply pass.
// R7 = R6 with the conv2 A-read base fixed (was shifted by (+1,+1): the +1
// belongs on the store side only — reads are (y*16+x)*24 + shift offset).
// conv2 emits in-lane-pooled max/min (quad-major fragment rows); fc1 =
// 128x128-tile bf16 MFMA split-K=4 with XCD-resident A stripes; tail
// (combine+sel+quantum+post) fused. fc1 2-way split A: absmax 7.6e-6.
// ---------------------------------------------------------------------------

#define BATCH 2048
#define PI_F 3.14159265358979323846f
#define KP 3328          // fc1 padded K' = 2*1568 -> 3328 (52 BK=64 steps)
#define KQ 13            // K-steps per split-K quarter
#define BSTRIDE 456      // conv2 B' row stride (ushorts): 912B -> bank step 4

typedef unsigned short ushort_t;
typedef __attribute__((ext_vector_type(8))) short bf16x8;
typedef __attribute__((ext_vector_type(4))) float f32x4;

__device__ __forceinline__ float wave_reduce_add(float v) {
#pragma unroll
  for (int off = 32; off >= 1; off >>= 1) v += __shfl_xor(v, off, 64);
  return v;
}

__device__ __forceinline__ ushort_t f2bf(float v) {  // RNE f32 -> bf16 bits
  unsigned u = __float_as_uint(v);
  u += 0x7FFFu + ((u >> 16) & 1u);
  return (ushort_t)(u >> 16);
}
__device__ __forceinline__ float bf2f(ushort_t b) {
  return __uint_as_float(((unsigned)b) << 16);
}

// ---------------- conv1: stats pass (+ bonus blocks: conv2 B', fc1 B') -----
__global__ __launch_bounds__(256) void k_conv1_stats(
    const float* __restrict__ x, const float* __restrict__ cw,
    const float* __restrict__ cb, float* __restrict__ part1,
    const float* __restrict__ cw2, ushort_t* __restrict__ wB,
    const float* __restrict__ fc1w, ushort_t* __restrict__ Bp) {
  const int t = threadIdx.x;
  if (blockIdx.x >= BATCH) {
    const int bid = blockIdx.x - BATCH;
    if (bid == 0) {
      // conv2 B': [oc][k'], k'=sec*16+ic, sec 0..26 = [Bh x9 | Bh x9 | Bl x9]
      for (int i = t; i < 32 * BSTRIDE; i += 256) {
        int oc = i / BSTRIDE, k = i - oc * BSTRIDE;
        ushort_t val = 0;
        if (k < 432) {
          int sec = k >> 4, ic = k & 15;
          int s = (sec >= 18) ? (sec - 18) : (sec >= 9 ? sec - 9 : sec);
          float w = cw2[oc * 144 + ic * 9 + s];
          if (sec < 18) val = f2bf(w);
          else val = f2bf(w - bf2f(f2bf(w)));
        }
        wB[i] = val;
      }
    } else {
      // fc1 B': [Bh | Bh] bf16, 896 rows x KP (rows>=784 and tail zeros)
      const int rb = (bid - 1) * 8;
      for (int i = t; i < 8 * (KP / 8); i += 256) {
        int rr = i / (KP / 8), c = i - rr * (KP / 8);
        int n = rb + rr;
        union { ushort_t u[8]; uint4 v; } o;
        o.v = make_uint4(0, 0, 0, 0);
        if (n < 784 && c < 392) {
          int cc = c < 196 ? c : c - 196;
          const float* wp = fc1w + (size_t)n * 1568 + cc * 8;
#pragma unroll
          for (int j = 0; j < 8; ++j) o.u[j] = f2bf(wp[j]);
        }
        ((uint4*)(Bp + (size_t)n * KP))[c] = o.v;
      }
    }
    return;
  }
  const int b = blockIdx.x;
  __shared__ float xs[30][33];
  __shared__ float ws[160];
  __shared__ float redS[16][28];
  __shared__ float redQ[16][28];
  for (int i = t; i < 30 * 33; i += 256) (&xs[0][0])[i] = 0.f;
  if (t < 144) ws[t] = cw[t];
  else if (t < 160) ws[t] = cb[t - 144];
  __syncthreads();
  const float* xb = x + b * 784;
  for (int i = t; i < 784; i += 256) xs[1 + i / 28][1 + (i % 28)] = xb[i];
  __syncthreads();
  for (int task = t; task < 448; task += 256) {
    const int oc = task / 28;
    const int row = task - oc * 28;
    float wk[9];
#pragma unroll
    for (int k = 0; k < 9; ++k) wk[k] = ws[oc * 9 + k];
    const float bc = ws[144 + oc];
    float A0 = xs[row][0], A1 = xs[row][1];
    float B0 = xs[row + 1][0], B1 = xs[row + 1][1];
    float C0 = xs[row + 2][0], C1 = xs[row + 2][1];
    float s = 0.f, q = 0.f;
#pragma unroll 4
    for (int xx = 0; xx < 28; ++xx) {
      float A2 = xs[row][xx + 2], B2 = xs[row + 1][xx + 2], C2 = xs[row + 2][xx + 2];
      float acc = bc;
      acc = fmaf(wk[0], A0, acc); acc = fmaf(wk[1], A1, acc); acc = fmaf(wk[2], A2, acc);
      acc = fmaf(wk[3], B0, acc); acc = fmaf(wk[4], B1, acc); acc = fmaf(wk[5], B2, acc);
      acc = fmaf(wk[6], C0, acc); acc = fmaf(wk[7], C1, acc); acc = fmaf(wk[8], C2, acc);
      s += acc; q = fmaf(acc, acc, q);
      A0 = A1; A1 = A2; B0 = B1; B1 = B2; C0 = C1; C1 = C2;
    }
    redS[oc][row] = s;
    redQ[oc][row] = q;
  }
  __syncthreads();
  if (t < 32) {
    const int c = t >> 1;
    float acc = 0.f;
    if (t & 1) {
#pragma unroll 4
      for (int r = 0; r < 28; ++r) acc += redQ[c][r];
    } else {
#pragma unroll 4
      for (int r = 0; r < 28; ++r) acc += redS[c][r];
    }
    part1[b * 32 + t] = acc;
  }
}

// ---------------- BN stats fold (both layers) -------------------------------
__global__ __launch_bounds__(256) void k_bnstat(
    const float* __restrict__ part, const float* __restrict__ g,
    const float* __restrict__ bb, float* __restrict__ stats,
    int nch, int nblk, double invN) {
  const int c = blockIdx.x;
  const int t = threadIdx.x;
  const int stride = nch * 2;
  double ls = 0.0, lq = 0.0;
  for (int i = t; i < nblk; i += 256) {
    ls += (double)part[i * stride + c * 2];
    lq += (double)part[i * stride + c * 2 + 1];
  }
#pragma unroll
  for (int off = 32; off >= 1; off >>= 1) {
    ls += __shfl_xor(ls, off, 64);
    lq += __shfl_xor(lq, off, 64);
  }
  __shared__ double rs[4], rq[4];
  if ((t & 63) == 0) { rs[t >> 6] = ls; rq[t >> 6] = lq; }
  __syncthreads();
  if (t == 0) {
    double S = rs[0] + rs[1] + rs[2] + rs[3];
    double Q = rq[0] + rq[1] + rq[2] + rq[3];
    double mean = S * invN;
    double var = Q * invN - mean * mean;
    double inv = 1.0 / sqrt(var + 1e-5);
    double sc = (double)g[c] * inv;
    stats[c * 2] = (float)sc;
    stats[c * 2 + 1] = (float)((double)bb[c] - mean * sc);
  }
}

// ---------------- conv1: fused BN+relu+pool, emits h1 as hi/lo bf16 ---------
// output layout: h1bf[b][plane][pixel=y*14+x][ic] ushort (6272/image)
__global__ __launch_bounds__(256) void k_conv1_fused(
    const float* __restrict__ x, const float* __restrict__ cw,
    const float* __restrict__ cb, const float* __restrict__ stats1,
    ushort_t* __restrict__ h1bf) {
  const int b = blockIdx.x;
  const int t = threadIdx.x;
  __shared__ float xs[30][33];
  __shared__ float ws[160];
  __shared__ __align__(16) ushort_t obuf[2 * 3136];
  for (int i = t; i < 30 * 33; i += 256) (&xs[0][0])[i] = 0.f;
  if (t < 144) ws[t] = cw[t];
  else if (t < 160) ws[t] = cb[t - 144];
  __syncthreads();
  const float* xb = x + b * 784;
  for (int i = t; i < 784; i += 256) xs[1 + i / 28][1 + (i % 28)] = xb[i];
  __syncthreads();
  if (t < 224) {
    const int oc = t / 14;
    const int pr = t - oc * 14;
    float wk[9];
#pragma unroll
    for (int k = 0; k < 9; ++k) wk[k] = ws[oc * 9 + k];
    const float bc = ws[144 + oc];
    const float scale = stats1[oc * 2], shift = stats1[oc * 2 + 1];
    const int r0 = 2 * pr;
    float A0 = xs[r0][0],     A1 = xs[r0][1];
    float B0 = xs[r0 + 1][0], B1 = xs[r0 + 1][1];
    float C0 = xs[r0 + 2][0], C1 = xs[r0 + 2][1];
    float D0 = xs[r0 + 3][0], D1 = xs[r0 + 3][1];
    float pmax = 0.f;
#pragma unroll 4
    for (int xx = 0; xx < 28; ++xx) {
      float A2 = xs[r0][xx + 2], B2 = xs[r0 + 1][xx + 2];
      float C2 = xs[r0 + 2][xx + 2], D2 = xs[r0 + 3][xx + 2];
      float c0 = bc, c1 = bc;
      c0 = fmaf(wk[0], A0, c0); c0 = fmaf(wk[1], A1, c0); c0 = fmaf(wk[2], A2, c0);
      c0 = fmaf(wk[3], B0, c0); c0 = fmaf(wk[4], B1, c0); c0 = fmaf(wk[5], B2, c0);
      c0 = fmaf(wk[6], C0, c0); c0 = fmaf(wk[7], C1, c0); c0 = fmaf(wk[8], C2, c0);
      c1 = fmaf(wk[0], B0, c1); c1 = fmaf(wk[1], B1, c1); c1 = fmaf(wk[2], B2, c1);
      c1 = fmaf(wk[3], C0, c1); c1 = fmaf(wk[4], C1, c1); c1 = fmaf(wk[5], C2, c1);
      c1 = fmaf(wk[6], D0, c1); c1 = fmaf(wk[7], D1, c1); c1 = fmaf(wk[8], D2, c1);
      float e0 = fmaxf(fmaf(scale, c0, shift), 0.f);
      float e1 = fmaxf(fmaf(scale, c1, shift), 0.f);
      float m = fmaxf(e0, e1);
      if ((xx & 1) == 0) {
        pmax = m;
      } else {
        float pv = fmaxf(pmax, m);
        ushort_t hi = f2bf(pv);
        ushort_t lo = f2bf(pv - bf2f(hi));
        int pidx = (pr * 14 + (xx >> 1)) * 16 + oc;
        obuf[pidx] = hi;
        obuf[3136 + pidx] = lo;
      }
      A0 = A1; A1 = A2; B0 = B1; B1 = B2; C0 = C1; C1 = C2; D0 = D1; D1 = D2;
    }
  }
  __syncthreads();
  uint4* dst = (uint4*)(h1bf + (size_t)b * 6272);
  const uint4* sob = (const uint4*)obuf;
  for (int i = t; i < 784; i += 256) dst[i] = sob[i];
}

// ---------------- conv2 via MFMA, in-lane 2x2 pooled output -----------------
// 2 images/block, 512 threads. A rows are QUAD-MAJOR: p' = quad*4+corner, so
// each fragment's 4-row group (lane>>4 quadrant) is exactly one pool quad ->
// pooled max/min = max4/min4(acc) in-lane. Output pooled[b][{max,min}][49][32].
// A-read base = (y*16+x)*24 (output coords; image stored at +1,+1 — the
// shift offset doff supplies dy,dx). NO +1 here (R6 bug).
__global__ __launch_bounds__(512, 4) void k_conv2_mfma(
    const ushort_t* __restrict__ h1bf, const ushort_t* __restrict__ wB,
    const float* __restrict__ cb, float* __restrict__ part2,
    float* __restrict__ pooled) {
  const int b0 = blockIdx.x * 2;
  const int t = threadIdx.x;
  __shared__ __align__(16) ushort_t aT[2 * 12288];   // 49,152 B
  __shared__ __align__(16) ushort_t bS[32 * BSTRIDE]; // 29,184 B
  __shared__ float red[2][4][64];                     //  2,048 B
  {
    uint4 z = make_uint4(0, 0, 0, 0);
    uint4* a4 = (uint4*)aT;
#pragma unroll
    for (int i = 0; i < 6; ++i) a4[t + i * 512] = z;
    uint4* b4 = (uint4*)bS;
    const uint4* w4 = (const uint4*)wB;
    for (int i = t; i < (32 * BSTRIDE) / 8; i += 512) b4[i] = w4[i];
  }
  __syncthreads();
  {
    uint4* a4 = (uint4*)aT;
    const uint4* src = (const uint4*)(h1bf + (size_t)b0 * 6272);
    for (int i = t; i < 1568; i += 512) {
      int img = i / 784, j = i - img * 784;
      int plane = j / 392, jj = j - plane * 392;
      int pix = jj >> 1, half = jj & 1;
      int y = pix / 14, x = pix - y * 14;
      a4[img * 1536 + plane * 768 + ((y + 1) * 16 + (x + 1)) * 3 + half] =
          src[img * 784 + j];
    }
  }
  __syncthreads();

  const int lane = t & 63;
  const int wv = t >> 6;
  const int img = wv >> 2, wi = wv & 3;
  const int ic0 = ((lane >> 4) & 1) * 8;
  const int hb = lane >> 5;
  const int imgbase = img * 12288;
  int abase[4];
#pragma unroll
  for (int fi = 0; fi < 4; ++fi) {
    int f = wi + fi * 4;
    int pp = f * 16 + (lane & 15);       // quad-major row index
    int quad = pp >> 2;
    if (quad > 48) quad = 48;            // clamp: keeps A-read in-bounds
    int corner = pp & 3;
    int qy = quad / 7, qx = quad - qy * 7;
    int y = 2 * qy + (corner >> 1), x = 2 * qx + (corner & 1);
    abase[fi] = imgbase + (y * 16 + x) * 24 + ic0;   // output coords, no +1
  }
  f32x4 acc[4][2];
  {
    const float bias0 = cb[lane & 15];
    const float bias1 = cb[16 + (lane & 15)];
#pragma unroll
    for (int fi = 0; fi < 4; ++fi) {
      acc[fi][0] = (f32x4){bias0, bias0, bias0, bias0};
      acc[fi][1] = (f32x4){bias1, bias1, bias1, bias1};
    }
  }
  const int kb = (lane & 15) * BSTRIDE + (lane >> 4) * 8;
#pragma unroll
  for (int kt = 0; kt < 14; ++kt) {
    bf16x8 bv0 = *(const bf16x8*)&bS[kb + kt * 32];
    bf16x8 bv1 = *(const bf16x8*)&bS[kb + 16 * BSTRIDE + kt * 32];
    int sec = 2 * kt + hb;
    int ss = sec >= 18 ? sec - 18 : (sec >= 9 ? sec - 9 : sec);
    if (ss > 8) ss = 8;  // sec==27: B is zero
    int plane = (sec >= 9 && sec < 18) ? 1 : 0;
    int dy = ss / 3, dx = ss - dy * 3;
    int doff = plane * 6144 + dy * 384 + dx * 24;
#pragma unroll
    for (int fi = 0; fi < 4; ++fi) {
      if (wi + fi * 4 < 13) {
        bf16x8 av = *(const bf16x8*)&aT[doff + abase[fi]];
        acc[fi][0] = __builtin_amdgcn_mfma_f32_16x16x32_bf16(av, bv0, acc[fi][0], 0, 0, 0);
        acc[fi][1] = __builtin_amdgcn_mfma_f32_16x16x32_bf16(av, bv1, acc[fi][1], 0, 0, 0);
      }
    }
  }
  // epilogue: in-lane 2x2 pool (fragment 4-row group == one quad) + stats
  float s0 = 0.f, q0 = 0.f, s1 = 0.f, q1 = 0.f;
  float* pm = pooled + (size_t)(b0 + img) * 3136;
#pragma unroll
  for (int fi = 0; fi < 4; ++fi) {
    int f = wi + fi * 4;
    int quad = f * 4 + (lane >> 4);
    if (quad < 49) {
      f32x4 a0 = acc[fi][0], a1 = acc[fi][1];
#pragma unroll
      for (int r = 0; r < 4; ++r) {
        s0 += a0[r]; q0 = fmaf(a0[r], a0[r], q0);
        s1 += a1[r]; q1 = fmaf(a1[r], a1[r], q1);
      }
      float mx0 = fmaxf(fmaxf(a0[0], a0[1]), fmaxf(a0[2], a0[3]));
      float mn0 = fminf(fminf(a0[0], a0[1]), fminf(a0[2], a0[3]));
      float mx1 = fmaxf(fmaxf(a1[0], a1[1]), fmaxf(a1[2], a1[3]));
      float mn1 = fminf(fminf(a1[0], a1[1]), fminf(a1[2], a1[3]));
      pm[quad * 32 + (lane & 15)] = mx0;
      pm[quad * 32 + 16 + (lane & 15)] = mx1;
      pm[1568 + quad * 32 + (lane & 15)] = mn0;
      pm[1568 + quad * 32 + 16 + (lane & 15)] = mn1;
    }
  }
  s0 += __shfl_xor(s0, 16, 64); s0 += __shfl_xor(s0, 32, 64);
  q0 += __shfl_xor(q0, 16, 64); q0 += __shfl_xor(q0, 32, 64);
  s1 += __shfl_xor(s1, 16, 64); s1 += __shfl_xor(s1, 32, 64);
  q1 += __shfl_xor(q1, 16, 64); q1 += __shfl_xor(q1, 32, 64);
  if (lane < 16) {
    red[img][wi][lane * 2] = s0;        red[img][wi][lane * 2 + 1] = q0;
    red[img][wi][(lane + 16) * 2] = s1; red[img][wi][(lane + 16) * 2 + 1] = q1;
  }
  __syncthreads();
  if (t < 128) {
    int im = t >> 6, c = t & 63;
    part2[(b0 + im) * 64 + c] =
        red[im][0][c] + red[im][1][c] + red[im][2][c] + red[im][3][c];
  }
}

// ---------------- pack A': BN+relu from pooled max/min, [Ah | Al] bf16 ------
__global__ __launch_bounds__(256) void k_pack_a(
    const float* __restrict__ pooled, const float* __restrict__ stats2,
    ushort_t* __restrict__ Ap) {
  const int m = blockIdx.x, t = threadIdx.x;
  __shared__ float rL[2 * 49 * 33];   // [plane][quad][oc], +1 pad per quad
  __shared__ float hv[1568];
  {
    const float4* src = (const float4*)(pooled + (size_t)m * 3136);
    for (int i = t; i < 784; i += 256) {
      int plane = i / 392, r4 = i - plane * 392;
      int quad = r4 >> 3, oc4 = (r4 & 7) * 4;
      float4 v = src[i];
      float* d = &rL[plane * 1617 + quad * 33 + oc4];
      d[0] = v.x; d[1] = v.y; d[2] = v.z; d[3] = v.w;
    }
  }
  __syncthreads();
  for (int i = t; i < 1568; i += 256) {
    int oc = i / 49, quad = i - oc * 49;
    float mx = rL[quad * 33 + oc];
    float mn = rL[1617 + quad * 33 + oc];
    float sc = stats2[oc * 2], sh = stats2[oc * 2 + 1];
    hv[i] = fmaxf(fmaf(sc, (sc >= 0.f ? mx : mn), sh), 0.f);  // BN monotone
  }
  __syncthreads();
  ushort_t* ap = Ap + (size_t)m * KP;
  for (int c = t; c < KP / 8; c += 256) {
    union { ushort_t u[8]; uint4 v; } o;
    if (c < 196) {
#pragma unroll
      for (int j = 0; j < 8; ++j) o.u[j] = f2bf(hv[c * 8 + j]);
    } else if (c < 392) {
#pragma unroll
      for (int j = 0; j < 8; ++j) {
        float v = hv[(c - 196) * 8 + j];
        o.u[j] = f2bf(v - bf2f(f2bf(v)));
      }
    } else {
      o.v = make_uint4(0, 0, 0, 0);
    }
    *(uint4*)(ap + c * 8) = o.v;
  }
}

// ---------------- fc1 bf16 MFMA GEMM: 128x128 tile, split-K=4 ---------------
// 8 waves (2x4 grid), wave-tile 64x32, BK=64. Grid 448 = 8 XCD x (2 mt x 4 ks
// x 7 nt): each XCD keeps its 2 A-stripes L2-resident across all nt.
__global__ __launch_bounds__(512, 2) void k_fc1_mfma(
    const ushort_t* __restrict__ Ap, const ushort_t* __restrict__ Bp,
    float* __restrict__ partial) {
  __shared__ ushort_t As[128 * 64];
  __shared__ ushort_t Bs[128 * 64];
  const int t = threadIdx.x;
  const int id = blockIdx.x;
  const int xcd = id & 7, w = id >> 3;           // w in 0..55
  const int mtl = w / 28, rem = w - mtl * 28;
  const int ks = rem / 7, nt = rem - ks * 7;
  const int mt = xcd * 2 + mtl;
  const int m0 = mt * 128, n0 = nt * 128;
  const int lane = t & 63, wid = t >> 6;
  const int wm = wid >> 2, wn = wid & 3;

  const int srow = t >> 3, sslot = t & 7;
  const int xsl = (sslot ^ (srow & 7)) << 3;
  ushort_t* awp = &As[srow * 64 + xsl];
  ushort_t* bwp = &Bs[srow * 64 + xsl];
  const uint4* agp = (const uint4*)(Ap + (size_t)(m0 + srow) * KP) + sslot;
  const uint4* bgp = (const uint4*)(Bp + (size_t)(n0 + srow) * KP) + sslot;
  const int ROWOFF = 64 * (KP / 8);

  const int rbaseA = (wm * 64 + (lane & 15)) * 64;
  const int rbaseB = (wn * 32 + (lane & 15)) * 64;
  const int x0 = ((lane >> 4) ^ (lane & 7)) << 3;
  const int x1 = (((lane >> 4) + 4) ^ (lane & 7)) << 3;

  f32x4 acc[4][2];
#pragma unroll
  for (int fm = 0; fm < 4; ++fm) {
    acc[fm][0] = (f32x4){0.f, 0.f, 0.f, 0.f};
    acc[fm][1] = (f32x4){0.f, 0.f, 0.f, 0.f};
  }
  const int kt0 = ks * KQ;
  uint4 ca0 = agp[kt0 * 8], ca1 = agp[kt0 * 8 + ROWOFF];
  uint4 cb0 = bgp[kt0 * 8], cb1 = bgp[kt0 * 8 + ROWOFF];
  for (int kt = kt0; kt < kt0 + KQ; ++kt) {
    __syncthreads();
    *(uint4*)awp = ca0; *(uint4*)(awp + 64 * 64) = ca1;
    *(uint4*)bwp = cb0; *(uint4*)(bwp + 64 * 64) = cb1;
    __syncthreads();
    if (kt + 1 < kt0 + KQ) {  // issue next-tile loads; MFMA hides latency
      ca0 = agp[(kt + 1) * 8]; ca1 = agp[(kt + 1) * 8 + ROWOFF];
      cb0 = bgp[(kt + 1) * 8]; cb1 = bgp[(kt + 1) * 8 + ROWOFF];
    }
#pragma unroll
    for (int kh = 0; kh < 2; ++kh) {
      const int xx = kh ? x1 : x0;
      bf16x8 b0 = *(const bf16x8*)&Bs[rbaseB + xx];
      bf16x8 b1 = *(const bf16x8*)&Bs[rbaseB + 16 * 64 + xx];
#pragma unroll
      for (int fm = 0; fm < 4; ++fm) {
        bf16x8 a = *(const bf16x8*)&As[rbaseA + fm * 1024 + xx];
        acc[fm][0] = __builtin_amdgcn_mfma_f32_16x16x32_bf16(a, b0, acc[fm][0], 0, 0, 0);
        acc[fm][1] = __builtin_amdgcn_mfma_f32_16x16x32_bf16(a, b1, acc[fm][1], 0, 0, 0);
      }
    }
  }
  // C/D: col=lane&15, row=(lane>>4)*4+reg [m89]
  const int mrow0 = m0 + wm * 64 + ((lane >> 4) << 2);
  const int col0 = n0 + wn * 32 + (lane & 15);
#pragma unroll
  for (int fm = 0; fm < 4; ++fm) {
#pragma unroll
    for (int fn = 0; fn < 2; ++fn) {
      int col = col0 + fn * 16;
      if (col < 832) {
        float* pb = partial + ((size_t)ks * 2048 + mrow0 + fm * 16) * 832 + col;
#pragma unroll
        for (int r = 0; r < 4; ++r) pb[(size_t)r * 832] = acc[fm][fn][r];
      }
    }
  }
}

// ---------------- quantum gate helpers --------------------------------------
template <int W>
__device__ __forceinline__ void ry_gate(float (&a)[16], int lane, float th) {
  float s, c;
  sincosf(0.5f * th, &s, &c);
  if (W < 4) {
    const int st = 1 << W;
#pragma unroll
    for (int r = 0; r < 16; ++r) {
      if (!(r & st)) {
        float lo = a[r], hi = a[r + st];
        a[r] = fmaf(c, lo, -s * hi);
        a[r + st] = fmaf(s, lo, c * hi);
      }
    }
  } else {
    const int m = 1 << (W - 4);
    const float sg = (lane & m) ? s : -s;
#pragma unroll
    for (int r = 0; r < 16; ++r) {
      float other = __shfl_xor(a[r], m, 64);
      a[r] = fmaf(c, a[r], sg * other);
    }
  }
}

#define RY10(EXPR)                                                   \
  {                                                                  \
    ry_gate<0>(a, lane, EXPR(0)); ry_gate<1>(a, lane, EXPR(1));      \
    ry_gate<2>(a, lane, EXPR(2)); ry_gate<3>(a, lane, EXPR(3));      \
    ry_gate<4>(a, lane, EXPR(4)); ry_gate<5>(a, lane, EXPR(5));      \
    ry_gate<6>(a, lane, EXPR(6)); ry_gate<7>(a, lane, EXPR(7));      \
    ry_gate<8>(a, lane, EXPR(8)); ry_gate<9>(a, lane, EXPR(9));      \
  }

// ---------------- fused tail: combine + sel + quantum + post ----------------
// one wave per batch row: sum 4 partials + bias, tanh, 10 sel dots (sel_w in
// LDS), 10-qubit circuit, post layers, write out[m][10].
__global__ __launch_bounds__(256) void k_tail(
    const float* __restrict__ partial, const float* __restrict__ fb,
    const float* __restrict__ sw, const float* __restrict__ sb,
    const float* __restrict__ qp, const float* __restrict__ w1,
    const float* __restrict__ b1, const float* __restrict__ w2,
    const float* __restrict__ b2, float* __restrict__ out) {
  const int t = threadIdx.x;
  __shared__ float swL[7840];
  for (int i = t; i < 7840; i += 256) swL[i] = sw[i];
  __syncthreads();
  const int m = blockIdx.x * 4 + (t >> 6);
  const int lane = t & 63;
  const float* p0 = partial + (size_t)m * 832;
  const size_t KSL = (size_t)2048 * 832;
  float acc[10];
#pragma unroll
  for (int i = 0; i < 10; ++i) acc[i] = 0.f;
  for (int c = lane; c < 784; c += 64) {
    float v = p0[c] + p0[c + KSL] + p0[c + 2 * KSL] + p0[c + 3 * KSL] + fb[c];
    v = tanhf(v);
#pragma unroll
    for (int i = 0; i < 10; ++i) acc[i] = fmaf(v, swL[i * 784 + c], acc[i]);
  }
#pragma unroll
  for (int i = 0; i < 10; ++i) acc[i] = wave_reduce_add(acc[i]) + sb[i];

  // quantum circuit (all lanes hold sel values)
  float a[16];
#pragma unroll
  for (int r = 0; r < 16; ++r) a[r] = 0.f;
  if (lane == 0) a[0] = 1.f;
  float czs[16];
#pragma unroll
  for (int r = 0; r < 16; ++r) {
    int idx = (lane << 4) | r;
    czs[r] = (__popc(idx & (idx >> 1)) & 1) ? -1.f : 1.f;
  }
#define ENC(i) (acc[i] * PI_F)
  RY10(ENC)
#undef ENC
  for (int layer = 0; layer < 3; ++layer) {
    const float* lp = qp + layer * 10;
#define LAY(i) (lp[i])
    RY10(LAY)
#undef LAY
#pragma unroll
    for (int r = 0; r < 16; ++r) a[r] *= czs[r];
  }
  float p[16];
  float lt = 0.f;
#pragma unroll
  for (int r = 0; r < 16; ++r) { p[r] = a[r] * a[r]; lt += p[r]; }
  float z[10];
#pragma unroll
  for (int ww = 0; ww < 4; ++ww) {
    float v = 0.f;
#pragma unroll
    for (int r = 0; r < 16; ++r) v += ((r >> ww) & 1) ? -p[r] : p[r];
    z[ww] = v;
  }
#pragma unroll
  for (int ww = 4; ww < 10; ++ww) z[ww] = ((lane >> (ww - 4)) & 1) ? -lt : lt;
#pragma unroll
  for (int ww = 0; ww < 10; ++ww) z[ww] = wave_reduce_add(z[ww]);

  // post layers (uniform across lanes; lane 0 writes)
  if (lane == 0) {
    float h[32];
#pragma unroll
    for (int jj = 0; jj < 32; ++jj) {
      float s = b1[jj];
#pragma unroll
      for (int i = 0; i < 10; ++i) s = fmaf(w1[jj * 10 + i], z[i], s);
      h[jj] = fmaxf(s, 0.f);
    }
#pragma unroll
    for (int o = 0; o < 10; ++o) {
      float s = b2[o];
#pragma unroll
      for (int jj = 0; jj < 32; ++jj) s = fmaf(w2[o * 32 + jj], h[jj], s);
      out[m * 10 + o] = s;
    }
  }
}

// ---------------------------------------------------------------------------
extern "C" void kernel_launch(void* const* d_in, const int* in_sizes, int n_in,
                              void* d_out, int out_size, void* d_ws, size_t ws_size,
                              hipStream_t stream) {
  (void)in_sizes; (void)n_in; (void)out_size; (void)ws_size;
  const float* x    = (const float*)d_in[0];
  const float* c1w  = (const float*)d_in[1];
  const float* c1b  = (const float*)d_in[2];
  const float* bn1g = (const float*)d_in[3];
  const float* bn1b = (const float*)d_in[4];
  const float* c2w  = (const float*)d_in[5];
  const float* c2b  = (const float*)d_in[6];
  const float* bn2g = (const float*)d_in[7];
  const float* bn2b = (const float*)d_in[8];
  const float* fc1w = (const float*)d_in[9];
  const float* fc1b = (const float*)d_in[10];
  const float* selw = (const float*)d_in[11];
  const float* selb = (const float*)d_in[12];
  const float* qpar = (const float*)d_in[13];
  const float* p1w  = (const float*)d_in[14];
  const float* p1b  = (const float*)d_in[15];
  const float* p2w  = (const float*)d_in[16];
  const float* p2b  = (const float*)d_in[17];

  // ws layout (floats), total ~59.7 MB (< proven 89.8 MB budget).
  // Aliases: Ap in h1bf region (h1bf dead after conv2);
  //          partial in pooled region (pooled dead after pack_a).
  float* ws = (float*)d_ws;
  ushort_t* h1bf = (ushort_t*)ws;           // 6,422,528 f
  ushort_t* Ap   = (ushort_t*)ws;           // alias (3,407,872 f)
  size_t o = 6422528;
  float* pooled  = ws + o;                  // 6,422,528 f [2048][2][49][32]
  float* partial = ws + o;                  // alias 6,815,744 f [4][2048][832]
  o += 6815744;
  ushort_t* Bp  = (ushort_t*)(ws + o); o += 1490944;  // 896*3328 ushorts
  ushort_t* wB  = (ushort_t*)(ws + o); o += 7296;
  float* part1  = ws + o; o += 65536;
  float* part2  = ws + o; o += 131072;
  float* stats1 = ws + o; o += 32;
  float* stats2 = ws + o; o += 64;
  float* outp   = (float*)d_out;

  k_conv1_stats<<<BATCH + 1 + 112, 256, 0, stream>>>(x, c1w, c1b, part1, c2w,
                                                     wB, fc1w, Bp);
  k_bnstat<<<16, 256, 0, stream>>>(part1, bn1g, bn1b, stats1, 16, BATCH,
                                   1.0 / (2048.0 * 784.0));
  k_conv1_fused<<<BATCH, 256, 0, stream>>>(x, c1w, c1b, stats1, h1bf);
  k_conv2_mfma<<<BATCH / 2, 512, 0, stream>>>(h1bf, wB, c2b, part2, pooled);
  k_bnstat<<<32, 256, 0, stream>>>(part2, bn2g, bn2b, stats2, 32, BATCH,
                                   1.0 / (2048.0 * 196.0));
  k_pack_a<<<BATCH, 256, 0, stream>>>(pooled, stats2, Ap);
  k_fc1_mfma<<<448, 512, 0, stream>>>(Ap, Bp, partial);
  k_tail<<<BATCH / 4, 256, 0, stream>>>(partial, fc1b, selw, selb, qpar,
                                        p1w, p1b, p2w, p2b, outp);
}

// Round 8
// 125.493 us; speedup vs baseline: 1.7623x; 1.0873x over previous
//
#include <hip/hip_runtime.h>
#include <math.h>

// ---------------------------------------------------------------------------
// AngleEncodingQuantumNet: conv1+BN+relu+pool -> conv2+BN+relu+pool -> fc1
// (tanh) -> sel -> 10-qubit RY/CZ circuit -> post1(relu) -> post2.
// Train-mode BN => stats pass then apply pass.
// R8: k_tail rebuilt — sincosf(ptr,ptr) forced scratch (VGPR=44, 60us);
// now value-returning __sinf/__cosf (layer angles precomputed once per
// block), __expf-based tanh, lane-parallel post layers, float4 combine.
// conv2 emits in-lane-pooled max/min; fc1 = 128x128 bf16 MFMA split-K=4.
// ---------------------------------------------------------------------------

#define BATCH 2048
#define PI_F 3.14159265358979323846f
#define KP 3328          // fc1 padded K' = 2*1568 -> 3328 (52 BK=64 steps)
#define KQ 13            // K-steps per split-K quarter
#define BSTRIDE 456      // conv2 B' row stride (ushorts): 912B -> bank step 4

typedef unsigned short ushort_t;
typedef __attribute__((ext_vector_type(8))) short bf16x8;
typedef __attribute__((ext_vector_type(4))) float f32x4;

__device__ __forceinline__ float wave_reduce_add(float v) {
#pragma unroll
  for (int off = 32; off >= 1; off >>= 1) v += __shfl_xor(v, off, 64);
  return v;
}

__device__ __forceinline__ ushort_t f2bf(float v) {  // RNE f32 -> bf16 bits
  unsigned u = __float_as_uint(v);
  u += 0x7FFFu + ((u >> 16) & 1u);
  return (ushort_t)(u >> 16);
}
__device__ __forceinline__ float bf2f(ushort_t b) {
  return __uint_as_float(((unsigned)b) << 16);
}

__device__ __forceinline__ float tanh_fast(float x) {  // overflow-safe, ~1e-7
  float e = __expf(-2.f * fabsf(x));
  float r = (1.f - e) / (1.f + e);
  return copysignf(r, x);
}

// ---------------- conv1: stats pass (+ bonus blocks: conv2 B', fc1 B') -----
__global__ __launch_bounds__(256) void k_conv1_stats(
    const float* __restrict__ x, const float* __restrict__ cw,
    const float* __restrict__ cb, float* __restrict__ part1,
    const float* __restrict__ cw2, ushort_t* __restrict__ wB,
    const float* __restrict__ fc1w, ushort_t* __restrict__ Bp) {
  const int t = threadIdx.x;
  if (blockIdx.x >= BATCH) {
    const int bid = blockIdx.x - BATCH;
    if (bid == 0) {
      // conv2 B': [oc][k'], k'=sec*16+ic, sec 0..26 = [Bh x9 | Bh x9 | Bl x9]
      for (int i = t; i < 32 * BSTRIDE; i += 256) {
        int oc = i / BSTRIDE, k = i - oc * BSTRIDE;
        ushort_t val = 0;
        if (k < 432) {
          int sec = k >> 4, ic = k & 15;
          int s = (sec >= 18) ? (sec - 18) : (sec >= 9 ? sec - 9 : sec);
          float w = cw2[oc * 144 + ic * 9 + s];
          if (sec < 18) val = f2bf(w);
          else val = f2bf(w - bf2f(f2bf(w)));
        }
        wB[i] = val;
      }
    } else {
      // fc1 B': [Bh | Bh] bf16, 896 rows x KP (rows>=784 and tail zeros)
      const int rb = (bid - 1) * 8;
      for (int i = t; i < 8 * (KP / 8); i += 256) {
        int rr = i / (KP / 8), c = i - rr * (KP / 8);
        int n = rb + rr;
        union { ushort_t u[8]; uint4 v; } o;
        o.v = make_uint4(0, 0, 0, 0);
        if (n < 784 && c < 392) {
          int cc = c < 196 ? c : c - 196;
          const float* wp = fc1w + (size_t)n * 1568 + cc * 8;
#pragma unroll
          for (int j = 0; j < 8; ++j) o.u[j] = f2bf(wp[j]);
        }
        ((uint4*)(Bp + (size_t)n * KP))[c] = o.v;
      }
    }
    return;
  }
  const int b = blockIdx.x;
  __shared__ float xs[30][33];
  __shared__ float ws[160];
  __shared__ float redS[16][28];
  __shared__ float redQ[16][28];
  for (int i = t; i < 30 * 33; i += 256) (&xs[0][0])[i] = 0.f;
  if (t < 144) ws[t] = cw[t];
  else if (t < 160) ws[t] = cb[t - 144];
  __syncthreads();
  const float* xb = x + b * 784;
  for (int i = t; i < 784; i += 256) xs[1 + i / 28][1 + (i % 28)] = xb[i];
  __syncthreads();
  for (int task = t; task < 448; task += 256) {
    const int oc = task / 28;
    const int row = task - oc * 28;
    float wk[9];
#pragma unroll
    for (int k = 0; k < 9; ++k) wk[k] = ws[oc * 9 + k];
    const float bc = ws[144 + oc];
    float A0 = xs[row][0], A1 = xs[row][1];
    float B0 = xs[row + 1][0], B1 = xs[row + 1][1];
    float C0 = xs[row + 2][0], C1 = xs[row + 2][1];
    float s = 0.f, q = 0.f;
#pragma unroll 4
    for (int xx = 0; xx < 28; ++xx) {
      float A2 = xs[row][xx + 2], B2 = xs[row + 1][xx + 2], C2 = xs[row + 2][xx + 2];
      float acc = bc;
      acc = fmaf(wk[0], A0, acc); acc = fmaf(wk[1], A1, acc); acc = fmaf(wk[2], A2, acc);
      acc = fmaf(wk[3], B0, acc); acc = fmaf(wk[4], B1, acc); acc = fmaf(wk[5], B2, acc);
      acc = fmaf(wk[6], C0, acc); acc = fmaf(wk[7], C1, acc); acc = fmaf(wk[8], C2, acc);
      s += acc; q = fmaf(acc, acc, q);
      A0 = A1; A1 = A2; B0 = B1; B1 = B2; C0 = C1; C1 = C2;
    }
    redS[oc][row] = s;
    redQ[oc][row] = q;
  }
  __syncthreads();
  if (t < 32) {
    const int c = t >> 1;
    float acc = 0.f;
    if (t & 1) {
#pragma unroll 4
      for (int r = 0; r < 28; ++r) acc += redQ[c][r];
    } else {
#pragma unroll 4
      for (int r = 0; r < 28; ++r) acc += redS[c][r];
    }
    part1[b * 32 + t] = acc;
  }
}

// ---------------- BN stats fold (both layers) -------------------------------
__global__ __launch_bounds__(256) void k_bnstat(
    const float* __restrict__ part, const float* __restrict__ g,
    const float* __restrict__ bb, float* __restrict__ stats,
    int nch, int nblk, double invN) {
  const int c = blockIdx.x;
  const int t = threadIdx.x;
  const int stride = nch * 2;
  double ls = 0.0, lq = 0.0;
  for (int i = t; i < nblk; i += 256) {
    ls += (double)part[i * stride + c * 2];
    lq += (double)part[i * stride + c * 2 + 1];
  }
#pragma unroll
  for (int off = 32; off >= 1; off >>= 1) {
    ls += __shfl_xor(ls, off, 64);
    lq += __shfl_xor(lq, off, 64);
  }
  __shared__ double rs[4], rq[4];
  if ((t & 63) == 0) { rs[t >> 6] = ls; rq[t >> 6] = lq; }
  __syncthreads();
  if (t == 0) {
    double S = rs[0] + rs[1] + rs[2] + rs[3];
    double Q = rq[0] + rq[1] + rq[2] + rq[3];
    double mean = S * invN;
    double var = Q * invN - mean * mean;
    double inv = 1.0 / sqrt(var + 1e-5);
    double sc = (double)g[c] * inv;
    stats[c * 2] = (float)sc;
    stats[c * 2 + 1] = (float)((double)bb[c] - mean * sc);
  }
}

// ---------------- conv1: fused BN+relu+pool, emits h1 as hi/lo bf16 ---------
// output layout: h1bf[b][plane][pixel=y*14+x][ic] ushort (6272/image)
__global__ __launch_bounds__(256) void k_conv1_fused(
    const float* __restrict__ x, const float* __restrict__ cw,
    const float* __restrict__ cb, const float* __restrict__ stats1,
    ushort_t* __restrict__ h1bf) {
  const int b = blockIdx.x;
  const int t = threadIdx.x;
  __shared__ float xs[30][33];
  __shared__ float ws[160];
  __shared__ __align__(16) ushort_t obuf[2 * 3136];
  for (int i = t; i < 30 * 33; i += 256) (&xs[0][0])[i] = 0.f;
  if (t < 144) ws[t] = cw[t];
  else if (t < 160) ws[t] = cb[t - 144];
  __syncthreads();
  const float* xb = x + b * 784;
  for (int i = t; i < 784; i += 256) xs[1 + i / 28][1 + (i % 28)] = xb[i];
  __syncthreads();
  if (t < 224) {
    const int oc = t / 14;
    const int pr = t - oc * 14;
    float wk[9];
#pragma unroll
    for (int k = 0; k < 9; ++k) wk[k] = ws[oc * 9 + k];
    const float bc = ws[144 + oc];
    const float scale = stats1[oc * 2], shift = stats1[oc * 2 + 1];
    const int r0 = 2 * pr;
    float A0 = xs[r0][0],     A1 = xs[r0][1];
    float B0 = xs[r0 + 1][0], B1 = xs[r0 + 1][1];
    float C0 = xs[r0 + 2][0], C1 = xs[r0 + 2][1];
    float D0 = xs[r0 + 3][0], D1 = xs[r0 + 3][1];
    float pmax = 0.f;
#pragma unroll 4
    for (int xx = 0; xx < 28; ++xx) {
      float A2 = xs[r0][xx + 2], B2 = xs[r0 + 1][xx + 2];
      float C2 = xs[r0 + 2][xx + 2], D2 = xs[r0 + 3][xx + 2];
      float c0 = bc, c1 = bc;
      c0 = fmaf(wk[0], A0, c0); c0 = fmaf(wk[1], A1, c0); c0 = fmaf(wk[2], A2, c0);
      c0 = fmaf(wk[3], B0, c0); c0 = fmaf(wk[4], B1, c0); c0 = fmaf(wk[5], B2, c0);
      c0 = fmaf(wk[6], C0, c0); c0 = fmaf(wk[7], C1, c0); c0 = fmaf(wk[8], C2, c0);
      c1 = fmaf(wk[0], B0, c1); c1 = fmaf(wk[1], B1, c1); c1 = fmaf(wk[2], B2, c1);
      c1 = fmaf(wk[3], C0, c1); c1 = fmaf(wk[4], C1, c1); c1 = fmaf(wk[5], C2, c1);
      c1 = fmaf(wk[6], D0, c1); c1 = fmaf(wk[7], D1, c1); c1 = fmaf(wk[8], D2, c1);
      float e0 = fmaxf(fmaf(scale, c0, shift), 0.f);
      float e1 = fmaxf(fmaf(scale, c1, shift), 0.f);
      float m = fmaxf(e0, e1);
      if ((xx & 1) == 0) {
        pmax = m;
      } else {
        float pv = fmaxf(pmax, m);
        ushort_t hi = f2bf(pv);
        ushort_t lo = f2bf(pv - bf2f(hi));
        int pidx = (pr * 14 + (xx >> 1)) * 16 + oc;
        obuf[pidx] = hi;
        obuf[3136 + pidx] = lo;
      }
      A0 = A1; A1 = A2; B0 = B1; B1 = B2; C0 = C1; C1 = C2; D0 = D1; D1 = D2;
    }
  }
  __syncthreads();
  uint4* dst = (uint4*)(h1bf + (size_t)b * 6272);
  const uint4* sob = (const uint4*)obuf;
  for (int i = t; i < 784; i += 256) dst[i] = sob[i];
}

// ---------------- conv2 via MFMA, in-lane 2x2 pooled output -----------------
// 2 images/block, 512 threads. A rows QUAD-MAJOR (fragment 4-row group ==
// one pool quad -> pooled max/min in-lane). Read base = (y*16+x)*24 (output
// coords; image stored at +1,+1; shift offset doff supplies dy,dx).
__global__ __launch_bounds__(512, 4) void k_conv2_mfma(
    const ushort_t* __restrict__ h1bf, const ushort_t* __restrict__ wB,
    const float* __restrict__ cb, float* __restrict__ part2,
    float* __restrict__ pooled) {
  const int b0 = blockIdx.x * 2;
  const int t = threadIdx.x;
  __shared__ __align__(16) ushort_t aT[2 * 12288];   // 49,152 B
  __shared__ __align__(16) ushort_t bS[32 * BSTRIDE]; // 29,184 B
  __shared__ float red[2][4][64];                     //  2,048 B
  {
    uint4 z = make_uint4(0, 0, 0, 0);
    uint4* a4 = (uint4*)aT;
#pragma unroll
    for (int i = 0; i < 6; ++i) a4[t + i * 512] = z;
    uint4* b4 = (uint4*)bS;
    const uint4* w4 = (const uint4*)wB;
    for (int i = t; i < (32 * BSTRIDE) / 8; i += 512) b4[i] = w4[i];
  }
  __syncthreads();
  {
    uint4* a4 = (uint4*)aT;
    const uint4* src = (const uint4*)(h1bf + (size_t)b0 * 6272);
    for (int i = t; i < 1568; i += 512) {
      int img = i / 784, j = i - img * 784;
      int plane = j / 392, jj = j - plane * 392;
      int pix = jj >> 1, half = jj & 1;
      int y = pix / 14, x = pix - y * 14;
      a4[img * 1536 + plane * 768 + ((y + 1) * 16 + (x + 1)) * 3 + half] =
          src[img * 784 + j];
    }
  }
  __syncthreads();

  const int lane = t & 63;
  const int wv = t >> 6;
  const int img = wv >> 2, wi = wv & 3;
  const int ic0 = ((lane >> 4) & 1) * 8;
  const int hb = lane >> 5;
  const int imgbase = img * 12288;
  int abase[4];
#pragma unroll
  for (int fi = 0; fi < 4; ++fi) {
    int f = wi + fi * 4;
    int pp = f * 16 + (lane & 15);       // quad-major row index
    int quad = pp >> 2;
    if (quad > 48) quad = 48;            // clamp: keeps A-read in-bounds
    int corner = pp & 3;
    int qy = quad / 7, qx = quad - qy * 7;
    int y = 2 * qy + (corner >> 1), x = 2 * qx + (corner & 1);
    abase[fi] = imgbase + (y * 16 + x) * 24 + ic0;   // output coords, no +1
  }
  f32x4 acc[4][2];
  {
    const float bias0 = cb[lane & 15];
    const float bias1 = cb[16 + (lane & 15)];
#pragma unroll
    for (int fi = 0; fi < 4; ++fi) {
      acc[fi][0] = (f32x4){bias0, bias0, bias0, bias0};
      acc[fi][1] = (f32x4){bias1, bias1, bias1, bias1};
    }
  }
  const int kb = (lane & 15) * BSTRIDE + (lane >> 4) * 8;
#pragma unroll
  for (int kt = 0; kt < 14; ++kt) {
    bf16x8 bv0 = *(const bf16x8*)&bS[kb + kt * 32];
    bf16x8 bv1 = *(const bf16x8*)&bS[kb + 16 * BSTRIDE + kt * 32];
    int sec = 2 * kt + hb;
    int ss = sec >= 18 ? sec - 18 : (sec >= 9 ? sec - 9 : sec);
    if (ss > 8) ss = 8;  // sec==27: B is zero
    int plane = (sec >= 9 && sec < 18) ? 1 : 0;
    int dy = ss / 3, dx = ss - dy * 3;
    int doff = plane * 6144 + dy * 384 + dx * 24;
#pragma unroll
    for (int fi = 0; fi < 4; ++fi) {
      if (wi + fi * 4 < 13) {
        bf16x8 av = *(const bf16x8*)&aT[doff + abase[fi]];
        acc[fi][0] = __builtin_amdgcn_mfma_f32_16x16x32_bf16(av, bv0, acc[fi][0], 0, 0, 0);
        acc[fi][1] = __builtin_amdgcn_mfma_f32_16x16x32_bf16(av, bv1, acc[fi][1], 0, 0, 0);
      }
    }
  }
  // epilogue: in-lane 2x2 pool + per-oc stats
  float s0 = 0.f, q0 = 0.f, s1 = 0.f, q1 = 0.f;
  float* pm = pooled + (size_t)(b0 + img) * 3136;
#pragma unroll
  for (int fi = 0; fi < 4; ++fi) {
    int f = wi + fi * 4;
    int quad = f * 4 + (lane >> 4);
    if (quad < 49) {
      f32x4 a0 = acc[fi][0], a1 = acc[fi][1];
#pragma unroll
      for (int r = 0; r < 4; ++r) {
        s0 += a0[r]; q0 = fmaf(a0[r], a0[r], q0);
        s1 += a1[r]; q1 = fmaf(a1[r], a1[r], q1);
      }
      float mx0 = fmaxf(fmaxf(a0[0], a0[1]), fmaxf(a0[2], a0[3]));
      float mn0 = fminf(fminf(a0[0], a0[1]), fminf(a0[2], a0[3]));
      float mx1 = fmaxf(fmaxf(a1[0], a1[1]), fmaxf(a1[2], a1[3]));
      float mn1 = fminf(fminf(a1[0], a1[1]), fminf(a1[2], a1[3]));
      pm[quad * 32 + (lane & 15)] = mx0;
      pm[quad * 32 + 16 + (lane & 15)] = mx1;
      pm[1568 + quad * 32 + (lane & 15)] = mn0;
      pm[1568 + quad * 32 + 16 + (lane & 15)] = mn1;
    }
  }
  s0 += __shfl_xor(s0, 16, 64); s0 += __shfl_xor(s0, 32, 64);
  q0 += __shfl_xor(q0, 16, 64); q0 += __shfl_xor(q0, 32, 64);
  s1 += __shfl_xor(s1, 16, 64); s1 += __shfl_xor(s1, 32, 64);
  q1 += __shfl_xor(q1, 16, 64); q1 += __shfl_xor(q1, 32, 64);
  if (lane < 16) {
    red[img][wi][lane * 2] = s0;        red[img][wi][lane * 2 + 1] = q0;
    red[img][wi][(lane + 16) * 2] = s1; red[img][wi][(lane + 16) * 2 + 1] = q1;
  }
  __syncthreads();
  if (t < 128) {
    int im = t >> 6, c = t & 63;
    part2[(b0 + im) * 64 + c] =
        red[im][0][c] + red[im][1][c] + red[im][2][c] + red[im][3][c];
  }
}

// ---------------- pack A': BN+relu from pooled max/min, [Ah | Al] bf16 ------
__global__ __launch_bounds__(256) void k_pack_a(
    const float* __restrict__ pooled, const float* __restrict__ stats2,
    ushort_t* __restrict__ Ap) {
  const int m = blockIdx.x, t = threadIdx.x;
  __shared__ float rL[2 * 49 * 33];   // [plane][quad][oc], +1 pad per quad
  __shared__ float hv[1568];
  {
    const float4* src = (const float4*)(pooled + (size_t)m * 3136);
    for (int i = t; i < 784; i += 256) {
      int plane = i / 392, r4 = i - plane * 392;
      int quad = r4 >> 3, oc4 = (r4 & 7) * 4;
      float4 v = src[i];
      float* d = &rL[plane * 1617 + quad * 33 + oc4];
      d[0] = v.x; d[1] = v.y; d[2] = v.z; d[3] = v.w;
    }
  }
  __syncthreads();
  for (int i = t; i < 1568; i += 256) {
    int oc = i / 49, quad = i - oc * 49;
    float mx = rL[quad * 33 + oc];
    float mn = rL[1617 + quad * 33 + oc];
    float sc = stats2[oc * 2], sh = stats2[oc * 2 + 1];
    hv[i] = fmaxf(fmaf(sc, (sc >= 0.f ? mx : mn), sh), 0.f);  // BN monotone
  }
  __syncthreads();
  ushort_t* ap = Ap + (size_t)m * KP;
  for (int c = t; c < KP / 8; c += 256) {
    union { ushort_t u[8]; uint4 v; } o;
    if (c < 196) {
#pragma unroll
      for (int j = 0; j < 8; ++j) o.u[j] = f2bf(hv[c * 8 + j]);
    } else if (c < 392) {
#pragma unroll
      for (int j = 0; j < 8; ++j) {
        float v = hv[(c - 196) * 8 + j];
        o.u[j] = f2bf(v - bf2f(f2bf(v)));
      }
    } else {
      o.v = make_uint4(0, 0, 0, 0);
    }
    *(uint4*)(ap + c * 8) = o.v;
  }
}

// ---------------- fc1 bf16 MFMA GEMM: 128x128 tile, split-K=4 ---------------
__global__ __launch_bounds__(512, 2) void k_fc1_mfma(
    const ushort_t* __restrict__ Ap, const ushort_t* __restrict__ Bp,
    float* __restrict__ partial) {
  __shared__ ushort_t As[128 * 64];
  __shared__ ushort_t Bs[128 * 64];
  const int t = threadIdx.x;
  const int id = blockIdx.x;
  const int xcd = id & 7, w = id >> 3;           // w in 0..55
  const int mtl = w / 28, rem = w - mtl * 28;
  const int ks = rem / 7, nt = rem - ks * 7;
  const int mt = xcd * 2 + mtl;
  const int m0 = mt * 128, n0 = nt * 128;
  const int lane = t & 63, wid = t >> 6;
  const int wm = wid >> 2, wn = wid & 3;

  const int srow = t >> 3, sslot = t & 7;
  const int xsl = (sslot ^ (srow & 7)) << 3;
  ushort_t* awp = &As[srow * 64 + xsl];
  ushort_t* bwp = &Bs[srow * 64 + xsl];
  const uint4* agp = (const uint4*)(Ap + (size_t)(m0 + srow) * KP) + sslot;
  const uint4* bgp = (const uint4*)(Bp + (size_t)(n0 + srow) * KP) + sslot;
  const int ROWOFF = 64 * (KP / 8);

  const int rbaseA = (wm * 64 + (lane & 15)) * 64;
  const int rbaseB = (wn * 32 + (lane & 15)) * 64;
  const int x0 = ((lane >> 4) ^ (lane & 7)) << 3;
  const int x1 = (((lane >> 4) + 4) ^ (lane & 7)) << 3;

  f32x4 acc[4][2];
#pragma unroll
  for (int fm = 0; fm < 4; ++fm) {
    acc[fm][0] = (f32x4){0.f, 0.f, 0.f, 0.f};
    acc[fm][1] = (f32x4){0.f, 0.f, 0.f, 0.f};
  }
  const int kt0 = ks * KQ;
  uint4 ca0 = agp[kt0 * 8], ca1 = agp[kt0 * 8 + ROWOFF];
  uint4 cb0 = bgp[kt0 * 8], cb1 = bgp[kt0 * 8 + ROWOFF];
  for (int kt = kt0; kt < kt0 + KQ; ++kt) {
    __syncthreads();
    *(uint4*)awp = ca0; *(uint4*)(awp + 64 * 64) = ca1;
    *(uint4*)bwp = cb0; *(uint4*)(bwp + 64 * 64) = cb1;
    __syncthreads();
    if (kt + 1 < kt0 + KQ) {  // issue next-tile loads; MFMA hides latency
      ca0 = agp[(kt + 1) * 8]; ca1 = agp[(kt + 1) * 8 + ROWOFF];
      cb0 = bgp[(kt + 1) * 8]; cb1 = bgp[(kt + 1) * 8 + ROWOFF];
    }
#pragma unroll
    for (int kh = 0; kh < 2; ++kh) {
      const int xx = kh ? x1 : x0;
      bf16x8 b0 = *(const bf16x8*)&Bs[rbaseB + xx];
      bf16x8 b1 = *(const bf16x8*)&Bs[rbaseB + 16 * 64 + xx];
#pragma unroll
      for (int fm = 0; fm < 4; ++fm) {
        bf16x8 a = *(const bf16x8*)&As[rbaseA + fm * 1024 + xx];
        acc[fm][0] = __builtin_amdgcn_mfma_f32_16x16x32_bf16(a, b0, acc[fm][0], 0, 0, 0);
        acc[fm][1] = __builtin_amdgcn_mfma_f32_16x16x32_bf16(a, b1, acc[fm][1], 0, 0, 0);
      }
    }
  }
  // C/D: col=lane&15, row=(lane>>4)*4+reg [m89]
  const int mrow0 = m0 + wm * 64 + ((lane >> 4) << 2);
  const int col0 = n0 + wn * 32 + (lane & 15);
#pragma unroll
  for (int fm = 0; fm < 4; ++fm) {
#pragma unroll
    for (int fn = 0; fn < 2; ++fn) {
      int col = col0 + fn * 16;
      if (col < 832) {
        float* pb = partial + ((size_t)ks * 2048 + mrow0 + fm * 16) * 832 + col;
#pragma unroll
        for (int r = 0; r < 4; ++r) pb[(size_t)r * 832] = acc[fm][fn][r];
      }
    }
  }
}

// ---------------- quantum gate helper (value-passed cos/sin) ----------------
template <int W>
__device__ __forceinline__ void ry_cs(float (&a)[16], int lane, float c, float s) {
  if (W < 4) {
    const int st = 1 << W;
#pragma unroll
    for (int r = 0; r < 16; ++r) {
      if (!(r & st)) {
        float lo = a[r], hi = a[r + st];
        a[r] = fmaf(c, lo, -s * hi);
        a[r + st] = fmaf(s, lo, c * hi);
      }
    }
  } else {
    const int m = 1 << (W - 4);
    const float sg = (lane & m) ? s : -s;
#pragma unroll
    for (int r = 0; r < 16; ++r) {
      float other = __shfl_xor(a[r], m, 64);
      a[r] = fmaf(c, a[r], sg * other);
    }
  }
}

#define RYCS(GC, GS)                                                  \
  {                                                                   \
    ry_cs<0>(a, lane, GC(0), GS(0)); ry_cs<1>(a, lane, GC(1), GS(1)); \
    ry_cs<2>(a, lane, GC(2), GS(2)); ry_cs<3>(a, lane, GC(3), GS(3)); \
    ry_cs<4>(a, lane, GC(4), GS(4)); ry_cs<5>(a, lane, GC(5), GS(5)); \
    ry_cs<6>(a, lane, GC(6), GS(6)); ry_cs<7>(a, lane, GC(7), GS(7)); \
    ry_cs<8>(a, lane, GC(8), GS(8)); ry_cs<9>(a, lane, GC(9), GS(9)); \
  }

// ---------------- fused tail: combine + sel + quantum + post ----------------
// one wave per batch row. No pointer-output trig (scratch-free): layer
// (cos,sin) precomputed once/block in LDS; encoding via __sinf/__cosf.
__global__ __launch_bounds__(256) void k_tail(
    const float* __restrict__ partial, const float* __restrict__ fb,
    const float* __restrict__ sw, const float* __restrict__ sb,
    const float* __restrict__ qp, const float* __restrict__ w1,
    const float* __restrict__ b1, const float* __restrict__ w2,
    const float* __restrict__ b2, float* __restrict__ out) {
  const int t = threadIdx.x;
  __shared__ __align__(16) float swL[7840];
  __shared__ float lc[30], ls[30];
  __shared__ float hbuf[4][32];
  for (int i = t; i < 7840; i += 256) swL[i] = sw[i];
  if (t < 30) {
    float th = 0.5f * qp[t];
    lc[t] = __cosf(th);
    ls[t] = __sinf(th);
  }
  __syncthreads();
  const int wv = t >> 6;
  const int m = blockIdx.x * 4 + wv;
  const int lane = t & 63;

  // combine 4 split-K partials + bias -> tanh -> 10 sel dots (float4)
  const float4* p4 = (const float4*)(partial + (size_t)m * 832);
  const size_t KSL4 = (size_t)2048 * 832 / 4;
  const float4* fb4 = (const float4*)fb;
  const float4* sw4 = (const float4*)swL;
  float acc[10];
#pragma unroll
  for (int i = 0; i < 10; ++i) acc[i] = 0.f;
  for (int c4 = lane; c4 < 196; c4 += 64) {
    float4 v0 = p4[c4];
    float4 v1 = p4[c4 + KSL4];
    float4 v2 = p4[c4 + 2 * KSL4];
    float4 v3 = p4[c4 + 3 * KSL4];
    float4 bb = fb4[c4];
    float t0 = tanh_fast(v0.x + v1.x + v2.x + v3.x + bb.x);
    float t1 = tanh_fast(v0.y + v1.y + v2.y + v3.y + bb.y);
    float t2 = tanh_fast(v0.z + v1.z + v2.z + v3.z + bb.z);
    float t3 = tanh_fast(v0.w + v1.w + v2.w + v3.w + bb.w);
#pragma unroll
    for (int i = 0; i < 10; ++i) {
      float4 w = sw4[i * 196 + c4];
      acc[i] = fmaf(t0, w.x, acc[i]);
      acc[i] = fmaf(t1, w.y, acc[i]);
      acc[i] = fmaf(t2, w.z, acc[i]);
      acc[i] = fmaf(t3, w.w, acc[i]);
    }
  }
#pragma unroll
  for (int i = 0; i < 10; ++i) acc[i] = wave_reduce_add(acc[i]) + sb[i];

  // 10-qubit circuit: amps idx = lane*16 + r; wires 0-3 reg bits, 4-9 lane
  float a[16];
#pragma unroll
  for (int r = 0; r < 16; ++r) a[r] = 0.f;
  if (lane == 0) a[0] = 1.f;
  float czs[16];
#pragma unroll
  for (int r = 0; r < 16; ++r) {
    int idx = (lane << 4) | r;
    czs[r] = (__popc(idx & (idx >> 1)) & 1) ? -1.f : 1.f;
  }
#define EC(i) __cosf(acc[i] * (0.5f * PI_F))
#define ES(i) __sinf(acc[i] * (0.5f * PI_F))
  RYCS(EC, ES)
#undef EC
#undef ES
#pragma unroll
  for (int layer = 0; layer < 3; ++layer) {
    const int lb = layer * 10;
#define LC(i) (lc[lb + i])
#define LS(i) (ls[lb + i])
    RYCS(LC, LS)
#undef LC
#undef LS
#pragma unroll
    for (int r = 0; r < 16; ++r) a[r] *= czs[r];
  }
  float p[16];
  float lt = 0.f;
#pragma unroll
  for (int r = 0; r < 16; ++r) { p[r] = a[r] * a[r]; lt += p[r]; }
  float z[10];
#pragma unroll
  for (int ww = 0; ww < 4; ++ww) {
    float v = 0.f;
#pragma unroll
    for (int r = 0; r < 16; ++r) v += ((r >> ww) & 1) ? -p[r] : p[r];
    z[ww] = v;
  }
#pragma unroll
  for (int ww = 4; ww < 10; ++ww) z[ww] = ((lane >> (ww - 4)) & 1) ? -lt : lt;
#pragma unroll
  for (int ww = 0; ww < 10; ++ww) z[ww] = wave_reduce_add(z[ww]);

  // post layers, lane-parallel: 32 lanes -> h[32], LDS, 10 lanes -> out
  if (lane < 32) {
    float s = b1[lane];
#pragma unroll
    for (int i = 0; i < 10; ++i) s = fmaf(w1[lane * 10 + i], z[i], s);
    hbuf[wv][lane] = fmaxf(s, 0.f);
  }
  __syncthreads();
  if (lane < 10) {
    float s = b2[lane];
#pragma unroll
    for (int jj = 0; jj < 32; ++jj) s = fmaf(w2[lane * 32 + jj], hbuf[wv][jj], s);
    out[m * 10 + lane] = s;
  }
}

// ---------------------------------------------------------------------------
extern "C" void kernel_launch(void* const* d_in, const int* in_sizes, int n_in,
                              void* d_out, int out_size, void* d_ws, size_t ws_size,
                              hipStream_t stream) {
  (void)in_sizes; (void)n_in; (void)out_size; (void)ws_size;
  const float* x    = (const float*)d_in[0];
  const float* c1w  = (const float*)d_in[1];
  const float* c1b  = (const float*)d_in[2];
  const float* bn1g = (const float*)d_in[3];
  const float* bn1b = (const float*)d_in[4];
  const float* c2w  = (const float*)d_in[5];
  const float* c2b  = (const float*)d_in[6];
  const float* bn2g = (const float*)d_in[7];
  const float* bn2b = (const float*)d_in[8];
  const float* fc1w = (const float*)d_in[9];
  const float* fc1b = (const float*)d_in[10];
  const float* selw = (const float*)d_in[11];
  const float* selb = (const float*)d_in[12];
  const float* qpar = (const float*)d_in[13];
  const float* p1w  = (const float*)d_in[14];
  const float* p1b  = (const float*)d_in[15];
  const float* p2w  = (const float*)d_in[16];
  const float* p2b  = (const float*)d_in[17];

  // ws layout (floats), total ~59.7 MB (< proven 89.8 MB budget).
  // Aliases: Ap in h1bf region (h1bf dead after conv2);
  //          partial in pooled region (pooled dead after pack_a).
  float* ws = (float*)d_ws;
  ushort_t* h1bf = (ushort_t*)ws;           // 6,422,528 f
  ushort_t* Ap   = (ushort_t*)ws;           // alias (3,407,872 f)
  size_t o = 6422528;
  float* pooled  = ws + o;                  // 6,422,528 f [2048][2][49][32]
  float* partial = ws + o;                  // alias 6,815,744 f [4][2048][832]
  o += 6815744;
  ushort_t* Bp  = (ushort_t*)(ws + o); o += 1490944;  // 896*3328 ushorts
  ushort_t* wB  = (ushort_t*)(ws + o); o += 7296;
  float* part1  = ws + o; o += 65536;
  float* part2  = ws + o; o += 131072;
  float* stats1 = ws + o; o += 32;
  float* stats2 = ws + o; o += 64;
  float* outp   = (float*)d_out;

  k_conv1_stats<<<BATCH + 1 + 112, 256, 0, stream>>>(x, c1w, c1b, part1, c2w,
                                                     wB, fc1w, Bp);
  k_bnstat<<<16, 256, 0, stream>>>(part1, bn1g, bn1b, stats1, 16, BATCH,
                                   1.0 / (2048.0 * 784.0));
  k_conv1_fused<<<BATCH, 256, 0, stream>>>(x, c1w, c1b, stats1, h1bf);
  k_conv2_mfma<<<BATCH / 2, 512, 0, stream>>>(h1bf, wB, c2b, part2, pooled);
  k_bnstat<<<32, 256, 0, stream>>>(part2, bn2g, bn2b, stats2, 32, BATCH,
                                   1.0 / (2048.0 * 196.0));
  k_pack_a<<<BATCH, 256, 0, stream>>>(pooled, stats2, Ap);
  k_fc1_mfma<<<448, 512, 0, stream>>>(Ap, Bp, partial);
  k_tail<<<BATCH / 4, 256, 0, stream>>>(partial, fc1b, selw, selb, qpar,
                                        p1w, p1b, p2w, p2b, outp);
}

// Round 9
// 119.604 us; speedup vs baseline: 1.8491x; 1.0492x over previous
//
#include <hip/hip_runtime.h>
#include <math.h>

// ---------------------------------------------------------------------------
// AngleEncodingQuantumNet: conv1+BN+relu+pool -> conv2+BN+relu+pool -> fc1
// (tanh) -> sel -> 10-qubit RY/CZ circuit -> post1(relu) -> post2.
// Train-mode BN => stats pass then apply pass.
// R9: conv1(BN+relu+pool) fused into conv2's prologue — h1bf 51MB round-trip
// and one launch removed. conv2 B operand deduped (Bh stored once; sections
// hi: col=ss, lo: col=9+ss) so LDS = 79.7KB keeps 2 blocks/CU.
// conv2 emits in-lane-pooled max/min; fc1 = 128x128 bf16 MFMA split-K=4;
// tail fused (combine+sel+quantum+post, scratch-free trig). absmax 7.6e-6.
// ---------------------------------------------------------------------------

#define BATCH 2048
#define PI_F 3.14159265358979323846f
#define KP 3328          // fc1 padded K' = 2*1568 -> 3328 (52 BK=64 steps)
#define KQ 13            // K-steps per split-K quarter
#define BSTR2 312        // conv2 B' row stride (ushorts): 18 sec + zero pad

typedef unsigned short ushort_t;
typedef __attribute__((ext_vector_type(8))) short bf16x8;
typedef __attribute__((ext_vector_type(4))) float f32x4;

__device__ __forceinline__ float wave_reduce_add(float v) {
#pragma unroll
  for (int off = 32; off >= 1; off >>= 1) v += __shfl_xor(v, off, 64);
  return v;
}

__device__ __forceinline__ ushort_t f2bf(float v) {  // RNE f32 -> bf16 bits
  unsigned u = __float_as_uint(v);
  u += 0x7FFFu + ((u >> 16) & 1u);
  return (ushort_t)(u >> 16);
}
__device__ __forceinline__ float bf2f(ushort_t b) {
  return __uint_as_float(((unsigned)b) << 16);
}

__device__ __forceinline__ float tanh_fast(float x) {  // overflow-safe, ~1e-7
  float e = __expf(-2.f * fabsf(x));
  float r = (1.f - e) / (1.f + e);
  return copysignf(r, x);
}

// ---------------- conv1: stats pass (+ bonus blocks: conv2 B', fc1 B') -----
__global__ __launch_bounds__(256) void k_conv1_stats(
    const float* __restrict__ x, const float* __restrict__ cw,
    const float* __restrict__ cb, float* __restrict__ part1,
    const float* __restrict__ cw2, ushort_t* __restrict__ wB,
    const float* __restrict__ fc1w, ushort_t* __restrict__ Bp) {
  const int t = threadIdx.x;
  if (blockIdx.x >= BATCH) {
    const int bid = blockIdx.x - BATCH;
    if (bid == 0) {
      // conv2 B': [oc][k2], k2 = sec*16+ic; sec 0..8 = Bh, 9..17 = Bl, pad 0
      for (int i = t; i < 32 * BSTR2; i += 256) {
        int oc = i / BSTR2, k = i - oc * BSTR2;
        ushort_t val = 0;
        if (k < 288) {
          int sec2 = k >> 4, ic = k & 15;
          if (sec2 < 9) {
            val = f2bf(cw2[oc * 144 + ic * 9 + sec2]);
          } else {
            float w = cw2[oc * 144 + ic * 9 + (sec2 - 9)];
            val = f2bf(w - bf2f(f2bf(w)));
          }
        }
        wB[i] = val;
      }
    } else {
      // fc1 B': [Bh | Bh] bf16, 896 rows x KP (rows>=784 and tail zeros)
      const int rb = (bid - 1) * 8;
      for (int i = t; i < 8 * (KP / 8); i += 256) {
        int rr = i / (KP / 8), c = i - rr * (KP / 8);
        int n = rb + rr;
        union { ushort_t u[8]; uint4 v; } o;
        o.v = make_uint4(0, 0, 0, 0);
        if (n < 784 && c < 392) {
          int cc = c < 196 ? c : c - 196;
          const float* wp = fc1w + (size_t)n * 1568 + cc * 8;
#pragma unroll
          for (int j = 0; j < 8; ++j) o.u[j] = f2bf(wp[j]);
        }
        ((uint4*)(Bp + (size_t)n * KP))[c] = o.v;
      }
    }
    return;
  }
  const int b = blockIdx.x;
  __shared__ float xs[30][33];
  __shared__ float ws[160];
  __shared__ float redS[16][28];
  __shared__ float redQ[16][28];
  for (int i = t; i < 30 * 33; i += 256) (&xs[0][0])[i] = 0.f;
  if (t < 144) ws[t] = cw[t];
  else if (t < 160) ws[t] = cb[t - 144];
  __syncthreads();
  const float* xb = x + b * 784;
  for (int i = t; i < 784; i += 256) xs[1 + i / 28][1 + (i % 28)] = xb[i];
  __syncthreads();
  for (int task = t; task < 448; task += 256) {
    const int oc = task / 28;
    const int row = task - oc * 28;
    float wk[9];
#pragma unroll
    for (int k = 0; k < 9; ++k) wk[k] = ws[oc * 9 + k];
    const float bc = ws[144 + oc];
    float A0 = xs[row][0], A1 = xs[row][1];
    float B0 = xs[row + 1][0], B1 = xs[row + 1][1];
    float C0 = xs[row + 2][0], C1 = xs[row + 2][1];
    float s = 0.f, q = 0.f;
#pragma unroll 4
    for (int xx = 0; xx < 28; ++xx) {
      float A2 = xs[row][xx + 2], B2 = xs[row + 1][xx + 2], C2 = xs[row + 2][xx + 2];
      float acc = bc;
      acc = fmaf(wk[0], A0, acc); acc = fmaf(wk[1], A1, acc); acc = fmaf(wk[2], A2, acc);
      acc = fmaf(wk[3], B0, acc); acc = fmaf(wk[4], B1, acc); acc = fmaf(wk[5], B2, acc);
      acc = fmaf(wk[6], C0, acc); acc = fmaf(wk[7], C1, acc); acc = fmaf(wk[8], C2, acc);
      s += acc; q = fmaf(acc, acc, q);
      A0 = A1; A1 = A2; B0 = B1; B1 = B2; C0 = C1; C1 = C2;
    }
    redS[oc][row] = s;
    redQ[oc][row] = q;
  }
  __syncthreads();
  if (t < 32) {
    const int c = t >> 1;
    float acc = 0.f;
    if (t & 1) {
#pragma unroll 4
      for (int r = 0; r < 28; ++r) acc += redQ[c][r];
    } else {
#pragma unroll 4
      for (int r = 0; r < 28; ++r) acc += redS[c][r];
    }
    part1[b * 32 + t] = acc;
  }
}

// ---------------- BN stats fold (both layers) -------------------------------
__global__ __launch_bounds__(256) void k_bnstat(
    const float* __restrict__ part, const float* __restrict__ g,
    const float* __restrict__ bb, float* __restrict__ stats,
    int nch, int nblk, double invN) {
  const int c = blockIdx.x;
  const int t = threadIdx.x;
  const int stride = nch * 2;
  double ls = 0.0, lq = 0.0;
  for (int i = t; i < nblk; i += 256) {
    ls += (double)part[i * stride + c * 2];
    lq += (double)part[i * stride + c * 2 + 1];
  }
#pragma unroll
  for (int off = 32; off >= 1; off >>= 1) {
    ls += __shfl_xor(ls, off, 64);
    lq += __shfl_xor(lq, off, 64);
  }
  __shared__ double rs[4], rq[4];
  if ((t & 63) == 0) { rs[t >> 6] = ls; rq[t >> 6] = lq; }
  __syncthreads();
  if (t == 0) {
    double S = rs[0] + rs[1] + rs[2] + rs[3];
    double Q = rq[0] + rq[1] + rq[2] + rq[3];
    double mean = S * invN;
    double var = Q * invN - mean * mean;
    double inv = 1.0 / sqrt(var + 1e-5);
    double sc = (double)g[c] * inv;
    stats[c * 2] = (float)sc;
    stats[c * 2 + 1] = (float)((double)bb[c] - mean * sc);
  }
}

// ---------------- conv1(fused)+conv2 via MFMA, in-lane 2x2 pooled output ----
// 2 images/block, 512 threads. Prologue computes conv1+BN1+relu+pool from x
// (LDS-staged) and writes hi/lo bf16 DIRECTLY into aT (the conv2 A staging):
// [img][plane][16x16 pixel pad][24], image at (+1,+1), borders zero.
// conv2: A rows QUAD-MAJOR (fragment 4-row group == one pool quad -> pooled
// max/min in-lane); A-read base = (y*16+x)*24; shift offset doff = dy,dx.
// B deduped: 18 sections (hi: col16=ss, lo: col16=9+ss; sec27 -> zero pad).
__global__ __launch_bounds__(512, 2) void k_conv2_mfma(
    const float* __restrict__ x, const float* __restrict__ cw1,
    const float* __restrict__ cb1, const float* __restrict__ stats1,
    const ushort_t* __restrict__ wB, const float* __restrict__ cb,
    float* __restrict__ part2, float* __restrict__ pooled) {
  const int b0 = blockIdx.x * 2;
  const int t = threadIdx.x;
  __shared__ __align__(16) ushort_t aT[2 * 12288];    // 49,152 B
  __shared__ __align__(16) ushort_t bS[32 * BSTR2];   // 19,968 B
  __shared__ float xs[2][30][33];                     //  7,920 B
  __shared__ float wsc[160];                          //    640 B
  __shared__ float red[2][4][64];                     //  2,048 B
  {
    uint4 z = make_uint4(0, 0, 0, 0);
    uint4* a4 = (uint4*)aT;
#pragma unroll
    for (int i = 0; i < 6; ++i) a4[t + i * 512] = z;
    float4* xz = (float4*)&xs[0][0][0];
    if (t < 495) xz[t] = make_float4(0.f, 0.f, 0.f, 0.f);  // 1980 f
    if (t < 160) wsc[t] = (t < 144) ? cw1[t] : cb1[t - 144];
    uint4* b4 = (uint4*)bS;
    const uint4* w4 = (const uint4*)wB;
    for (int i = t; i < (32 * BSTR2) / 8; i += 512) b4[i] = w4[i];
  }
  __syncthreads();
  {
    const float* xb = x + (size_t)b0 * 784;
    for (int i = t; i < 1568; i += 512) {
      int img = i / 784, j = i - img * 784;
      xs[img][1 + j / 28][1 + (j % 28)] = xb[img * 784 + j];
    }
  }
  __syncthreads();
  // ---- conv1 + BN1 + relu + 2x2 pool, hi/lo split -> aT ----
  if (t < 448) {
    const int img = t / 224, tt = t - img * 224;
    const int oc = tt / 14, pr = tt - oc * 14;
    float wk[9];
#pragma unroll
    for (int k = 0; k < 9; ++k) wk[k] = wsc[oc * 9 + k];
    const float bc = wsc[144 + oc];
    const float scale = stats1[oc * 2], shift = stats1[oc * 2 + 1];
    const int r0 = 2 * pr;
    float A0 = xs[img][r0][0],     A1 = xs[img][r0][1];
    float B0 = xs[img][r0 + 1][0], B1 = xs[img][r0 + 1][1];
    float C0 = xs[img][r0 + 2][0], C1 = xs[img][r0 + 2][1];
    float D0 = xs[img][r0 + 3][0], D1 = xs[img][r0 + 3][1];
    float pmax = 0.f;
#pragma unroll 4
    for (int xx = 0; xx < 28; ++xx) {
      float A2 = xs[img][r0][xx + 2], B2 = xs[img][r0 + 1][xx + 2];
      float C2 = xs[img][r0 + 2][xx + 2], D2 = xs[img][r0 + 3][xx + 2];
      float c0 = bc, c1 = bc;
      c0 = fmaf(wk[0], A0, c0); c0 = fmaf(wk[1], A1, c0); c0 = fmaf(wk[2], A2, c0);
      c0 = fmaf(wk[3], B0, c0); c0 = fmaf(wk[4], B1, c0); c0 = fmaf(wk[5], B2, c0);
      c0 = fmaf(wk[6], C0, c0); c0 = fmaf(wk[7], C1, c0); c0 = fmaf(wk[8], C2, c0);
      c1 = fmaf(wk[0], B0, c1); c1 = fmaf(wk[1], B1, c1); c1 = fmaf(wk[2], B2, c1);
      c1 = fmaf(wk[3], C0, c1); c1 = fmaf(wk[4], C1, c1); c1 = fmaf(wk[5], C2, c1);
      c1 = fmaf(wk[6], D0, c1); c1 = fmaf(wk[7], D1, c1); c1 = fmaf(wk[8], D2, c1);
      float e0 = fmaxf(fmaf(scale, c0, shift), 0.f);
      float e1 = fmaxf(fmaf(scale, c1, shift), 0.f);
      float m = fmaxf(e0, e1);
      if ((xx & 1) == 0) {
        pmax = m;
      } else {
        float pv = fmaxf(pmax, m);
        ushort_t hi = f2bf(pv);
        ushort_t lo = f2bf(pv - bf2f(hi));
        int off = img * 12288 + ((pr + 1) * 16 + ((xx >> 1) + 1)) * 24 + oc;
        aT[off] = hi;
        aT[off + 6144] = lo;
      }
      A0 = A1; A1 = A2; B0 = B1; B1 = B2; C0 = C1; C1 = C2; D0 = D1; D1 = D2;
    }
  }
  __syncthreads();

  // ---- conv2 MFMA ----
  const int lane = t & 63;
  const int wv = t >> 6;
  const int img = wv >> 2, wi = wv & 3;
  const int ic0 = ((lane >> 4) & 1) * 8;
  const int hb = lane >> 5;
  const int imgbase = img * 12288;
  int abase[4];
#pragma unroll
  for (int fi = 0; fi < 4; ++fi) {
    int f = wi + fi * 4;
    int pp = f * 16 + (lane & 15);       // quad-major row index
    int quad = pp >> 2;
    if (quad > 48) quad = 48;            // clamp: keeps A-read in-bounds
    int corner = pp & 3;
    int qy = quad / 7, qx = quad - qy * 7;
    int y = 2 * qy + (corner >> 1), xq = 2 * qx + (corner & 1);
    abase[fi] = imgbase + (y * 16 + xq) * 24 + ic0;  // output coords, no +1
  }
  f32x4 acc[4][2];
  {
    const float bias0 = cb[lane & 15];
    const float bias1 = cb[16 + (lane & 15)];
#pragma unroll
    for (int fi = 0; fi < 4; ++fi) {
      acc[fi][0] = (f32x4){bias0, bias0, bias0, bias0};
      acc[fi][1] = (f32x4){bias1, bias1, bias1, bias1};
    }
  }
  const int brow = (lane & 15) * BSTR2 + ic0;  // ic0 == ((lane>>4)&1)*8
#pragma unroll
  for (int kt = 0; kt < 14; ++kt) {
    int sec = 2 * kt + hb;
    int ss = sec >= 18 ? sec - 18 : (sec >= 9 ? sec - 9 : sec);
    int col16;                       // deduped B column (16-wide sections)
    if (sec >= 27) { ss = 8; col16 = 18; }      // zero pad
    else if (sec >= 18) col16 = 9 + ss;          // Bl
    else col16 = ss;                             // Bh (sec 0..17)
    int plane = (sec >= 9 && sec < 18) ? 1 : 0;
    bf16x8 bv0 = *(const bf16x8*)&bS[brow + col16 * 16];
    bf16x8 bv1 = *(const bf16x8*)&bS[brow + 16 * BSTR2 + col16 * 16];
    int dy = ss / 3, dx = ss - dy * 3;
    int doff = plane * 6144 + dy * 384 + dx * 24;
#pragma unroll
    for (int fi = 0; fi < 4; ++fi) {
      if (wi + fi * 4 < 13) {
        bf16x8 av = *(const bf16x8*)&aT[doff + abase[fi]];
        acc[fi][0] = __builtin_amdgcn_mfma_f32_16x16x32_bf16(av, bv0, acc[fi][0], 0, 0, 0);
        acc[fi][1] = __builtin_amdgcn_mfma_f32_16x16x32_bf16(av, bv1, acc[fi][1], 0, 0, 0);
      }
    }
  }
  // epilogue: in-lane 2x2 pool + per-oc stats
  float s0 = 0.f, q0 = 0.f, s1 = 0.f, q1 = 0.f;
  float* pm = pooled + (size_t)(b0 + img) * 3136;
#pragma unroll
  for (int fi = 0; fi < 4; ++fi) {
    int f = wi + fi * 4;
    int quad = f * 4 + (lane >> 4);
    if (quad < 49) {
      f32x4 a0 = acc[fi][0], a1 = acc[fi][1];
#pragma unroll
      for (int r = 0; r < 4; ++r) {
        s0 += a0[r]; q0 = fmaf(a0[r], a0[r], q0);
        s1 += a1[r]; q1 = fmaf(a1[r], a1[r], q1);
      }
      float mx0 = fmaxf(fmaxf(a0[0], a0[1]), fmaxf(a0[2], a0[3]));
      float mn0 = fminf(fminf(a0[0], a0[1]), fminf(a0[2], a0[3]));
      float mx1 = fmaxf(fmaxf(a1[0], a1[1]), fmaxf(a1[2], a1[3]));
      float mn1 = fminf(fminf(a1[0], a1[1]), fminf(a1[2], a1[3]));
      pm[quad * 32 + (lane & 15)] = mx0;
      pm[quad * 32 + 16 + (lane & 15)] = mx1;
      pm[1568 + quad * 32 + (lane & 15)] = mn0;
      pm[1568 + quad * 32 + 16 + (lane & 15)] = mn1;
    }
  }
  s0 += __shfl_xor(s0, 16, 64); s0 += __shfl_xor(s0, 32, 64);
  q0 += __shfl_xor(q0, 16, 64); q0 += __shfl_xor(q0, 32, 64);
  s1 += __shfl_xor(s1, 16, 64); s1 += __shfl_xor(s1, 32, 64);
  q1 += __shfl_xor(q1, 16, 64); q1 += __shfl_xor(q1, 32, 64);
  if (lane < 16) {
    red[img][wi][lane * 2] = s0;        red[img][wi][lane * 2 + 1] = q0;
    red[img][wi][(lane + 16) * 2] = s1; red[img][wi][(lane + 16) * 2 + 1] = q1;
  }
  __syncthreads();
  if (t < 128) {
    int im = t >> 6, c = t & 63;
    part2[(b0 + im) * 64 + c] =
        red[im][0][c] + red[im][1][c] + red[im][2][c] + red[im][3][c];
  }
}

// ---------------- pack A': BN+relu from pooled max/min, [Ah | Al] bf16 ------
__global__ __launch_bounds__(256) void k_pack_a(
    const float* __restrict__ pooled, const float* __restrict__ stats2,
    ushort_t* __restrict__ Ap) {
  const int m = blockIdx.x, t = threadIdx.x;
  __shared__ float rL[2 * 49 * 33];   // [plane][quad][oc], +1 pad per quad
  __shared__ float hv[1568];
  {
    const float4* src = (const float4*)(pooled + (size_t)m * 3136);
    for (int i = t; i < 784; i += 256) {
      int plane = i / 392, r4 = i - plane * 392;
      int quad = r4 >> 3, oc4 = (r4 & 7) * 4;
      float4 v = src[i];
      float* d = &rL[plane * 1617 + quad * 33 + oc4];
      d[0] = v.x; d[1] = v.y; d[2] = v.z; d[3] = v.w;
    }
  }
  __syncthreads();
  for (int i = t; i < 1568; i += 256) {
    int oc = i / 49, quad = i - oc * 49;
    float mx = rL[quad * 33 + oc];
    float mn = rL[1617 + quad * 33 + oc];
    float sc = stats2[oc * 2], sh = stats2[oc * 2 + 1];
    hv[i] = fmaxf(fmaf(sc, (sc >= 0.f ? mx : mn), sh), 0.f);  // BN monotone
  }
  __syncthreads();
  ushort_t* ap = Ap + (size_t)m * KP;
  for (int c = t; c < KP / 8; c += 256) {
    union { ushort_t u[8]; uint4 v; } o;
    if (c < 196) {
#pragma unroll
      for (int j = 0; j < 8; ++j) o.u[j] = f2bf(hv[c * 8 + j]);
    } else if (c < 392) {
#pragma unroll
      for (int j = 0; j < 8; ++j) {
        float v = hv[(c - 196) * 8 + j];
        o.u[j] = f2bf(v - bf2f(f2bf(v)));
      }
    } else {
      o.v = make_uint4(0, 0, 0, 0);
    }
    *(uint4*)(ap + c * 8) = o.v;
  }
}

// ---------------- fc1 bf16 MFMA GEMM: 128x128 tile, split-K=4 ---------------
__global__ __launch_bounds__(512, 2) void k_fc1_mfma(
    const ushort_t* __restrict__ Ap, const ushort_t* __restrict__ Bp,
    float* __restrict__ partial) {
  __shared__ ushort_t As[128 * 64];
  __shared__ ushort_t Bs[128 * 64];
  const int t = threadIdx.x;
  const int id = blockIdx.x;
  const int xcd = id & 7, w = id >> 3;           // w in 0..55
  const int mtl = w / 28, rem = w - mtl * 28;
  const int ks = rem / 7, nt = rem - ks * 7;
  const int mt = xcd * 2 + mtl;
  const int m0 = mt * 128, n0 = nt * 128;
  const int lane = t & 63, wid = t >> 6;
  const int wm = wid >> 2, wn = wid & 3;

  const int srow = t >> 3, sslot = t & 7;
  const int xsl = (sslot ^ (srow & 7)) << 3;
  ushort_t* awp = &As[srow * 64 + xsl];
  ushort_t* bwp = &Bs[srow * 64 + xsl];
  const uint4* agp = (const uint4*)(Ap + (size_t)(m0 + srow) * KP) + sslot;
  const uint4* bgp = (const uint4*)(Bp + (size_t)(n0 + srow) * KP) + sslot;
  const int ROWOFF = 64 * (KP / 8);

  const int rbaseA = (wm * 64 + (lane & 15)) * 64;
  const int rbaseB = (wn * 32 + (lane & 15)) * 64;
  const int x0 = ((lane >> 4) ^ (lane & 7)) << 3;
  const int x1 = (((lane >> 4) + 4) ^ (lane & 7)) << 3;

  f32x4 acc[4][2];
#pragma unroll
  for (int fm = 0; fm < 4; ++fm) {
    acc[fm][0] = (f32x4){0.f, 0.f, 0.f, 0.f};
    acc[fm][1] = (f32x4){0.f, 0.f, 0.f, 0.f};
  }
  const int kt0 = ks * KQ;
  uint4 ca0 = agp[kt0 * 8], ca1 = agp[kt0 * 8 + ROWOFF];
  uint4 cb0 = bgp[kt0 * 8], cb1 = bgp[kt0 * 8 + ROWOFF];
  for (int kt = kt0; kt < kt0 + KQ; ++kt) {
    __syncthreads();
    *(uint4*)awp = ca0; *(uint4*)(awp + 64 * 64) = ca1;
    *(uint4*)bwp = cb0; *(uint4*)(bwp + 64 * 64) = cb1;
    __syncthreads();
    if (kt + 1 < kt0 + KQ) {  // issue next-tile loads; MFMA hides latency
      ca0 = agp[(kt + 1) * 8]; ca1 = agp[(kt + 1) * 8 + ROWOFF];
      cb0 = bgp[(kt + 1) * 8]; cb1 = bgp[(kt + 1) * 8 + ROWOFF];
    }
#pragma unroll
    for (int kh = 0; kh < 2; ++kh) {
      const int xx = kh ? x1 : x0;
      bf16x8 b0 = *(const bf16x8*)&Bs[rbaseB + xx];
      bf16x8 b1 = *(const bf16x8*)&Bs[rbaseB + 16 * 64 + xx];
#pragma unroll
      for (int fm = 0; fm < 4; ++fm) {
        bf16x8 a = *(const bf16x8*)&As[rbaseA + fm * 1024 + xx];
        acc[fm][0] = __builtin_amdgcn_mfma_f32_16x16x32_bf16(a, b0, acc[fm][0], 0, 0, 0);
        acc[fm][1] = __builtin_amdgcn_mfma_f32_16x16x32_bf16(a, b1, acc[fm][1], 0, 0, 0);
      }
    }
  }
  // C/D: col=lane&15, row=(lane>>4)*4+reg [m89]
  const int mrow0 = m0 + wm * 64 + ((lane >> 4) << 2);
  const int col0 = n0 + wn * 32 + (lane & 15);
#pragma unroll
  for (int fm = 0; fm < 4; ++fm) {
#pragma unroll
    for (int fn = 0; fn < 2; ++fn) {
      int col = col0 + fn * 16;
      if (col < 832) {
        float* pb = partial + ((size_t)ks * 2048 + mrow0 + fm * 16) * 832 + col;
#pragma unroll
        for (int r = 0; r < 4; ++r) pb[(size_t)r * 832] = acc[fm][fn][r];
      }
    }
  }
}

// ---------------- quantum gate helper (value-passed cos/sin) ----------------
template <int W>
__device__ __forceinline__ void ry_cs(float (&a)[16], int lane, float c, float s) {
  if (W < 4) {
    const int st = 1 << W;
#pragma unroll
    for (int r = 0; r < 16; ++r) {
      if (!(r & st)) {
        float lo = a[r], hi = a[r + st];
        a[r] = fmaf(c, lo, -s * hi);
        a[r + st] = fmaf(s, lo, c * hi);
      }
    }
  } else {
    const int m = 1 << (W - 4);
    const float sg = (lane & m) ? s : -s;
#pragma unroll
    for (int r = 0; r < 16; ++r) {
      float other = __shfl_xor(a[r], m, 64);
      a[r] = fmaf(c, a[r], sg * other);
    }
  }
}

#define RYCS(GC, GS)                                                  \
  {                                                                   \
    ry_cs<0>(a, lane, GC(0), GS(0)); ry_cs<1>(a, lane, GC(1), GS(1)); \
    ry_cs<2>(a, lane, GC(2), GS(2)); ry_cs<3>(a, lane, GC(3), GS(3)); \
    ry_cs<4>(a, lane, GC(4), GS(4)); ry_cs<5>(a, lane, GC(5), GS(5)); \
    ry_cs<6>(a, lane, GC(6), GS(6)); ry_cs<7>(a, lane, GC(7), GS(7)); \
    ry_cs<8>(a, lane, GC(8), GS(8)); ry_cs<9>(a, lane, GC(9), GS(9)); \
  }

// ---------------- fused tail: combine + sel + quantum + post ----------------
__global__ __launch_bounds__(256) void k_tail(
    const float* __restrict__ partial, const float* __restrict__ fb,
    const float* __restrict__ sw, const float* __restrict__ sb,
    const float* __restrict__ qp, const float* __restrict__ w1,
    const float* __restrict__ b1, const float* __restrict__ w2,
    const float* __restrict__ b2, float* __restrict__ out) {
  const int t = threadIdx.x;
  __shared__ __align__(16) float swL[7840];
  __shared__ float lc[30], ls[30];
  __shared__ float hbuf[4][32];
  for (int i = t; i < 7840; i += 256) swL[i] = sw[i];
  if (t < 30) {
    float th = 0.5f * qp[t];
    lc[t] = __cosf(th);
    ls[t] = __sinf(th);
  }
  __syncthreads();
  const int wv = t >> 6;
  const int m = blockIdx.x * 4 + wv;
  const int lane = t & 63;

  const float4* p4 = (const float4*)(partial + (size_t)m * 832);
  const size_t KSL4 = (size_t)2048 * 832 / 4;
  const float4* fb4 = (const float4*)fb;
  const float4* sw4 = (const float4*)swL;
  float acc[10];
#pragma unroll
  for (int i = 0; i < 10; ++i) acc[i] = 0.f;
  for (int c4 = lane; c4 < 196; c4 += 64) {
    float4 v0 = p4[c4];
    float4 v1 = p4[c4 + KSL4];
    float4 v2 = p4[c4 + 2 * KSL4];
    float4 v3 = p4[c4 + 3 * KSL4];
    float4 bb = fb4[c4];
    float t0 = tanh_fast(v0.x + v1.x + v2.x + v3.x + bb.x);
    float t1 = tanh_fast(v0.y + v1.y + v2.y + v3.y + bb.y);
    float t2 = tanh_fast(v0.z + v1.z + v2.z + v3.z + bb.z);
    float t3 = tanh_fast(v0.w + v1.w + v2.w + v3.w + bb.w);
#pragma unroll
    for (int i = 0; i < 10; ++i) {
      float4 w = sw4[i * 196 + c4];
      acc[i] = fmaf(t0, w.x, acc[i]);
      acc[i] = fmaf(t1, w.y, acc[i]);
      acc[i] = fmaf(t2, w.z, acc[i]);
      acc[i] = fmaf(t3, w.w, acc[i]);
    }
  }
#pragma unroll
  for (int i = 0; i < 10; ++i) acc[i] = wave_reduce_add(acc[i]) + sb[i];

  float a[16];
#pragma unroll
  for (int r = 0; r < 16; ++r) a[r] = 0.f;
  if (lane == 0) a[0] = 1.f;
  float czs[16];
#pragma unroll
  for (int r = 0; r < 16; ++r) {
    int idx = (lane << 4) | r;
    czs[r] = (__popc(idx & (idx >> 1)) & 1) ? -1.f : 1.f;
  }
#define EC(i) __cosf(acc[i] * (0.5f * PI_F))
#define ES(i) __sinf(acc[i] * (0.5f * PI_F))
  RYCS(EC, ES)
#undef EC
#undef ES
#pragma unroll
  for (int layer = 0; layer < 3; ++layer) {
    const int lb = layer * 10;
#define LC(i) (lc[lb + i])
#define LS(i) (ls[lb + i])
    RYCS(LC, LS)
#undef LC
#undef LS
#pragma unroll
    for (int r = 0; r < 16; ++r) a[r] *= czs[r];
  }
  float p[16];
  float lt = 0.f;
#pragma unroll
  for (int r = 0; r < 16; ++r) { p[r] = a[r] * a[r]; lt += p[r]; }
  float z[10];
#pragma unroll
  for (int ww = 0; ww < 4; ++ww) {
    float v = 0.f;
#pragma unroll
    for (int r = 0; r < 16; ++r) v += ((r >> ww) & 1) ? -p[r] : p[r];
    z[ww] = v;
  }
#pragma unroll
  for (int ww = 4; ww < 10; ++ww) z[ww] = ((lane >> (ww - 4)) & 1) ? -lt : lt;
#pragma unroll
  for (int ww = 0; ww < 10; ++ww) z[ww] = wave_reduce_add(z[ww]);

  if (lane < 32) {
    float s = b1[lane];
#pragma unroll
    for (int i = 0; i < 10; ++i) s = fmaf(w1[lane * 10 + i], z[i], s);
    hbuf[wv][lane] = fmaxf(s, 0.f);
  }
  __syncthreads();
  if (lane < 10) {
    float s = b2[lane];
#pragma unroll
    for (int jj = 0; jj < 32; ++jj) s = fmaf(w2[lane * 32 + jj], hbuf[wv][jj], s);
    out[m * 10 + lane] = s;
  }
}

// ---------------------------------------------------------------------------
extern "C" void kernel_launch(void* const* d_in, const int* in_sizes, int n_in,
                              void* d_out, int out_size, void* d_ws, size_t ws_size,
                              hipStream_t stream) {
  (void)in_sizes; (void)n_in; (void)out_size; (void)ws_size;
  const float* x    = (const float*)d_in[0];
  const float* c1w  = (const float*)d_in[1];
  const float* c1b  = (const float*)d_in[2];
  const float* bn1g = (const float*)d_in[3];
  const float* bn1b = (const float*)d_in[4];
  const float* c2w  = (const float*)d_in[5];
  const float* c2b  = (const float*)d_in[6];
  const float* bn2g = (const float*)d_in[7];
  const float* bn2b = (const float*)d_in[8];
  const float* fc1w = (const float*)d_in[9];
  const float* fc1b = (const float*)d_in[10];
  const float* selw = (const float*)d_in[11];
  const float* selb = (const float*)d_in[12];
  const float* qpar = (const float*)d_in[13];
  const float* p1w  = (const float*)d_in[14];
  const float* p1b  = (const float*)d_in[15];
  const float* p2w  = (const float*)d_in[16];
  const float* p2b  = (const float*)d_in[17];

  // ws layout (floats). Aliases: Ap at ws start (free region);
  //                              partial in pooled region (dead after pack_a).
  float* ws = (float*)d_ws;
  ushort_t* Ap = (ushort_t*)ws;             // 3,407,872 f region reserved
  size_t o = 6422528;
  float* pooled  = ws + o;                  // 6,422,528 f [2048][2][49][32]
  float* partial = ws + o;                  // alias 6,815,744 f [4][2048][832]
  o += 6815744;
  ushort_t* Bp  = (ushort_t*)(ws + o); o += 1490944;  // 896*3328 ushorts
  ushort_t* wB  = (ushort_t*)(ws + o); o += 4992;     // 32*312 ushorts
  float* part1  = ws + o; o += 65536;
  float* part2  = ws + o; o += 131072;
  float* stats1 = ws + o; o += 32;
  float* stats2 = ws + o; o += 64;
  float* outp   = (float*)d_out;

  k_conv1_stats<<<BATCH + 1 + 112, 256, 0, stream>>>(x, c1w, c1b, part1, c2w,
                                                     wB, fc1w, Bp);
  k_bnstat<<<16, 256, 0, stream>>>(part1, bn1g, bn1b, stats1, 16, BATCH,
                                   1.0 / (2048.0 * 784.0));
  k_conv2_mfma<<<BATCH / 2, 512, 0, stream>>>(x, c1w, c1b, stats1, wB, c2b,
                                              part2, pooled);
  k_bnstat<<<32, 256, 0, stream>>>(part2, bn2g, bn2b, stats2, 32, BATCH,
                                   1.0 / (2048.0 * 196.0));
  k_pack_a<<<BATCH, 256, 0, stream>>>(pooled, stats2, Ap);
  k_fc1_mfma<<<448, 512, 0, stream>>>(Ap, Bp, partial);
  k_tail<<<BATCH / 4, 256, 0, stream>>>(partial, fc1b, selw, selb, qpar,
                                        p1w, p1b, p2w, p2b, outp);
}